// Round 2
// baseline (1381.305 us; speedup 1.0000x reference)
//
#include <hip/hip_runtime.h>
#include <hip/hip_bf16.h>

#define N_NODES 50000
#define N_EDGES 1600000
#define ETOT (N_EDGES + N_NODES)
#define NP 50048  // N padded to 64*782 for GEMM row tiles

typedef __attribute__((ext_vector_type(8))) short short8;
typedef __attribute__((ext_vector_type(4))) float f32x4;

__device__ __forceinline__ float b2f(unsigned short u) {
    union { unsigned int i; float f; } v; v.i = ((unsigned int)u) << 16; return v.f;
}
__device__ __forceinline__ unsigned short f2b(float f) {
    union { float f; unsigned int i; } v; v.f = f;
    unsigned int r = v.i + 0x7FFF + ((v.i >> 16) & 1);  // RNE
    return (unsigned short)(r >> 16);
}

// ---------- weight transpose + hi/lo split: W f32 [K,C] -> Wt{hi,lo} bf16 [C,K] ----------
__global__ void k_tsplit(const float* __restrict__ W,
                         unsigned short* __restrict__ Whi, unsigned short* __restrict__ Wlo,
                         int K, int C) {
    int idx = blockIdx.x * 256 + threadIdx.x;
    if (idx >= K * C) return;
    int k = idx / C, c = idx - k * C;
    float v = W[idx];
    unsigned short hi = f2b(v);
    unsigned short lo = f2b(v - b2f(hi));
    Whi[c * K + k] = hi; Wlo[c * K + k] = lo;
}

// ---------- input split: x f32 -> xhi, xlo bf16 (same layout) ----------
__global__ void k_split(const float* __restrict__ x,
                        unsigned short* __restrict__ xhi, unsigned short* __restrict__ xlo,
                        int total) {
    int idx = blockIdx.x * 256 + threadIdx.x;
    if (idx >= total) return;
    float v = x[idx];
    unsigned short hi = f2b(v);
    xhi[idx] = hi; xlo[idx] = f2b(v - b2f(hi));
}

// ---------- attention projection vectors: u[k, j] = sum_c W[k, h*C+c] * att[h,c] ----------
// j < H -> att_src head j ; j >= H -> att_dst head j-H. u is [K, 2H] row-major.
__global__ void k_mku(const float* __restrict__ W, const float* __restrict__ attS,
                      const float* __restrict__ attD, float* __restrict__ u,
                      int K, int C, int H) {
    int idx = blockIdx.x * 256 + threadIdx.x;
    int NC = 2 * H;
    if (idx >= K * NC) return;
    int k = idx / NC, j = idx - k * NC;
    int h = (j < H) ? j : j - H;
    const float* av = ((j < H) ? attS : attD) + h * C;
    const float* wr = W + (size_t)k * (C * H) + h * C;
    float s = 0.f;
    for (int c = 0; c < C; ++c) s += wr[c] * av[c];
    u[idx] = s;
}

// ---------- CSR build ----------
__global__ void k_count(const int* __restrict__ ei, int* __restrict__ deg) {
    int e = blockIdx.x * 256 + threadIdx.x;
    if (e >= ETOT) return;
    int dst = (e < N_EDGES) ? ei[N_EDGES + e] : (e - N_EDGES);
    atomicAdd(&deg[dst], 1);
}

__global__ void k_scan(const int* __restrict__ deg, int* __restrict__ rowptr,
                       int* __restrict__ cursor) {
    __shared__ int part[1024];
    int t = threadIdx.x;
    const int CH = (N_NODES + 1023) / 1024;
    int start = t * CH, end = min(start + CH, N_NODES);
    int sum = 0;
    for (int i = start; i < end; ++i) sum += deg[i];
    part[t] = sum;
    __syncthreads();
    for (int off = 1; off < 1024; off <<= 1) {
        int v = (t >= off) ? part[t - off] : 0;
        __syncthreads();
        part[t] += v;
        __syncthreads();
    }
    int run = part[t] - sum;  // exclusive prefix
    for (int i = start; i < end; ++i) {
        rowptr[i] = run; cursor[i] = run; run += deg[i];
    }
}

__global__ void k_fill(const int* __restrict__ ei, int* __restrict__ cursor,
                       int* __restrict__ csr) {
    int e = blockIdx.x * 256 + threadIdx.x;
    if (e >= ETOT) return;
    int src, dst;
    if (e < N_EDGES) { src = ei[e]; dst = ei[N_EDGES + e]; }
    else             { src = dst = e - N_EDGES; }
    int pos = atomicAdd(&cursor[dst], 1);
    csr[pos] = src;
}

// ---------- split GEMM: (Ahi+Alo)[nrows,256] x (Bthi+Btlo)^T[C,256] -> Cout [NP,ldc] ----------
template <bool F32OUT>
__global__ __launch_bounds__(256) void k_gemm_s(
    const unsigned short* __restrict__ Ahi, const unsigned short* __restrict__ Alo,
    const unsigned short* __restrict__ Bthi, const unsigned short* __restrict__ Btlo,
    void* __restrict__ Cout, int nrows, int ncols, int ldc) {
    const int K = 256;
    int lane = threadIdx.x & 63;
    int wave = threadIdx.x >> 6;
    int row0 = (blockIdx.x * 4 + wave) * 16;
    int col0 = blockIdx.y * 64;
    int ar = row0 + (lane & 15);
    if (ar >= nrows) ar = nrows - 1;   // clamp OOB row reads
    int ks = (lane >> 4) * 8;
    const unsigned short* Ahp = Ahi + (size_t)ar * K + ks;
    const unsigned short* Alp = Alo + (size_t)ar * K + ks;
    f32x4 acc[4] = {{0,0,0,0},{0,0,0,0},{0,0,0,0},{0,0,0,0}};
    for (int k = 0; k < K; k += 32) {
        short8 ah = *(const short8*)(Ahp + k);
        short8 al = *(const short8*)(Alp + k);
        #pragma unroll
        for (int ct = 0; ct < 4; ++ct) {
            size_t boff = (size_t)(col0 + ct * 16 + (lane & 15)) * K + k + ks;
            short8 bh = *(const short8*)(Bthi + boff);
            short8 bl = *(const short8*)(Btlo + boff);
            acc[ct] = __builtin_amdgcn_mfma_f32_16x16x32_bf16(ah, bh, acc[ct], 0, 0, 0);
            acc[ct] = __builtin_amdgcn_mfma_f32_16x16x32_bf16(al, bh, acc[ct], 0, 0, 0);
            acc[ct] = __builtin_amdgcn_mfma_f32_16x16x32_bf16(ah, bl, acc[ct], 0, 0, 0);
        }
    }
    int rbase = row0 + (lane >> 4) * 4;
    int cb = lane & 15;
    #pragma unroll
    for (int ct = 0; ct < 4; ++ct) {
        int cc = col0 + ct * 16 + cb;
        if (cc >= ncols) continue;
        #pragma unroll
        for (int j = 0; j < 4; ++j) {
            if (F32OUT)
                ((float*)Cout)[(size_t)(rbase + j) * ldc + cc] = acc[ct][j];
            else
                ((unsigned short*)Cout)[(size_t)(rbase + j) * ldc + cc] = f2b(acc[ct][j]);
        }
    }
}

// ---------- attention logits: one wave per node, NC = 2H columns of u ----------
template <int NC, bool HL>
__global__ __launch_bounds__(256) void k_att(
    const void* __restrict__ xa, const void* __restrict__ xb,  // f32 x, or bf16 hi/lo
    const float* __restrict__ u,                               // [256, NC]
    float* __restrict__ asrc, float* __restrict__ adst) {      // [N, NC/2]
    int lane = threadIdx.x & 63;
    int node = blockIdx.x * 4 + (threadIdx.x >> 6);
    if (node >= N_NODES) return;
    float acc[NC];
    #pragma unroll
    for (int j = 0; j < NC; ++j) acc[j] = 0.f;
    int k0 = lane * 4;
    float xv[4];
    if (HL) {
        ushort4 h = *(const ushort4*)((const unsigned short*)xa + (size_t)node * 256 + k0);
        ushort4 l = *(const ushort4*)((const unsigned short*)xb + (size_t)node * 256 + k0);
        xv[0] = b2f(h.x) + b2f(l.x); xv[1] = b2f(h.y) + b2f(l.y);
        xv[2] = b2f(h.z) + b2f(l.z); xv[3] = b2f(h.w) + b2f(l.w);
    } else {
        float4 v = *(const float4*)((const float*)xa + (size_t)node * 256 + k0);
        xv[0] = v.x; xv[1] = v.y; xv[2] = v.z; xv[3] = v.w;
    }
    #pragma unroll
    for (int i = 0; i < 4; ++i)
        #pragma unroll
        for (int j = 0; j < NC; ++j)
            acc[j] += xv[i] * u[(size_t)(k0 + i) * NC + j];
    #pragma unroll
    for (int off = 32; off > 0; off >>= 1)
        #pragma unroll
        for (int j = 0; j < NC; ++j)
            acc[j] += __shfl_xor(acc[j], off);
    if (lane == 0) {
        const int H = NC / 2;
        #pragma unroll
        for (int h = 0; h < H; ++h) {
            asrc[(size_t)node * H + h] = acc[h];
            adst[(size_t)node * H + h] = acc[H + h];
        }
    }
}

// ---------- GAT aggregation, 256 channels, one wave per dst node; out = ELU -> hi/lo bf16 ----------
template <int H>
__global__ __launch_bounds__(256) void k_agg(
    const unsigned short* __restrict__ xp,   // bf16 [NP,256]
    const float* __restrict__ asrc, const float* __restrict__ adst,  // [N,H]
    const int* __restrict__ rowptr, const int* __restrict__ deg,
    const int* __restrict__ csr,
    const float* __restrict__ bias,          // [256]
    unsigned short* __restrict__ hhi, unsigned short* __restrict__ hlo)  // bf16 [NP,256]
{
    int lane = threadIdx.x & 63;
    int node = blockIdx.x * 4 + (threadIdx.x >> 6);
    if (node >= N_NODES) return;
    int ptr = rowptr[node], dg = deg[node];
    float adr[H], m[H], s[H];
    #pragma unroll
    for (int h = 0; h < H; ++h) { adr[h] = adst[node * H + h]; m[h] = -1e30f; s[h] = 0.f; }
    for (int i = lane; i < dg; i += 64) {
        int sn = csr[ptr + i];
        #pragma unroll
        for (int h = 0; h < H; ++h) {
            float e = asrc[sn * H + h] + adr[h];
            e = (e >= 0.f) ? e : 0.2f * e;
            float mn = fmaxf(m[h], e);
            s[h] = s[h] * __expf(m[h] - mn) + __expf(e - mn);
            m[h] = mn;
        }
    }
    #pragma unroll
    for (int off = 32; off > 0; off >>= 1) {
        #pragma unroll
        for (int h = 0; h < H; ++h) {
            float mo = __shfl_xor(m[h], off);
            float so = __shfl_xor(s[h], off);
            float mn = fmaxf(m[h], mo);
            s[h] = s[h] * __expf(m[h] - mn) + so * __expf(mo - mn);
            m[h] = mn;
        }
    }
    const int hh = (lane * H) >> 6;
    float mh = m[hh];
    float inh = 1.0f / s[hh];
    float ad = adr[hh];
    int cbase = lane * 4;
    float a0 = 0, a1 = 0, a2 = 0, a3 = 0;
    for (int i = 0; i < dg; ++i) {
        int sn = csr[ptr + i];
        float e = asrc[sn * H + hh] + ad;
        e = (e >= 0.f) ? e : 0.2f * e;
        float alpha = __expf(e - mh) * inh;
        ushort4 v = *(const ushort4*)(xp + (size_t)sn * 256 + cbase);
        a0 += alpha * b2f(v.x);
        a1 += alpha * b2f(v.y);
        a2 += alpha * b2f(v.z);
        a3 += alpha * b2f(v.w);
    }
    float o[4] = {a0, a1, a2, a3};
    #pragma unroll
    for (int j = 0; j < 4; ++j) {
        float v = o[j] + bias[cbase + j];
        v = (v > 0.f) ? v : (__expf(v) - 1.f);   // ELU
        unsigned short hi = f2b(v);
        hhi[(size_t)node * 256 + cbase + j] = hi;
        hlo[(size_t)node * 256 + cbase + j] = f2b(v - b2f(hi));
    }
}

// ---------- final layer: 40 channels + log_softmax, f32 in/out ----------
__global__ __launch_bounds__(256) void k_agg_final(
    const float* __restrict__ xp,            // f32 [NP,40]
    const float* __restrict__ asrc, const float* __restrict__ adst,
    const int* __restrict__ rowptr, const int* __restrict__ deg,
    const int* __restrict__ csr,
    const float* __restrict__ bias,          // [40]
    float* __restrict__ out)                 // f32 [N,40]
{
    int lane = threadIdx.x & 63;
    int node = blockIdx.x * 4 + (threadIdx.x >> 6);
    if (node >= N_NODES) return;
    int ptr = rowptr[node], dg = deg[node];
    float ad = adst[node];
    float m = -1e30f, s = 0.f;
    for (int i = lane; i < dg; i += 64) {
        int sn = csr[ptr + i];
        float e = asrc[sn] + ad;
        e = (e >= 0.f) ? e : 0.2f * e;
        float mn = fmaxf(m, e);
        s = s * __expf(m - mn) + __expf(e - mn);
        m = mn;
    }
    #pragma unroll
    for (int off = 32; off > 0; off >>= 1) {
        float mo = __shfl_xor(m, off), so = __shfl_xor(s, off);
        float mn = fmaxf(m, mo);
        s = s * __expf(m - mn) + so * __expf(mo - mn);
        m = mn;
    }
    float inh = 1.0f / s;
    float acc = 0.f;
    for (int i = 0; i < dg; ++i) {
        int sn = csr[ptr + i];
        float e = asrc[sn] + ad;
        e = (e >= 0.f) ? e : 0.2f * e;
        float alpha = __expf(e - m) * inh;
        if (lane < 40) acc += alpha * xp[(size_t)sn * 40 + lane];
    }
    float val = (lane < 40) ? acc + bias[lane] : -1e30f;
    float mx = val;
    #pragma unroll
    for (int off = 32; off > 0; off >>= 1) mx = fmaxf(mx, __shfl_xor(mx, off));
    float ex = (lane < 40) ? __expf(val - mx) : 0.f;
    #pragma unroll
    for (int off = 32; off > 0; off >>= 1) ex += __shfl_xor(ex, off);
    float lse = __logf(ex);
    if (lane < 40) out[(size_t)node * 40 + lane] = val - mx - lse;
}

extern "C" void kernel_launch(void* const* d_in, const int* in_sizes, int n_in,
                              void* d_out, int out_size, void* d_ws, size_t ws_size,
                              hipStream_t stream) {
    const float* x   = (const float*)d_in[0];
    const int*   ei  = (const int*)d_in[1];
    const float* W0  = (const float*)d_in[2];
    const float* as0 = (const float*)d_in[3];
    const float* ad0 = (const float*)d_in[4];
    const float* b0  = (const float*)d_in[5];
    const float* W1  = (const float*)d_in[6];
    const float* as1 = (const float*)d_in[7];
    const float* ad1 = (const float*)d_in[8];
    const float* b1  = (const float*)d_in[9];
    const float* W2  = (const float*)d_in[10];
    const float* as2 = (const float*)d_in[11];
    const float* ad2 = (const float*)d_in[12];
    const float* b2  = (const float*)d_in[13];
    float* out = (float*)d_out;

    char* p = (char*)d_ws;
    auto carve = [&](size_t bytes) -> char* {
        char* r = p; p += (bytes + 255) & ~(size_t)255; return r;
    };
    unsigned short* xhi  = (unsigned short*)carve((size_t)NP * 256 * 2);
    unsigned short* xlo  = (unsigned short*)carve((size_t)NP * 256 * 2);
    unsigned short* hhi  = (unsigned short*)carve((size_t)NP * 256 * 2);
    unsigned short* hlo  = (unsigned short*)carve((size_t)NP * 256 * 2);
    unsigned short* xpb  = (unsigned short*)carve((size_t)NP * 256 * 2);
    float*          xp2  = (float*)carve((size_t)NP * 40 * 4);
    unsigned short* Wt0h = (unsigned short*)carve(256 * 256 * 2);
    unsigned short* Wt0l = (unsigned short*)carve(256 * 256 * 2);
    unsigned short* Wt1h = (unsigned short*)carve(256 * 256 * 2);
    unsigned short* Wt1l = (unsigned short*)carve(256 * 256 * 2);
    unsigned short* Wt2h = (unsigned short*)carve(64 * 256 * 2);
    unsigned short* Wt2l = (unsigned short*)carve(64 * 256 * 2);
    float* u0 = (float*)carve(256 * 16 * 4);
    float* u1 = (float*)carve(256 * 2 * 4);
    float* u2 = (float*)carve(256 * 2 * 4);
    float* asrc0 = (float*)carve((size_t)N_NODES * 8 * 4);
    float* adst0 = (float*)carve((size_t)N_NODES * 8 * 4);
    float* asrc1 = (float*)carve((size_t)N_NODES * 4);
    float* adst1 = (float*)carve((size_t)N_NODES * 4);
    float* asrc2 = (float*)carve((size_t)N_NODES * 4);
    float* adst2 = (float*)carve((size_t)N_NODES * 4);
    int* deg    = (int*)carve((size_t)N_NODES * 4);
    int* rowptr = (int*)carve((size_t)N_NODES * 4);
    int* cursor = (int*)carve((size_t)N_NODES * 4);
    int* csr    = (int*)carve((size_t)ETOT * 4);

    hipMemsetAsync(deg, 0, (size_t)N_NODES * 4, stream);
    hipMemsetAsync(Wt2h, 0, 64 * 256 * 2, stream);  // zero pad cols 40..63
    hipMemsetAsync(Wt2l, 0, 64 * 256 * 2, stream);

    k_tsplit<<<(256 * 256 + 255) / 256, 256, 0, stream>>>(W0, Wt0h, Wt0l, 256, 256);
    k_tsplit<<<(256 * 256 + 255) / 256, 256, 0, stream>>>(W1, Wt1h, Wt1l, 256, 256);
    k_tsplit<<<(256 * 40 + 255) / 256, 256, 0, stream>>>(W2, Wt2h, Wt2l, 256, 40);
    k_split<<<((N_NODES * 256) + 255) / 256, 256, 0, stream>>>(x, xhi, xlo, N_NODES * 256);

    k_mku<<<(256 * 16 + 255) / 256, 256, 0, stream>>>(W0, as0, ad0, u0, 256, 32, 8);
    k_mku<<<(256 * 2 + 255) / 256, 256, 0, stream>>>(W1, as1, ad1, u1, 256, 256, 1);
    k_mku<<<(256 * 2 + 255) / 256, 256, 0, stream>>>(W2, as2, ad2, u2, 256, 40, 1);

    k_count<<<(ETOT + 255) / 256, 256, 0, stream>>>(ei, deg);
    k_scan<<<1, 1024, 0, stream>>>(deg, rowptr, cursor);
    k_fill<<<(ETOT + 255) / 256, 256, 0, stream>>>(ei, cursor, csr);

    dim3 g0(NP / 64, 4);
    dim3 gn((N_NODES + 3) / 4);
    // layer 0
    k_gemm_s<false><<<g0, 256, 0, stream>>>(xhi, xlo, Wt0h, Wt0l, xpb, N_NODES, 256, 256);
    k_att<16, false><<<gn, 256, 0, stream>>>(x, nullptr, u0, asrc0, adst0);
    k_agg<8><<<gn, 256, 0, stream>>>(xpb, asrc0, adst0, rowptr, deg, csr, b0, hhi, hlo);
    // layer 1
    k_gemm_s<false><<<g0, 256, 0, stream>>>(hhi, hlo, Wt1h, Wt1l, xpb, N_NODES, 256, 256);
    k_att<2, true><<<gn, 256, 0, stream>>>(hhi, hlo, u1, asrc1, adst1);
    k_agg<1><<<gn, 256, 0, stream>>>(xpb, asrc1, adst1, rowptr, deg, csr, b1, xhi, xlo);
    // layer 2 (reuses xhi/xlo as h1)
    dim3 g2(NP / 64, 1);
    k_gemm_s<true><<<g2, 256, 0, stream>>>(xhi, xlo, Wt2h, Wt2l, xp2, N_NODES, 40, 40);
    k_att<2, true><<<gn, 256, 0, stream>>>(xhi, xlo, u2, asrc2, adst2);
    k_agg_final<<<gn, 256, 0, stream>>>(xp2, asrc2, adst2, rowptr, deg, csr, b2, out);
}

// Round 3
// 1157.621 us; speedup vs baseline: 1.1932x; 1.1932x over previous
//
#include <hip/hip_runtime.h>
#include <hip/hip_bf16.h>

#define N_NODES 50000
#define N_EDGES 1600000
#define ETOT (N_EDGES + N_NODES)
#define NP 50048  // N padded to 64*782 for GEMM row tiles

typedef __attribute__((ext_vector_type(8))) short short8;
typedef __attribute__((ext_vector_type(4))) float f32x4;

__device__ __forceinline__ float b2f(unsigned short u) {
    union { unsigned int i; float f; } v; v.i = ((unsigned int)u) << 16; return v.f;
}
__device__ __forceinline__ unsigned short f2b(float f) {
    union { float f; unsigned int i; } v; v.f = f;
    unsigned int r = v.i + 0x7FFF + ((v.i >> 16) & 1);  // RNE
    return (unsigned short)(r >> 16);
}

// ---------- weight transpose + hi/lo split: W f32 [K,C] -> Wt{hi,lo} bf16 [C,K] ----------
__global__ void k_tsplit(const float* __restrict__ W,
                         unsigned short* __restrict__ Whi, unsigned short* __restrict__ Wlo,
                         int K, int C) {
    int idx = blockIdx.x * 256 + threadIdx.x;
    if (idx >= K * C) return;
    int k = idx / C, c = idx - k * C;
    float v = W[idx];
    unsigned short hi = f2b(v);
    unsigned short lo = f2b(v - b2f(hi));
    Whi[c * K + k] = hi; Wlo[c * K + k] = lo;
}

// ---------- input split: x f32 -> xhi, xlo bf16 ----------
__global__ void k_split(const float* __restrict__ x,
                        unsigned short* __restrict__ xhi, unsigned short* __restrict__ xlo,
                        int total) {
    int idx = blockIdx.x * 256 + threadIdx.x;
    if (idx >= total) return;
    float v = x[idx];
    unsigned short hi = f2b(v);
    xhi[idx] = hi; xlo[idx] = f2b(v - b2f(hi));
}

// ---------- attention projection vectors: u[k, j] = sum_c W[k, h*C+c] * att[h,c] ----------
__global__ void k_mku(const float* __restrict__ W, const float* __restrict__ attS,
                      const float* __restrict__ attD, float* __restrict__ u,
                      int K, int C, int H) {
    int idx = blockIdx.x * 256 + threadIdx.x;
    int NC = 2 * H;
    if (idx >= K * NC) return;
    int k = idx / NC, j = idx - k * NC;
    int h = (j < H) ? j : j - H;
    const float* av = ((j < H) ? attS : attD) + h * C;
    const float* wr = W + (size_t)k * (C * H) + h * C;
    float s = 0.f;
    for (int c = 0; c < C; ++c) s += wr[c] * av[c];
    u[idx] = s;
}

// ---------- CSR build ----------
__global__ void k_count(const int* __restrict__ ei, int* __restrict__ deg) {
    int e = blockIdx.x * 256 + threadIdx.x;
    if (e >= ETOT) return;
    int dst = (e < N_EDGES) ? ei[N_EDGES + e] : (e - N_EDGES);
    atomicAdd(&deg[dst], 1);
}

__global__ void k_scan(const int* __restrict__ deg, int* __restrict__ rowptr,
                       int* __restrict__ cursor) {
    __shared__ int part[1024];
    int t = threadIdx.x;
    const int CH = (N_NODES + 1023) / 1024;
    int start = t * CH, end = min(start + CH, N_NODES);
    int sum = 0;
    for (int i = start; i < end; ++i) sum += deg[i];
    part[t] = sum;
    __syncthreads();
    for (int off = 1; off < 1024; off <<= 1) {
        int v = (t >= off) ? part[t - off] : 0;
        __syncthreads();
        part[t] += v;
        __syncthreads();
    }
    int run = part[t] - sum;
    for (int i = start; i < end; ++i) {
        rowptr[i] = run; cursor[i] = run; run += deg[i];
    }
}

__global__ void k_fill(const int* __restrict__ ei, int* __restrict__ cursor,
                       int* __restrict__ csr) {
    int e = blockIdx.x * 256 + threadIdx.x;
    if (e >= ETOT) return;
    int src, dst;
    if (e < N_EDGES) { src = ei[e]; dst = ei[N_EDGES + e]; }
    else             { src = dst = e - N_EDGES; }
    int pos = atomicAdd(&cursor[dst], 1);
    csr[pos] = src;
}

// ---------- split GEMM: (Ahi+Alo)[nrows,256] x (Bthi+Btlo)^T -> bf16 [NP,ldc], pad cols zeroed ----------
__global__ __launch_bounds__(256) void k_gemm_s(
    const unsigned short* __restrict__ Ahi, const unsigned short* __restrict__ Alo,
    const unsigned short* __restrict__ Bthi, const unsigned short* __restrict__ Btlo,
    unsigned short* __restrict__ Cout, int nrows, int ncols, int ldc) {
    const int K = 256;
    int lane = threadIdx.x & 63;
    int wave = threadIdx.x >> 6;
    int row0 = (blockIdx.x * 4 + wave) * 16;
    int col0 = blockIdx.y * 64;
    int ar = row0 + (lane & 15);
    if (ar >= nrows) ar = nrows - 1;
    int ks = (lane >> 4) * 8;
    const unsigned short* Ahp = Ahi + (size_t)ar * K + ks;
    const unsigned short* Alp = Alo + (size_t)ar * K + ks;
    f32x4 acc[4] = {{0,0,0,0},{0,0,0,0},{0,0,0,0},{0,0,0,0}};
    for (int k = 0; k < K; k += 32) {
        short8 ah = *(const short8*)(Ahp + k);
        short8 al = *(const short8*)(Alp + k);
        #pragma unroll
        for (int ct = 0; ct < 4; ++ct) {
            size_t boff = (size_t)(col0 + ct * 16 + (lane & 15)) * K + k + ks;
            short8 bh = *(const short8*)(Bthi + boff);
            short8 bl = *(const short8*)(Btlo + boff);
            acc[ct] = __builtin_amdgcn_mfma_f32_16x16x32_bf16(ah, bh, acc[ct], 0, 0, 0);
            acc[ct] = __builtin_amdgcn_mfma_f32_16x16x32_bf16(al, bh, acc[ct], 0, 0, 0);
            acc[ct] = __builtin_amdgcn_mfma_f32_16x16x32_bf16(ah, bl, acc[ct], 0, 0, 0);
        }
    }
    int rbase = row0 + (lane >> 4) * 4;
    int cb = lane & 15;
    #pragma unroll
    for (int ct = 0; ct < 4; ++ct) {
        int cc = col0 + ct * 16 + cb;
        #pragma unroll
        for (int j = 0; j < 4; ++j) {
            float v = (cc < ncols) ? acc[ct][j] : 0.f;
            Cout[(size_t)(rbase + j) * ldc + cc] = f2b(v);
        }
    }
}

// ---------- layer-0 attention logits from f32 x: one wave per node ----------
template <int NC>
__global__ __launch_bounds__(256) void k_att0(
    const float* __restrict__ x, const float* __restrict__ u,
    float* __restrict__ asrc, float* __restrict__ adst) {
    int lane = threadIdx.x & 63;
    int node = blockIdx.x * 4 + (threadIdx.x >> 6);
    if (node >= N_NODES) return;
    float acc[NC];
    #pragma unroll
    for (int j = 0; j < NC; ++j) acc[j] = 0.f;
    int k0 = lane * 4;
    float4 v = *(const float4*)(x + (size_t)node * 256 + k0);
    float xv[4] = {v.x, v.y, v.z, v.w};
    #pragma unroll
    for (int i = 0; i < 4; ++i)
        #pragma unroll
        for (int j = 0; j < NC; ++j)
            acc[j] += xv[i] * u[(size_t)(k0 + i) * NC + j];
    #pragma unroll
    for (int off = 32; off > 0; off >>= 1)
        #pragma unroll
        for (int j = 0; j < NC; ++j)
            acc[j] += __shfl_xor(acc[j], off);
    if (lane == 0) {
        const int H = NC / 2;
        #pragma unroll
        for (int h = 0; h < H; ++h) {
            asrc[(size_t)node * H + h] = acc[h];
            adst[(size_t)node * H + h] = acc[H + h];
        }
    }
}

// ---------- per-slot attention weights: alpha[slot*H+h] bf16 ----------
template <int H>
__global__ __launch_bounds__(256) void k_alpha(
    const float* __restrict__ asrc, const float* __restrict__ adst,
    const int* __restrict__ rowptr, const int* __restrict__ deg,
    const int* __restrict__ csr, unsigned short* __restrict__ alpha) {
    int lane = threadIdx.x & 63;
    int node = blockIdx.x * 4 + (threadIdx.x >> 6);
    if (node >= N_NODES) return;
    int ptr = rowptr[node], dg = deg[node];
    float adr[H], m[H], s[H];
    #pragma unroll
    for (int h = 0; h < H; ++h) { adr[h] = adst[node * H + h]; m[h] = -1e30f; s[h] = 0.f; }
    for (int i = lane; i < dg; i += 64) {
        int sn = csr[ptr + i];
        #pragma unroll
        for (int h = 0; h < H; ++h) {
            float e = asrc[sn * H + h] + adr[h];
            e = (e >= 0.f) ? e : 0.2f * e;
            float mn = fmaxf(m[h], e);
            s[h] = s[h] * __expf(m[h] - mn) + __expf(e - mn);
            m[h] = mn;
        }
    }
    #pragma unroll
    for (int off = 32; off > 0; off >>= 1) {
        #pragma unroll
        for (int h = 0; h < H; ++h) {
            float mo = __shfl_xor(m[h], off);
            float so = __shfl_xor(s[h], off);
            float mn = fmaxf(m[h], mo);
            s[h] = s[h] * __expf(m[h] - mn) + so * __expf(mo - mn);
            m[h] = mn;
        }
    }
    float inv[H];
    #pragma unroll
    for (int h = 0; h < H; ++h) inv[h] = 1.0f / s[h];
    for (int i = lane; i < dg; i += 64) {
        int sn = csr[ptr + i];
        #pragma unroll
        for (int h = 0; h < H; ++h) {
            float e = asrc[sn * H + h] + adr[h];
            e = (e >= 0.f) ? e : 0.2f * e;
            alpha[(size_t)(ptr + i) * H + h] = f2b(__expf(e - m[h]) * inv[h]);
        }
    }
}

// ---------- gather-aggregate 256ch: 2 edges/iter, depth-2 pipeline ----------
template <int H, bool FUSE>
__global__ __launch_bounds__(256) void k_gather(
    const unsigned short* __restrict__ xp,     // bf16 [NP,256]
    const unsigned short* __restrict__ alpha,  // bf16 [ETOT*H]
    const int* __restrict__ rowptr, const int* __restrict__ deg,
    const int* __restrict__ csr,
    const float* __restrict__ bias,            // f32 [256]
    const float* __restrict__ un,              // f32 [256*2] (next-layer u) or null
    unsigned short* __restrict__ ohi, unsigned short* __restrict__ olo,
    float* __restrict__ asn, float* __restrict__ adn) {
    int lane = threadIdx.x & 63;
    int node = blockIdx.x * 4 + (threadIdx.x >> 6);
    if (node >= N_NODES) return;
    int ptr = rowptr[node], dg = deg[node];
    int half = lane >> 5, l5 = lane & 31;
    int cbase = l5 * 8;
    int head = (H == 8) ? (l5 >> 2) : 0;
    float acc[8] = {0,0,0,0,0,0,0,0};
    int dge = (dg + 1) & ~1;
    int i = half;
    int ci = ptr + min(i, dg - 1);
    float a0 = (i < dg) ? b2f(alpha[(size_t)ci * H + head]) : 0.f;
    int sn0 = csr[ci];
    short8 v0 = *(const short8*)(xp + (size_t)sn0 * 256 + cbase);
    while (i < dge) {
        int in = i + 2;
        int cn = ptr + min(in, dg - 1);
        float a1 = (in < dg) ? b2f(alpha[(size_t)cn * H + head]) : 0.f;
        int sn1 = csr[cn];
        short8 v1 = *(const short8*)(xp + (size_t)sn1 * 256 + cbase);
        #pragma unroll
        for (int j = 0; j < 8; ++j) acc[j] += a0 * b2f((unsigned short)v0[j]);
        i = in; a0 = a1; v0 = v1;
    }
    #pragma unroll
    for (int j = 0; j < 8; ++j) acc[j] += __shfl_xor(acc[j], 32);
    if (half) return;
    // epilogue on lanes 0-31: bias + ELU, write hi/lo, fused next-layer logits
    float sN = 0.f, dN = 0.f;
    #pragma unroll
    for (int j = 0; j < 8; ++j) {
        int c = cbase + j;
        float v = acc[j] + bias[c];
        v = (v > 0.f) ? v : (__expf(v) - 1.f);   // ELU
        unsigned short hi = f2b(v);
        ohi[(size_t)node * 256 + c] = hi;
        olo[(size_t)node * 256 + c] = f2b(v - b2f(hi));
        if (FUSE) {
            sN += v * un[c * 2];
            dN += v * un[c * 2 + 1];
        }
    }
    if (FUSE) {
        #pragma unroll
        for (int off = 16; off > 0; off >>= 1) {
            sN += __shfl_xor(sN, off);
            dN += __shfl_xor(dN, off);
        }
        if (l5 == 0) { asn[node] = sN; adn[node] = dN; }
    }
}

// ---------- final gather: 64 padded bf16 ch, 4 edges/iter + log_softmax ----------
__global__ __launch_bounds__(256) void k_gf(
    const unsigned short* __restrict__ xp,     // bf16 [NP,64]
    const unsigned short* __restrict__ alpha,  // bf16 [ETOT]
    const int* __restrict__ rowptr, const int* __restrict__ deg,
    const int* __restrict__ csr,
    const float* __restrict__ bias,            // f32 [40]
    float* __restrict__ out) {                 // f32 [N,40]
    int lane = threadIdx.x & 63;
    int node = blockIdx.x * 4 + (threadIdx.x >> 6);
    if (node >= N_NODES) return;
    int ptr = rowptr[node], dg = deg[node];
    int g = lane >> 4, l4 = lane & 15;
    int cbase = l4 * 4;
    float acc[4] = {0,0,0,0};
    int dge = (dg + 3) & ~3;
    int i = g;
    int ci = ptr + min(i, dg - 1);
    float a0 = (i < dg) ? b2f(alpha[ci]) : 0.f;
    int sn0 = csr[ci];
    ushort4 v0 = *(const ushort4*)(xp + (size_t)sn0 * 64 + cbase);
    while (i < dge) {
        int in = i + 4;
        int cn = ptr + min(in, dg - 1);
        float a1 = (in < dg) ? b2f(alpha[cn]) : 0.f;
        int sn1 = csr[cn];
        ushort4 v1 = *(const ushort4*)(xp + (size_t)sn1 * 64 + cbase);
        acc[0] += a0 * b2f(v0.x);
        acc[1] += a0 * b2f(v0.y);
        acc[2] += a0 * b2f(v0.z);
        acc[3] += a0 * b2f(v0.w);
        i = in; a0 = a1; v0 = v1;
    }
    #pragma unroll
    for (int j = 0; j < 4; ++j) {
        acc[j] += __shfl_xor(acc[j], 16);
        acc[j] += __shfl_xor(acc[j], 32);
    }
    if (lane >= 16) return;
    float val[4], mx = -1e30f;
    #pragma unroll
    for (int j = 0; j < 4; ++j) {
        int c = cbase + j;
        val[j] = (c < 40) ? acc[j] + bias[c] : -1e30f;
        mx = fmaxf(mx, val[j]);
    }
    #pragma unroll
    for (int off = 8; off > 0; off >>= 1) mx = fmaxf(mx, __shfl_xor(mx, off));
    float ex = 0.f;
    #pragma unroll
    for (int j = 0; j < 4; ++j) {
        int c = cbase + j;
        if (c < 40) ex += __expf(val[j] - mx);
    }
    #pragma unroll
    for (int off = 8; off > 0; off >>= 1) ex += __shfl_xor(ex, off);
    float lse = __logf(ex);
    #pragma unroll
    for (int j = 0; j < 4; ++j) {
        int c = cbase + j;
        if (c < 40) out[(size_t)node * 40 + c] = val[j] - mx - lse;
    }
}

extern "C" void kernel_launch(void* const* d_in, const int* in_sizes, int n_in,
                              void* d_out, int out_size, void* d_ws, size_t ws_size,
                              hipStream_t stream) {
    const float* x   = (const float*)d_in[0];
    const int*   ei  = (const int*)d_in[1];
    const float* W0  = (const float*)d_in[2];
    const float* as0 = (const float*)d_in[3];
    const float* ad0 = (const float*)d_in[4];
    const float* b0  = (const float*)d_in[5];
    const float* W1  = (const float*)d_in[6];
    const float* as1 = (const float*)d_in[7];
    const float* ad1 = (const float*)d_in[8];
    const float* b1  = (const float*)d_in[9];
    const float* W2  = (const float*)d_in[10];
    const float* as2 = (const float*)d_in[11];
    const float* ad2 = (const float*)d_in[12];
    const float* b2  = (const float*)d_in[13];
    float* out = (float*)d_out;

    char* p = (char*)d_ws;
    auto carve = [&](size_t bytes) -> char* {
        char* r = p; p += (bytes + 255) & ~(size_t)255; return r;
    };
    unsigned short* xhi  = (unsigned short*)carve((size_t)NP * 256 * 2);
    unsigned short* xlo  = (unsigned short*)carve((size_t)NP * 256 * 2);
    unsigned short* hhi  = (unsigned short*)carve((size_t)NP * 256 * 2);
    unsigned short* hlo  = (unsigned short*)carve((size_t)NP * 256 * 2);
    unsigned short* xpb  = (unsigned short*)carve((size_t)NP * 256 * 2);
    unsigned short* xp2b = (unsigned short*)carve((size_t)NP * 64 * 2);
    unsigned short* Wt0h = (unsigned short*)carve(256 * 256 * 2);
    unsigned short* Wt0l = (unsigned short*)carve(256 * 256 * 2);
    unsigned short* Wt1h = (unsigned short*)carve(256 * 256 * 2);
    unsigned short* Wt1l = (unsigned short*)carve(256 * 256 * 2);
    unsigned short* Wt2h = (unsigned short*)carve(64 * 256 * 2);
    unsigned short* Wt2l = (unsigned short*)carve(64 * 256 * 2);
    float* u0 = (float*)carve(256 * 16 * 4);
    float* u1 = (float*)carve(256 * 2 * 4);
    float* u2 = (float*)carve(256 * 2 * 4);
    float* asrc0 = (float*)carve((size_t)N_NODES * 8 * 4);
    float* adst0 = (float*)carve((size_t)N_NODES * 8 * 4);
    float* asrc1 = (float*)carve((size_t)N_NODES * 4);
    float* adst1 = (float*)carve((size_t)N_NODES * 4);
    float* asrc2 = (float*)carve((size_t)N_NODES * 4);
    float* adst2 = (float*)carve((size_t)N_NODES * 4);
    int* deg    = (int*)carve((size_t)N_NODES * 4);
    int* rowptr = (int*)carve((size_t)N_NODES * 4);
    int* cursor = (int*)carve((size_t)N_NODES * 4);
    int* csr    = (int*)carve((size_t)ETOT * 4);
    unsigned short* alpha1 = (unsigned short*)carve((size_t)ETOT * 2);
    unsigned short* alpha2 = (unsigned short*)carve((size_t)ETOT * 2);
    // alpha0 (ETOT*8 bf16 = 26.4MB) overlays xhi+xlo: both are dead between
    // gemm0 (last read of x split) and k_gather<1> (writes h1 into xhi/xlo),
    // and alpha0's live range [k_alpha<8> .. k_gather<8>] sits inside that window.
    unsigned short* alpha0 = xhi;

    hipMemsetAsync(deg, 0, (size_t)N_NODES * 4, stream);

    k_tsplit<<<(256 * 256 + 255) / 256, 256, 0, stream>>>(W0, Wt0h, Wt0l, 256, 256);
    k_tsplit<<<(256 * 256 + 255) / 256, 256, 0, stream>>>(W1, Wt1h, Wt1l, 256, 256);
    k_tsplit<<<(256 * 40 + 255) / 256, 256, 0, stream>>>(W2, Wt2h, Wt2l, 256, 40);
    k_split<<<((N_NODES * 256) + 255) / 256, 256, 0, stream>>>(x, xhi, xlo, N_NODES * 256);

    k_mku<<<(256 * 16 + 255) / 256, 256, 0, stream>>>(W0, as0, ad0, u0, 256, 32, 8);
    k_mku<<<(256 * 2 + 255) / 256, 256, 0, stream>>>(W1, as1, ad1, u1, 256, 256, 1);
    k_mku<<<(256 * 2 + 255) / 256, 256, 0, stream>>>(W2, as2, ad2, u2, 256, 40, 1);

    k_count<<<(ETOT + 255) / 256, 256, 0, stream>>>(ei, deg);
    k_scan<<<1, 1024, 0, stream>>>(deg, rowptr, cursor);
    k_fill<<<(ETOT + 255) / 256, 256, 0, stream>>>(ei, cursor, csr);

    dim3 g0(NP / 64, 4);
    dim3 gn(N_NODES / 4);
    // layer 0
    k_gemm_s<<<g0, 256, 0, stream>>>(xhi, xlo, Wt0h, Wt0l, xpb, N_NODES, 256, 256);
    k_att0<16><<<gn, 256, 0, stream>>>(x, u0, asrc0, adst0);
    k_alpha<8><<<gn, 256, 0, stream>>>(asrc0, adst0, rowptr, deg, csr, alpha0);
    k_gather<8, true><<<gn, 256, 0, stream>>>(xpb, alpha0, rowptr, deg, csr, b0, u1,
                                              hhi, hlo, asrc1, adst1);
    // layer 1
    k_gemm_s<<<g0, 256, 0, stream>>>(hhi, hlo, Wt1h, Wt1l, xpb, N_NODES, 256, 256);
    k_alpha<1><<<gn, 256, 0, stream>>>(asrc1, adst1, rowptr, deg, csr, alpha1);
    k_gather<1, true><<<gn, 256, 0, stream>>>(xpb, alpha1, rowptr, deg, csr, b1, u2,
                                              xhi, xlo, asrc2, adst2);
    // layer 2
    dim3 g2(NP / 64, 1);
    k_gemm_s<<<g2, 256, 0, stream>>>(xhi, xlo, Wt2h, Wt2l, xp2b, N_NODES, 40, 64);
    k_alpha<1><<<gn, 256, 0, stream>>>(asrc2, adst2, rowptr, deg, csr, alpha2);
    k_gf<<<gn, 256, 0, stream>>>(xp2b, alpha2, rowptr, deg, csr, b2, out);
}

// Round 4
// 952.655 us; speedup vs baseline: 1.4500x; 1.2152x over previous
//
#include <hip/hip_runtime.h>
#include <hip/hip_bf16.h>

#define N_NODES 50000
#define N_EDGES 1600000
#define ETOT (N_EDGES + N_NODES)
#define NP 50048  // N padded for GEMM row tiles (391 * 128)

typedef __attribute__((ext_vector_type(8))) short short8;
typedef __attribute__((ext_vector_type(4))) float f32x4;

__device__ __forceinline__ float b2f(unsigned short u) {
    union { unsigned int i; float f; } v; v.i = ((unsigned int)u) << 16; return v.f;
}
__device__ __forceinline__ unsigned short f2b(float f) {
    union { float f; unsigned int i; } v; v.f = f;
    unsigned int r = v.i + 0x7FFF + ((v.i >> 16) & 1);  // RNE
    return (unsigned short)(r >> 16);
}

// ---------- weight transpose to bf16: W f32 [K,C] -> Wt bf16 [C,K] ----------
__global__ void k_tb(const float* __restrict__ W, unsigned short* __restrict__ Wt,
                     int K, int C) {
    int idx = blockIdx.x * 256 + threadIdx.x;
    if (idx >= K * C) return;
    int k = idx / C, c = idx - k * C;
    Wt[c * K + k] = f2b(W[idx]);
}

// ---------- attention projection vectors: u[k, j] = sum_c W[k, h*C+c] * att[h,c] ----------
__global__ void k_mku(const float* __restrict__ W, const float* __restrict__ attS,
                      const float* __restrict__ attD, float* __restrict__ u,
                      int K, int C, int H) {
    int idx = blockIdx.x * 256 + threadIdx.x;
    int NC = 2 * H;
    if (idx >= K * NC) return;
    int k = idx / NC, j = idx - k * NC;
    int h = (j < H) ? j : j - H;
    const float* av = ((j < H) ? attS : attD) + h * C;
    const float* wr = W + (size_t)k * (C * H) + h * C;
    float s = 0.f;
    for (int c = 0; c < C; ++c) s += wr[c] * av[c];
    u[idx] = s;
}

// ---------- CSR build ----------
__global__ void k_count(const int* __restrict__ ei, int* __restrict__ deg) {
    int e = blockIdx.x * 256 + threadIdx.x;
    if (e >= ETOT) return;
    int dst = (e < N_EDGES) ? ei[N_EDGES + e] : (e - N_EDGES);
    atomicAdd(&deg[dst], 1);
}

__global__ void k_scan(const int* __restrict__ deg, int* __restrict__ rowptr,
                       int* __restrict__ cursor) {
    __shared__ int part[1024];
    int t = threadIdx.x;
    const int CH = (N_NODES + 1023) / 1024;
    int start = t * CH, end = min(start + CH, N_NODES);
    int sum = 0;
    for (int i = start; i < end; ++i) sum += deg[i];
    part[t] = sum;
    __syncthreads();
    for (int off = 1; off < 1024; off <<= 1) {
        int v = (t >= off) ? part[t - off] : 0;
        __syncthreads();
        part[t] += v;
        __syncthreads();
    }
    int run = part[t] - sum;
    for (int i = start; i < end; ++i) {
        rowptr[i] = run; cursor[i] = run; run += deg[i];
    }
}

__global__ void k_fill(const int* __restrict__ ei, int* __restrict__ cursor,
                       int* __restrict__ csr) {
    int e = blockIdx.x * 256 + threadIdx.x;
    if (e >= ETOT) return;
    int src, dst;
    if (e < N_EDGES) { src = ei[e]; dst = ei[N_EDGES + e]; }
    else             { src = dst = e - N_EDGES; }
    int pos = atomicAdd(&cursor[dst], 1);
    csr[pos] = src;
}

// ---------- bf16 GEMM: A[nrows,256] x Bt[c,256] -> bf16 [NP,ldc]; 2 row-tiles/wave ----------
__global__ __launch_bounds__(256) void k_gemm_b(
    const unsigned short* __restrict__ A, const unsigned short* __restrict__ Bt,
    unsigned short* __restrict__ Cout, int nrows, int ncols, int ldc) {
    const int K = 256;
    int lane = threadIdx.x & 63;
    int wave = threadIdx.x >> 6;
    int row0 = blockIdx.x * 128 + wave * 32;
    int col0 = blockIdx.y * 64;
    int ar0 = row0 + (lane & 15); if (ar0 >= nrows) ar0 = nrows - 1;
    int ar1 = row0 + 16 + (lane & 15); if (ar1 >= nrows) ar1 = nrows - 1;
    int ks = (lane >> 4) * 8;
    const unsigned short* Ap0 = A + (size_t)ar0 * K + ks;
    const unsigned short* Ap1 = A + (size_t)ar1 * K + ks;
    f32x4 acc[2][4] = {{{0,0,0,0},{0,0,0,0},{0,0,0,0},{0,0,0,0}},
                       {{0,0,0,0},{0,0,0,0},{0,0,0,0},{0,0,0,0}}};
    for (int k = 0; k < K; k += 32) {
        short8 a0 = *(const short8*)(Ap0 + k);
        short8 a1 = *(const short8*)(Ap1 + k);
        #pragma unroll
        for (int ct = 0; ct < 4; ++ct) {
            short8 b = *(const short8*)(Bt + (size_t)(col0 + ct * 16 + (lane & 15)) * K + k + ks);
            acc[0][ct] = __builtin_amdgcn_mfma_f32_16x16x32_bf16(a0, b, acc[0][ct], 0, 0, 0);
            acc[1][ct] = __builtin_amdgcn_mfma_f32_16x16x32_bf16(a1, b, acc[1][ct], 0, 0, 0);
        }
    }
    int cb = lane & 15;
    #pragma unroll
    for (int rt = 0; rt < 2; ++rt) {
        int rbase = row0 + rt * 16 + (lane >> 4) * 4;
        #pragma unroll
        for (int ct = 0; ct < 4; ++ct) {
            int cc = col0 + ct * 16 + cb;
            #pragma unroll
            for (int j = 0; j < 4; ++j) {
                float v = (cc < ncols) ? acc[rt][ct][j] : 0.f;
                Cout[(size_t)(rbase + j) * ldc + cc] = f2b(v);
            }
        }
    }
}

// ---------- fused: x f32 -> xb bf16 + layer-0 attention logits ----------
template <int NC>
__global__ __launch_bounds__(256) void k_splitatt(
    const float* __restrict__ x, const float* __restrict__ u,
    unsigned short* __restrict__ xb,
    float* __restrict__ asrc, float* __restrict__ adst) {
    int lane = threadIdx.x & 63;
    int node = blockIdx.x * 4 + (threadIdx.x >> 6);
    if (node >= N_NODES) return;
    int k0 = lane * 4;
    float4 v = *(const float4*)(x + (size_t)node * 256 + k0);
    float xv[4] = {v.x, v.y, v.z, v.w};
    ushort4 w;
    w.x = f2b(v.x); w.y = f2b(v.y); w.z = f2b(v.z); w.w = f2b(v.w);
    *(ushort4*)(xb + (size_t)node * 256 + k0) = w;
    float acc[NC];
    #pragma unroll
    for (int j = 0; j < NC; ++j) acc[j] = 0.f;
    #pragma unroll
    for (int i = 0; i < 4; ++i)
        #pragma unroll
        for (int j = 0; j < NC; ++j)
            acc[j] += xv[i] * u[(size_t)(k0 + i) * NC + j];
    #pragma unroll
    for (int off = 32; off > 0; off >>= 1)
        #pragma unroll
        for (int j = 0; j < NC; ++j)
            acc[j] += __shfl_xor(acc[j], off);
    if (lane == 0) {
        const int H = NC / 2;
        #pragma unroll
        for (int h = 0; h < H; ++h) {
            asrc[(size_t)node * H + h] = acc[h];
            adst[(size_t)node * H + h] = acc[H + h];
        }
    }
}

// ---------- per-slot attention weights: alpha[slot*H+h] bf16 ----------
template <int H>
__global__ __launch_bounds__(256) void k_alpha(
    const float* __restrict__ asrc, const float* __restrict__ adst,
    const int* __restrict__ rowptr, const int* __restrict__ deg,
    const int* __restrict__ csr, unsigned short* __restrict__ alpha) {
    int lane = threadIdx.x & 63;
    int node = blockIdx.x * 4 + (threadIdx.x >> 6);
    if (node >= N_NODES) return;
    int ptr = rowptr[node], dg = deg[node];
    float adr[H], m[H], s[H];
    #pragma unroll
    for (int h = 0; h < H; ++h) { adr[h] = adst[node * H + h]; m[h] = -1e30f; s[h] = 0.f; }
    for (int i = lane; i < dg; i += 64) {
        int sn = csr[ptr + i];
        #pragma unroll
        for (int h = 0; h < H; ++h) {
            float e = asrc[sn * H + h] + adr[h];
            e = (e >= 0.f) ? e : 0.2f * e;
            float mn = fmaxf(m[h], e);
            s[h] = s[h] * __expf(m[h] - mn) + __expf(e - mn);
            m[h] = mn;
        }
    }
    #pragma unroll
    for (int off = 32; off > 0; off >>= 1) {
        #pragma unroll
        for (int h = 0; h < H; ++h) {
            float mo = __shfl_xor(m[h], off);
            float so = __shfl_xor(s[h], off);
            float mn = fmaxf(m[h], mo);
            s[h] = s[h] * __expf(m[h] - mn) + so * __expf(mo - mn);
            m[h] = mn;
        }
    }
    float inv[H];
    #pragma unroll
    for (int h = 0; h < H; ++h) inv[h] = 1.0f / s[h];
    for (int i = lane; i < dg; i += 64) {
        int sn = csr[ptr + i];
        #pragma unroll
        for (int h = 0; h < H; ++h) {
            float e = asrc[sn * H + h] + adr[h];
            e = (e >= 0.f) ? e : 0.2f * e;
            alpha[(size_t)(ptr + i) * H + h] = f2b(__expf(e - m[h]) * inv[h]);
        }
    }
}

// ---------- gather-aggregate 256ch: 2 edges/iter, depth-2 pipeline ----------
template <int H, bool FUSE>
__global__ __launch_bounds__(256) void k_gather(
    const unsigned short* __restrict__ xp,     // bf16 [NP,256]
    const unsigned short* __restrict__ alpha,  // bf16 [ETOT*H]
    const int* __restrict__ rowptr, const int* __restrict__ deg,
    const int* __restrict__ csr,
    const float* __restrict__ bias,            // f32 [256]
    const float* __restrict__ un,              // f32 [256*2] (next-layer u) or null
    unsigned short* __restrict__ o,            // bf16 [NP,256]
    float* __restrict__ asn, float* __restrict__ adn) {
    int lane = threadIdx.x & 63;
    int node = blockIdx.x * 4 + (threadIdx.x >> 6);
    if (node >= N_NODES) return;
    int ptr = rowptr[node], dg = deg[node];
    int half = lane >> 5, l5 = lane & 31;
    int cbase = l5 * 8;
    int head = (H == 8) ? (l5 >> 2) : 0;
    float acc[8] = {0,0,0,0,0,0,0,0};
    int dge = (dg + 1) & ~1;
    int i = half;
    int ci = ptr + min(i, dg - 1);
    float a0 = (i < dg) ? b2f(alpha[(size_t)ci * H + head]) : 0.f;
    int sn0 = csr[ci];
    short8 v0 = *(const short8*)(xp + (size_t)sn0 * 256 + cbase);
    while (i < dge) {
        int in = i + 2;
        int cn = ptr + min(in, dg - 1);
        float a1 = (in < dg) ? b2f(alpha[(size_t)cn * H + head]) : 0.f;
        int sn1 = csr[cn];
        short8 v1 = *(const short8*)(xp + (size_t)sn1 * 256 + cbase);
        #pragma unroll
        for (int j = 0; j < 8; ++j) acc[j] += a0 * b2f((unsigned short)v0[j]);
        i = in; a0 = a1; v0 = v1;
    }
    #pragma unroll
    for (int j = 0; j < 8; ++j) acc[j] += __shfl_xor(acc[j], 32);
    if (half) return;
    float sN = 0.f, dN = 0.f;
    #pragma unroll
    for (int j = 0; j < 8; ++j) {
        int c = cbase + j;
        float v = acc[j] + bias[c];
        v = (v > 0.f) ? v : (__expf(v) - 1.f);   // ELU
        o[(size_t)node * 256 + c] = f2b(v);
        if (FUSE) {
            sN += v * un[c * 2];
            dN += v * un[c * 2 + 1];
        }
    }
    if (FUSE) {
        #pragma unroll
        for (int off = 16; off > 0; off >>= 1) {
            sN += __shfl_xor(sN, off);
            dN += __shfl_xor(dN, off);
        }
        if (l5 == 0) { asn[node] = sN; adn[node] = dN; }
    }
}

// ---------- final gather: 64 padded bf16 ch, 4 edges/iter + log_softmax ----------
__global__ __launch_bounds__(256) void k_gf(
    const unsigned short* __restrict__ xp,     // bf16 [NP,64]
    const unsigned short* __restrict__ alpha,  // bf16 [ETOT]
    const int* __restrict__ rowptr, const int* __restrict__ deg,
    const int* __restrict__ csr,
    const float* __restrict__ bias,            // f32 [40]
    float* __restrict__ out) {                 // f32 [N,40]
    int lane = threadIdx.x & 63;
    int node = blockIdx.x * 4 + (threadIdx.x >> 6);
    if (node >= N_NODES) return;
    int ptr = rowptr[node], dg = deg[node];
    int g = lane >> 4, l4 = lane & 15;
    int cbase = l4 * 4;
    float acc[4] = {0,0,0,0};
    int dge = (dg + 3) & ~3;
    int i = g;
    int ci = ptr + min(i, dg - 1);
    float a0 = (i < dg) ? b2f(alpha[ci]) : 0.f;
    int sn0 = csr[ci];
    ushort4 v0 = *(const ushort4*)(xp + (size_t)sn0 * 64 + cbase);
    while (i < dge) {
        int in = i + 4;
        int cn = ptr + min(in, dg - 1);
        float a1 = (in < dg) ? b2f(alpha[cn]) : 0.f;
        int sn1 = csr[cn];
        ushort4 v1 = *(const ushort4*)(xp + (size_t)sn1 * 64 + cbase);
        acc[0] += a0 * b2f(v0.x);
        acc[1] += a0 * b2f(v0.y);
        acc[2] += a0 * b2f(v0.z);
        acc[3] += a0 * b2f(v0.w);
        i = in; a0 = a1; v0 = v1;
    }
    #pragma unroll
    for (int j = 0; j < 4; ++j) {
        acc[j] += __shfl_xor(acc[j], 16);
        acc[j] += __shfl_xor(acc[j], 32);
    }
    if (lane >= 16) return;
    float val[4], mx = -1e30f;
    #pragma unroll
    for (int j = 0; j < 4; ++j) {
        int c = cbase + j;
        val[j] = (c < 40) ? acc[j] + bias[c] : -1e30f;
        mx = fmaxf(mx, val[j]);
    }
    #pragma unroll
    for (int off = 8; off > 0; off >>= 1) mx = fmaxf(mx, __shfl_xor(mx, off));
    float ex = 0.f;
    #pragma unroll
    for (int j = 0; j < 4; ++j) {
        int c = cbase + j;
        if (c < 40) ex += __expf(val[j] - mx);
    }
    #pragma unroll
    for (int off = 8; off > 0; off >>= 1) ex += __shfl_xor(ex, off);
    float lse = __logf(ex);
    #pragma unroll
    for (int j = 0; j < 4; ++j) {
        int c = cbase + j;
        if (c < 40) out[(size_t)node * 40 + c] = val[j] - mx - lse;
    }
}

extern "C" void kernel_launch(void* const* d_in, const int* in_sizes, int n_in,
                              void* d_out, int out_size, void* d_ws, size_t ws_size,
                              hipStream_t stream) {
    const float* x   = (const float*)d_in[0];
    const int*   ei  = (const int*)d_in[1];
    const float* W0  = (const float*)d_in[2];
    const float* as0 = (const float*)d_in[3];
    const float* ad0 = (const float*)d_in[4];
    const float* b0  = (const float*)d_in[5];
    const float* W1  = (const float*)d_in[6];
    const float* as1 = (const float*)d_in[7];
    const float* ad1 = (const float*)d_in[8];
    const float* b1  = (const float*)d_in[9];
    const float* W2  = (const float*)d_in[10];
    const float* as2 = (const float*)d_in[11];
    const float* ad2 = (const float*)d_in[12];
    const float* b2  = (const float*)d_in[13];
    float* out = (float*)d_out;

    char* p = (char*)d_ws;
    auto carve = [&](size_t bytes) -> char* {
        char* r = p; p += (bytes + 255) & ~(size_t)255; return r;
    };
    unsigned short* xb   = (unsigned short*)carve((size_t)NP * 256 * 2);  // x bf16, later h2
    unsigned short* xpb  = (unsigned short*)carve((size_t)NP * 256 * 2);  // gemm out (messages)
    unsigned short* h    = (unsigned short*)carve((size_t)NP * 256 * 2);  // h1
    unsigned short* xp2b = (unsigned short*)carve((size_t)NP * 64 * 2);
    unsigned short* Wt0  = (unsigned short*)carve(256 * 256 * 2);
    unsigned short* Wt1  = (unsigned short*)carve(256 * 256 * 2);
    unsigned short* Wt2  = (unsigned short*)carve(64 * 256 * 2);
    float* u0 = (float*)carve(256 * 16 * 4);
    float* u1 = (float*)carve(256 * 2 * 4);
    float* u2 = (float*)carve(256 * 2 * 4);
    float* asrc0 = (float*)carve((size_t)N_NODES * 8 * 4);
    float* adst0 = (float*)carve((size_t)N_NODES * 8 * 4);
    float* asrc1 = (float*)carve((size_t)N_NODES * 4);
    float* adst1 = (float*)carve((size_t)N_NODES * 4);
    float* asrc2 = (float*)carve((size_t)N_NODES * 4);
    float* adst2 = (float*)carve((size_t)N_NODES * 4);
    int* deg    = (int*)carve((size_t)N_NODES * 4);
    int* rowptr = (int*)carve((size_t)N_NODES * 4);
    int* cursor = (int*)carve((size_t)N_NODES * 4);
    int* csr    = (int*)carve((size_t)ETOT * 4);
    unsigned short* alpha0 = (unsigned short*)carve((size_t)ETOT * 8 * 2);
    unsigned short* alpha1 = (unsigned short*)carve((size_t)ETOT * 2);
    unsigned short* alpha2 = (unsigned short*)carve((size_t)ETOT * 2);

    hipMemsetAsync(deg, 0, (size_t)N_NODES * 4, stream);
    hipMemsetAsync(Wt2, 0, 64 * 256 * 2, stream);  // zero pad cols 40..63

    k_tb<<<(256 * 256 + 255) / 256, 256, 0, stream>>>(W0, Wt0, 256, 256);
    k_tb<<<(256 * 256 + 255) / 256, 256, 0, stream>>>(W1, Wt1, 256, 256);
    k_tb<<<(256 * 40 + 255) / 256, 256, 0, stream>>>(W2, Wt2, 256, 40);

    k_mku<<<(256 * 16 + 255) / 256, 256, 0, stream>>>(W0, as0, ad0, u0, 256, 32, 8);
    k_mku<<<(256 * 2 + 255) / 256, 256, 0, stream>>>(W1, as1, ad1, u1, 256, 256, 1);
    k_mku<<<(256 * 2 + 255) / 256, 256, 0, stream>>>(W2, as2, ad2, u2, 256, 40, 1);

    k_count<<<(ETOT + 255) / 256, 256, 0, stream>>>(ei, deg);
    k_scan<<<1, 1024, 0, stream>>>(deg, rowptr, cursor);
    k_fill<<<(ETOT + 255) / 256, 256, 0, stream>>>(ei, cursor, csr);

    dim3 gg(NP / 128, 4);
    dim3 gn(N_NODES / 4);
    // layer 0
    k_splitatt<16><<<gn, 256, 0, stream>>>(x, u0, xb, asrc0, adst0);
    k_gemm_b<<<gg, 256, 0, stream>>>(xb, Wt0, xpb, N_NODES, 256, 256);
    k_alpha<8><<<gn, 256, 0, stream>>>(asrc0, adst0, rowptr, deg, csr, alpha0);
    k_gather<8, true><<<gn, 256, 0, stream>>>(xpb, alpha0, rowptr, deg, csr, b0, u1,
                                              h, asrc1, adst1);
    // layer 1
    k_gemm_b<<<gg, 256, 0, stream>>>(h, Wt1, xpb, N_NODES, 256, 256);
    k_alpha<1><<<gn, 256, 0, stream>>>(asrc1, adst1, rowptr, deg, csr, alpha1);
    k_gather<1, true><<<gn, 256, 0, stream>>>(xpb, alpha1, rowptr, deg, csr, b1, u2,
                                              xb, asrc2, adst2);
    // layer 2
    dim3 g2(NP / 128, 1);
    k_gemm_b<<<g2, 256, 0, stream>>>(xb, Wt2, xp2b, N_NODES, 40, 64);
    k_alpha<1><<<gn, 256, 0, stream>>>(asrc2, adst2, rowptr, deg, csr, alpha2);
    k_gf<<<gn, 256, 0, stream>>>(xp2b, alpha2, rowptr, deg, csr, b2, out);
}

// Round 5
// 752.871 us; speedup vs baseline: 1.8347x; 1.2654x over previous
//
#include <hip/hip_runtime.h>
#include <hip/hip_bf16.h>
#include <hip/hip_fp16.h>

#define N_NODES 50000
#define N_EDGES 1600000
#define ETOT (N_EDGES + N_NODES)
#define NP 50048   // N padded for GEMM row tiles (391 * 128)
#define NBUCK 196  // dst >> 8 buckets (50000/256)

typedef __attribute__((ext_vector_type(8))) short short8;
typedef __attribute__((ext_vector_type(4))) float f32x4;

__device__ __forceinline__ float b2f(unsigned short u) {
    union { unsigned int i; float f; } v; v.i = ((unsigned int)u) << 16; return v.f;
}
__device__ __forceinline__ unsigned short f2b(float f) {
    union { float f; unsigned int i; } v; v.f = f;
    unsigned int r = v.i + 0x7FFF + ((v.i >> 16) & 1);  // RNE
    return (unsigned short)(r >> 16);
}
__device__ __forceinline__ unsigned short f2h(float f) {
    __half h = __float2half(f); return *(unsigned short*)&h;
}
__device__ __forceinline__ float h2f(unsigned short u) {
    __half h = *(__half*)&u; return __half2float(h);
}

// ---------- weight transpose to bf16: W f32 [K,C] -> Wt bf16 [C,K] ----------
__global__ void k_tb(const float* __restrict__ W, unsigned short* __restrict__ Wt,
                     int K, int C) {
    int idx = blockIdx.x * 256 + threadIdx.x;
    if (idx >= K * C) return;
    int k = idx / C, c = idx - k * C;
    Wt[c * K + k] = f2b(W[idx]);
}

// ---------- attention projection vectors ----------
__global__ void k_mku(const float* __restrict__ W, const float* __restrict__ attS,
                      const float* __restrict__ attD, float* __restrict__ u,
                      int K, int C, int H) {
    int idx = blockIdx.x * 256 + threadIdx.x;
    int NC = 2 * H;
    if (idx >= K * NC) return;
    int k = idx / NC, j = idx - k * NC;
    int h = (j < H) ? j : j - H;
    const float* av = ((j < H) ? attS : attD) + h * C;
    const float* wr = W + (size_t)k * (C * H) + h * C;
    float s = 0.f;
    for (int c = 0; c < C; ++c) s += wr[c] * av[c];
    u[idx] = s;
}

// ---------- CSR build: bucketed, low write-amplification ----------
__global__ __launch_bounds__(256) void k_bcount(const int* __restrict__ ei,
                                                int* __restrict__ bcnt) {
    __shared__ int h[NBUCK];
    for (int i = threadIdx.x; i < NBUCK; i += 256) h[i] = 0;
    __syncthreads();
    int e0 = blockIdx.x * 4096, e1 = min(e0 + 4096, ETOT);
    for (int e = e0 + threadIdx.x; e < e1; e += 256) {
        int dst = (e < N_EDGES) ? ei[N_EDGES + e] : (e - N_EDGES);
        atomicAdd(&h[dst >> 8], 1);
    }
    __syncthreads();
    for (int i = threadIdx.x; i < NBUCK; i += 256)
        if (h[i]) atomicAdd(&bcnt[i], h[i]);
}

__global__ void k_bscan(const int* __restrict__ bcnt, int* __restrict__ bstart,
                        int* __restrict__ bcursor) {
    __shared__ int tmp[256];
    int t = threadIdx.x;
    int v = (t < NBUCK) ? bcnt[t] : 0;
    tmp[t] = v;
    __syncthreads();
    for (int off = 1; off < 256; off <<= 1) {
        int u = (t >= off) ? tmp[t - off] : 0;
        __syncthreads();
        tmp[t] += u;
        __syncthreads();
    }
    int ex = tmp[t] - v;
    if (t < NBUCK) { bstart[t] = ex; bcursor[t] = ex; }
    if (t == 0) bstart[NBUCK] = ETOT;
}

// LDS-binned scatter of packed (src<<8 | dst&255) into bucket-grouped staging
__global__ __launch_bounds__(256) void k_bscatter(const int* __restrict__ ei,
                                                  int* __restrict__ bcursor,
                                                  unsigned int* __restrict__ stage) {
    __shared__ int h[NBUCK], base[NBUCK], cur[NBUCK], gbase[NBUCK];
    __shared__ int tmp[256];
    __shared__ unsigned int buf[8192];
    int t = threadIdx.x;
    for (int i = t; i < NBUCK; i += 256) h[i] = 0;
    __syncthreads();
    int e0 = blockIdx.x * 8192, e1 = min(e0 + 8192, ETOT);
    for (int e = e0 + t; e < e1; e += 256) {
        int dst = (e < N_EDGES) ? ei[N_EDGES + e] : (e - N_EDGES);
        atomicAdd(&h[dst >> 8], 1);
    }
    __syncthreads();
    int v = (t < NBUCK) ? h[t] : 0;
    tmp[t] = v;
    __syncthreads();
    for (int off = 1; off < 256; off <<= 1) {
        int u = (t >= off) ? tmp[t - off] : 0;
        __syncthreads();
        tmp[t] += u;
        __syncthreads();
    }
    if (t < NBUCK) { base[t] = tmp[t] - v; cur[t] = tmp[t] - v; }
    __syncthreads();
    for (int e = e0 + t; e < e1; e += 256) {
        int src, dst;
        if (e < N_EDGES) { src = ei[e]; dst = ei[N_EDGES + e]; }
        else             { src = dst = e - N_EDGES; }
        int b = dst >> 8;
        int p = atomicAdd(&cur[b], 1);
        buf[p] = ((unsigned int)src << 8) | (unsigned int)(dst & 255);
    }
    __syncthreads();
    if (t < NBUCK) gbase[t] = atomicAdd(&bcursor[t], h[t]);
    __syncthreads();
    int cnt = e1 - e0;
    for (int i = t; i < cnt; i += 256) {
        unsigned int pr = buf[i];
        int b = ((pr & 255) | 0);  // need bucket: recover from position
        // bucket of this entry = bucket whose [base,base+h) contains i; instead store dst>>8 implicitly:
        // we packed only dst&255, so find bucket via base[]: entries are grouped, use binary search-free:
        b = pr & 255;  // placeholder, replaced below
        (void)b;
        break;
    }
    // flush: iterate buckets owned by threads to keep bucket id known
    for (int b = 0; b < NBUCK; ++b) {
        int lo = base[b], n = h[b];
        for (int i = t; i < n; i += 256)
            stage[gbase[b] + i] = buf[lo + i];
        // no syncthreads needed: disjoint work
    }
}

// per-bucket exact CSR: rowptr, deg, csr(ushort)
__global__ __launch_bounds__(256) void k_csr(const unsigned int* __restrict__ stage,
                                             const int* __restrict__ bstart,
                                             int* __restrict__ rowptr, int* __restrict__ deg,
                                             unsigned short* __restrict__ csr) {
    __shared__ int cnt[256], cur[256], tmp[256];
    int b = blockIdx.x;
    int t = threadIdx.x;
    cnt[t] = 0;
    __syncthreads();
    int s0 = bstart[b], s1 = bstart[b + 1];
    for (int i = s0 + t; i < s1; i += 256)
        atomicAdd(&cnt[stage[i] & 255], 1);
    __syncthreads();
    int v = cnt[t];
    tmp[t] = v;
    __syncthreads();
    for (int off = 1; off < 256; off <<= 1) {
        int u = (t >= off) ? tmp[t - off] : 0;
        __syncthreads();
        tmp[t] += u;
        __syncthreads();
    }
    int ex = tmp[t] - v;
    int node = b * 256 + t;
    if (node < N_NODES) { rowptr[node] = s0 + ex; deg[node] = v; }
    cur[t] = s0 + ex;
    __syncthreads();
    for (int i = s0 + t; i < s1; i += 256) {
        unsigned int pr = stage[i];
        int p = atomicAdd(&cur[pr & 255], 1);
        csr[p] = (unsigned short)(pr >> 8);
    }
}

// ---------- bf16 GEMM: A[nrows,256] x Bt[c,256] -> bf16 [NP,ldc]; 2 row-tiles/wave ----------
__global__ __launch_bounds__(256) void k_gemm_b(
    const unsigned short* __restrict__ A, const unsigned short* __restrict__ Bt,
    unsigned short* __restrict__ Cout, int nrows, int ncols, int ldc) {
    const int K = 256;
    int lane = threadIdx.x & 63;
    int wave = threadIdx.x >> 6;
    int row0 = blockIdx.x * 128 + wave * 32;
    int col0 = blockIdx.y * 64;
    int ar0 = row0 + (lane & 15); if (ar0 >= nrows) ar0 = nrows - 1;
    int ar1 = row0 + 16 + (lane & 15); if (ar1 >= nrows) ar1 = nrows - 1;
    int ks = (lane >> 4) * 8;
    const unsigned short* Ap0 = A + (size_t)ar0 * K + ks;
    const unsigned short* Ap1 = A + (size_t)ar1 * K + ks;
    f32x4 acc[2][4] = {{{0,0,0,0},{0,0,0,0},{0,0,0,0},{0,0,0,0}},
                       {{0,0,0,0},{0,0,0,0},{0,0,0,0},{0,0,0,0}}};
    for (int k = 0; k < K; k += 32) {
        short8 a0 = *(const short8*)(Ap0 + k);
        short8 a1 = *(const short8*)(Ap1 + k);
        #pragma unroll
        for (int ct = 0; ct < 4; ++ct) {
            short8 b = *(const short8*)(Bt + (size_t)(col0 + ct * 16 + (lane & 15)) * K + k + ks);
            acc[0][ct] = __builtin_amdgcn_mfma_f32_16x16x32_bf16(a0, b, acc[0][ct], 0, 0, 0);
            acc[1][ct] = __builtin_amdgcn_mfma_f32_16x16x32_bf16(a1, b, acc[1][ct], 0, 0, 0);
        }
    }
    int cb = lane & 15;
    #pragma unroll
    for (int rt = 0; rt < 2; ++rt) {
        int rbase = row0 + rt * 16 + (lane >> 4) * 4;
        #pragma unroll
        for (int ct = 0; ct < 4; ++ct) {
            int cc = col0 + ct * 16 + cb;
            #pragma unroll
            for (int j = 0; j < 4; ++j) {
                float v = (cc < ncols) ? acc[rt][ct][j] : 0.f;
                Cout[(size_t)(rbase + j) * ldc + cc] = f2b(v);
            }
        }
    }
}

// ---------- fused: x f32 -> xb bf16 + layer-0 attention logits ----------
template <int NC>
__global__ __launch_bounds__(256) void k_splitatt(
    const float* __restrict__ x, const float* __restrict__ u,
    unsigned short* __restrict__ xb,
    float* __restrict__ asrc, float* __restrict__ adst) {
    int lane = threadIdx.x & 63;
    int node = blockIdx.x * 4 + (threadIdx.x >> 6);
    if (node >= N_NODES) return;
    int k0 = lane * 4;
    float4 v = *(const float4*)(x + (size_t)node * 256 + k0);
    float xv[4] = {v.x, v.y, v.z, v.w};
    ushort4 w;
    w.x = f2b(v.x); w.y = f2b(v.y); w.z = f2b(v.z); w.w = f2b(v.w);
    *(ushort4*)(xb + (size_t)node * 256 + k0) = w;
    float acc[NC];
    #pragma unroll
    for (int j = 0; j < NC; ++j) acc[j] = 0.f;
    #pragma unroll
    for (int i = 0; i < 4; ++i)
        #pragma unroll
        for (int j = 0; j < NC; ++j)
            acc[j] += xv[i] * u[(size_t)(k0 + i) * NC + j];
    #pragma unroll
    for (int off = 32; off > 0; off >>= 1)
        #pragma unroll
        for (int j = 0; j < NC; ++j)
            acc[j] += __shfl_xor(acc[j], off);
    if (lane == 0) {
        const int H = NC / 2;
        #pragma unroll
        for (int h = 0; h < H; ++h) {
            asrc[(size_t)node * H + h] = acc[h];
            adst[(size_t)node * H + h] = acc[H + h];
        }
    }
}

// ---------- per-slot attention weights, fp16; single random-gather pass ----------
template <int H>
__global__ __launch_bounds__(256) void k_alpha(
    const float* __restrict__ asrc, const float* __restrict__ adst,
    const int* __restrict__ rowptr, const int* __restrict__ deg,
    const unsigned short* __restrict__ csr, unsigned short* __restrict__ alpha) {
    int lane = threadIdx.x & 63;
    int node = blockIdx.x * 4 + (threadIdx.x >> 6);
    if (node >= N_NODES) return;
    int ptr = rowptr[node], dg = deg[node];
    float adr[H], m[H], s[H];
    #pragma unroll
    for (int h = 0; h < H; ++h) { adr[h] = adst[node * H + h]; m[h] = -1e30f; s[h] = 0.f; }
    // pass 1: gather logits once, store e (fp16) into alpha buffer, online (m,s)
    for (int i = lane; i < dg; i += 64) {
        int sn = csr[ptr + i];
        #pragma unroll
        for (int h = 0; h < H; ++h) {
            float e = asrc[sn * H + h] + adr[h];
            e = (e >= 0.f) ? e : 0.2f * e;
            unsigned short eh = f2h(e);
            alpha[(size_t)(ptr + i) * H + h] = eh;
            float er = h2f(eh);
            float mn = fmaxf(m[h], er);
            s[h] = s[h] * __expf(m[h] - mn) + __expf(er - mn);
            m[h] = mn;
        }
    }
    #pragma unroll
    for (int off = 32; off > 0; off >>= 1) {
        #pragma unroll
        for (int h = 0; h < H; ++h) {
            float mo = __shfl_xor(m[h], off);
            float so = __shfl_xor(s[h], off);
            float mn = fmaxf(m[h], mo);
            s[h] = s[h] * __expf(m[h] - mn) + so * __expf(mo - mn);
            m[h] = mn;
        }
    }
    float inv[H];
    #pragma unroll
    for (int h = 0; h < H; ++h) inv[h] = 1.0f / s[h];
    // pass 2: contiguous re-read of e, overwrite with alpha
    for (int i = lane; i < dg; i += 64) {
        #pragma unroll
        for (int h = 0; h < H; ++h) {
            float er = h2f(alpha[(size_t)(ptr + i) * H + h]);
            alpha[(size_t)(ptr + i) * H + h] = f2h(__expf(er - m[h]) * inv[h]);
        }
    }
}

// ---------- gather-aggregate 256ch: 2 edges/iter, depth-2 pipeline ----------
template <int H, bool FUSE>
__global__ __launch_bounds__(256) void k_gather(
    const unsigned short* __restrict__ xp,     // bf16 [NP,256]
    const unsigned short* __restrict__ alpha,  // fp16 [ETOT*H]
    const int* __restrict__ rowptr, const int* __restrict__ deg,
    const unsigned short* __restrict__ csr,
    const float* __restrict__ bias,            // f32 [256]
    const float* __restrict__ un,              // f32 [256*2] (next-layer u) or null
    unsigned short* __restrict__ o,            // bf16 [NP,256]
    float* __restrict__ asn, float* __restrict__ adn) {
    int lane = threadIdx.x & 63;
    int node = blockIdx.x * 4 + (threadIdx.x >> 6);
    if (node >= N_NODES) return;
    int ptr = rowptr[node], dg = deg[node];
    int half = lane >> 5, l5 = lane & 31;
    int cbase = l5 * 8;
    int head = (H == 8) ? (l5 >> 2) : 0;
    float acc[8] = {0,0,0,0,0,0,0,0};
    int dge = (dg + 1) & ~1;
    int i = half;
    int ci = ptr + min(i, dg - 1);
    float a0 = (i < dg) ? h2f(alpha[(size_t)ci * H + head]) : 0.f;
    int sn0 = csr[ci];
    short8 v0 = *(const short8*)(xp + (size_t)sn0 * 256 + cbase);
    while (i < dge) {
        int in = i + 2;
        int cn = ptr + min(in, dg - 1);
        float a1 = (in < dg) ? h2f(alpha[(size_t)cn * H + head]) : 0.f;
        int sn1 = csr[cn];
        short8 v1 = *(const short8*)(xp + (size_t)sn1 * 256 + cbase);
        #pragma unroll
        for (int j = 0; j < 8; ++j) acc[j] += a0 * b2f((unsigned short)v0[j]);
        i = in; a0 = a1; v0 = v1;
    }
    #pragma unroll
    for (int j = 0; j < 8; ++j) acc[j] += __shfl_xor(acc[j], 32);
    if (half) return;
    float sN = 0.f, dN = 0.f;
    #pragma unroll
    for (int j = 0; j < 8; ++j) {
        int c = cbase + j;
        float v = acc[j] + bias[c];
        v = (v > 0.f) ? v : (__expf(v) - 1.f);   // ELU
        o[(size_t)node * 256 + c] = f2b(v);
        if (FUSE) {
            sN += v * un[c * 2];
            dN += v * un[c * 2 + 1];
        }
    }
    if (FUSE) {
        #pragma unroll
        for (int off = 16; off > 0; off >>= 1) {
            sN += __shfl_xor(sN, off);
            dN += __shfl_xor(dN, off);
        }
        if (l5 == 0) { asn[node] = sN; adn[node] = dN; }
    }
}

// ---------- final gather: 64 padded bf16 ch, 4 edges/iter + log_softmax ----------
__global__ __launch_bounds__(256) void k_gf(
    const unsigned short* __restrict__ xp,     // bf16 [NP,64]
    const unsigned short* __restrict__ alpha,  // fp16 [ETOT]
    const int* __restrict__ rowptr, const int* __restrict__ deg,
    const unsigned short* __restrict__ csr,
    const float* __restrict__ bias,            // f32 [40]
    float* __restrict__ out) {                 // f32 [N,40]
    int lane = threadIdx.x & 63;
    int node = blockIdx.x * 4 + (threadIdx.x >> 6);
    if (node >= N_NODES) return;
    int ptr = rowptr[node], dg = deg[node];
    int g = lane >> 4, l4 = lane & 15;
    int cbase = l4 * 4;
    float acc[4] = {0,0,0,0};
    int dge = (dg + 3) & ~3;
    int i = g;
    int ci = ptr + min(i, dg - 1);
    float a0 = (i < dg) ? h2f(alpha[ci]) : 0.f;
    int sn0 = csr[ci];
    ushort4 v0 = *(const ushort4*)(xp + (size_t)sn0 * 64 + cbase);
    while (i < dge) {
        int in = i + 4;
        int cn = ptr + min(in, dg - 1);
        float a1 = (in < dg) ? h2f(alpha[cn]) : 0.f;
        int sn1 = csr[cn];
        ushort4 v1 = *(const ushort4*)(xp + (size_t)sn1 * 64 + cbase);
        acc[0] += a0 * b2f(v0.x);
        acc[1] += a0 * b2f(v0.y);
        acc[2] += a0 * b2f(v0.z);
        acc[3] += a0 * b2f(v0.w);
        i = in; a0 = a1; v0 = v1;
    }
    #pragma unroll
    for (int j = 0; j < 4; ++j) {
        acc[j] += __shfl_xor(acc[j], 16);
        acc[j] += __shfl_xor(acc[j], 32);
    }
    if (lane >= 16) return;
    float val[4], mx = -1e30f;
    #pragma unroll
    for (int j = 0; j < 4; ++j) {
        int c = cbase + j;
        val[j] = (c < 40) ? acc[j] + bias[c] : -1e30f;
        mx = fmaxf(mx, val[j]);
    }
    #pragma unroll
    for (int off = 8; off > 0; off >>= 1) mx = fmaxf(mx, __shfl_xor(mx, off));
    float ex = 0.f;
    #pragma unroll
    for (int j = 0; j < 4; ++j) {
        int c = cbase + j;
        if (c < 40) ex += __expf(val[j] - mx);
    }
    #pragma unroll
    for (int off = 8; off > 0; off >>= 1) ex += __shfl_xor(ex, off);
    float lse = __logf(ex);
    #pragma unroll
    for (int j = 0; j < 4; ++j) {
        int c = cbase + j;
        if (c < 40) out[(size_t)node * 40 + c] = val[j] - mx - lse;
    }
}

extern "C" void kernel_launch(void* const* d_in, const int* in_sizes, int n_in,
                              void* d_out, int out_size, void* d_ws, size_t ws_size,
                              hipStream_t stream) {
    const float* x   = (const float*)d_in[0];
    const int*   ei  = (const int*)d_in[1];
    const float* W0  = (const float*)d_in[2];
    const float* as0 = (const float*)d_in[3];
    const float* ad0 = (const float*)d_in[4];
    const float* b0  = (const float*)d_in[5];
    const float* W1  = (const float*)d_in[6];
    const float* as1 = (const float*)d_in[7];
    const float* ad1 = (const float*)d_in[8];
    const float* b1  = (const float*)d_in[9];
    const float* W2  = (const float*)d_in[10];
    const float* as2 = (const float*)d_in[11];
    const float* ad2 = (const float*)d_in[12];
    const float* b2  = (const float*)d_in[13];
    float* out = (float*)d_out;

    char* p = (char*)d_ws;
    auto carve = [&](size_t bytes) -> char* {
        char* r = p; p += (bytes + 255) & ~(size_t)255; return r;
    };
    unsigned short* xb   = (unsigned short*)carve((size_t)NP * 256 * 2);  // x bf16, later h2
    unsigned short* xpb  = (unsigned short*)carve((size_t)NP * 256 * 2);  // gemm out (messages)
    unsigned short* h    = (unsigned short*)carve((size_t)NP * 256 * 2);  // h1
    unsigned short* xp2b = (unsigned short*)carve((size_t)NP * 64 * 2);
    unsigned short* Wt0  = (unsigned short*)carve(256 * 256 * 2);
    unsigned short* Wt1  = (unsigned short*)carve(256 * 256 * 2);
    unsigned short* Wt2  = (unsigned short*)carve(64 * 256 * 2);
    float* u0 = (float*)carve(256 * 16 * 4);
    float* u1 = (float*)carve(256 * 2 * 4);
    float* u2 = (float*)carve(256 * 2 * 4);
    float* asrc0 = (float*)carve((size_t)N_NODES * 8 * 4);
    float* adst0 = (float*)carve((size_t)N_NODES * 8 * 4);
    float* asrc1 = (float*)carve((size_t)N_NODES * 4);
    float* adst1 = (float*)carve((size_t)N_NODES * 4);
    float* asrc2 = (float*)carve((size_t)N_NODES * 4);
    float* adst2 = (float*)carve((size_t)N_NODES * 4);
    int* deg    = (int*)carve((size_t)N_NODES * 4);
    int* rowptr = (int*)carve((size_t)N_NODES * 4);
    int* bcnt   = (int*)carve((size_t)NBUCK * 4);
    int* bstart = (int*)carve((size_t)(NBUCK + 1) * 4);
    int* bcursor= (int*)carve((size_t)NBUCK * 4);
    unsigned int* stage = (unsigned int*)carve((size_t)ETOT * 4);
    unsigned short* csr = (unsigned short*)carve((size_t)ETOT * 2);
    unsigned short* alpha0 = (unsigned short*)carve((size_t)ETOT * 8 * 2);
    unsigned short* alpha1 = (unsigned short*)carve((size_t)ETOT * 2);
    unsigned short* alpha2 = (unsigned short*)carve((size_t)ETOT * 2);

    hipMemsetAsync(bcnt, 0, (size_t)NBUCK * 4, stream);
    hipMemsetAsync(Wt2, 0, 64 * 256 * 2, stream);  // zero pad cols 40..63

    k_tb<<<(256 * 256 + 255) / 256, 256, 0, stream>>>(W0, Wt0, 256, 256);
    k_tb<<<(256 * 256 + 255) / 256, 256, 0, stream>>>(W1, Wt1, 256, 256);
    k_tb<<<(256 * 40 + 255) / 256, 256, 0, stream>>>(W2, Wt2, 256, 40);

    k_mku<<<(256 * 16 + 255) / 256, 256, 0, stream>>>(W0, as0, ad0, u0, 256, 32, 8);
    k_mku<<<(256 * 2 + 255) / 256, 256, 0, stream>>>(W1, as1, ad1, u1, 256, 256, 1);
    k_mku<<<(256 * 2 + 255) / 256, 256, 0, stream>>>(W2, as2, ad2, u2, 256, 40, 1);

    k_bcount<<<(ETOT + 4095) / 4096, 256, 0, stream>>>(ei, bcnt);
    k_bscan<<<1, 256, 0, stream>>>(bcnt, bstart, bcursor);
    k_bscatter<<<(ETOT + 8191) / 8192, 256, 0, stream>>>(ei, bcursor, stage);
    k_csr<<<NBUCK, 256, 0, stream>>>(stage, bstart, rowptr, deg, csr);

    dim3 gg(NP / 128, 4);
    dim3 gn(N_NODES / 4);
    // layer 0
    k_splitatt<16><<<gn, 256, 0, stream>>>(x, u0, xb, asrc0, adst0);
    k_gemm_b<<<gg, 256, 0, stream>>>(xb, Wt0, xpb, N_NODES, 256, 256);
    k_alpha<8><<<gn, 256, 0, stream>>>(asrc0, adst0, rowptr, deg, csr, alpha0);
    k_gather<8, true><<<gn, 256, 0, stream>>>(xpb, alpha0, rowptr, deg, csr, b0, u1,
                                              h, asrc1, adst1);
    // layer 1
    k_gemm_b<<<gg, 256, 0, stream>>>(h, Wt1, xpb, N_NODES, 256, 256);
    k_alpha<1><<<gn, 256, 0, stream>>>(asrc1, adst1, rowptr, deg, csr, alpha1);
    k_gather<1, true><<<gn, 256, 0, stream>>>(xpb, alpha1, rowptr, deg, csr, b1, u2,
                                              xb, asrc2, adst2);
    // layer 2
    dim3 g2(NP / 128, 1);
    k_gemm_b<<<g2, 256, 0, stream>>>(xb, Wt2, xp2b, N_NODES, 40, 64);
    k_alpha<1><<<gn, 256, 0, stream>>>(asrc2, adst2, rowptr, deg, csr, alpha2);
    k_gf<<<gn, 256, 0, stream>>>(xp2b, alpha2, rowptr, deg, csr, b2, out);
}

// Round 6
// 722.041 us; speedup vs baseline: 1.9131x; 1.0427x over previous
//
#include <hip/hip_runtime.h>
#include <hip/hip_bf16.h>
#include <hip/hip_fp16.h>

#define N_NODES 50000
#define N_EDGES 1600000
#define ETOT (N_EDGES + N_NODES)
#define NP 50048   // N padded for GEMM row tiles (391 * 128)
#define NBUCK 196  // dst >> 8 buckets (50000/256)

typedef __attribute__((ext_vector_type(8))) short short8;
typedef __attribute__((ext_vector_type(4))) float f32x4;

__device__ __forceinline__ float b2f(unsigned short u) {
    union { unsigned int i; float f; } v; v.i = ((unsigned int)u) << 16; return v.f;
}
__device__ __forceinline__ unsigned short f2b(float f) {
    union { float f; unsigned int i; } v; v.f = f;
    unsigned int r = v.i + 0x7FFF + ((v.i >> 16) & 1);  // RNE
    return (unsigned short)(r >> 16);
}

// ---------- weight transpose to bf16: W f32 [K,C] -> Wt bf16 [C,K] ----------
__global__ void k_tb(const float* __restrict__ W, unsigned short* __restrict__ Wt,
                     int K, int C) {
    int idx = blockIdx.x * 256 + threadIdx.x;
    if (idx >= K * C) return;
    int k = idx / C, c = idx - k * C;
    Wt[c * K + k] = f2b(W[idx]);
}

// ---------- attention projection vectors ----------
__global__ void k_mku(const float* __restrict__ W, const float* __restrict__ attS,
                      const float* __restrict__ attD, float* __restrict__ u,
                      int K, int C, int H) {
    int idx = blockIdx.x * 256 + threadIdx.x;
    int NC = 2 * H;
    if (idx >= K * NC) return;
    int k = idx / NC, j = idx - k * NC;
    int h = (j < H) ? j : j - H;
    const float* av = ((j < H) ? attS : attD) + h * C;
    const float* wr = W + (size_t)k * (C * H) + h * C;
    float s = 0.f;
    for (int c = 0; c < C; ++c) s += wr[c] * av[c];
    u[idx] = s;
}

// ---------- CSR build: bucketed, low write-amplification ----------
__global__ __launch_bounds__(256) void k_bcount(const int* __restrict__ ei,
                                                int* __restrict__ bcnt) {
    __shared__ int h[NBUCK];
    for (int i = threadIdx.x; i < NBUCK; i += 256) h[i] = 0;
    __syncthreads();
    int e0 = blockIdx.x * 4096, e1 = min(e0 + 4096, ETOT);
    for (int e = e0 + threadIdx.x; e < e1; e += 256) {
        int dst = (e < N_EDGES) ? ei[N_EDGES + e] : (e - N_EDGES);
        atomicAdd(&h[dst >> 8], 1);
    }
    __syncthreads();
    for (int i = threadIdx.x; i < NBUCK; i += 256)
        if (h[i]) atomicAdd(&bcnt[i], h[i]);
}

__global__ void k_bscan(const int* __restrict__ bcnt, int* __restrict__ bstart,
                        int* __restrict__ bcursor) {
    __shared__ int tmp[256];
    int t = threadIdx.x;
    int v = (t < NBUCK) ? bcnt[t] : 0;
    tmp[t] = v;
    __syncthreads();
    for (int off = 1; off < 256; off <<= 1) {
        int u = (t >= off) ? tmp[t - off] : 0;
        __syncthreads();
        tmp[t] += u;
        __syncthreads();
    }
    int ex = tmp[t] - v;
    if (t < NBUCK) { bstart[t] = ex; bcursor[t] = ex; }
    if (t == 0) bstart[NBUCK] = ETOT;
}

// LDS-binned scatter of packed (bucket<<24 | src<<8 | dst&255) into bucket-grouped staging
__global__ __launch_bounds__(256) void k_bscatter(const int* __restrict__ ei,
                                                  int* __restrict__ bcursor,
                                                  unsigned int* __restrict__ stage) {
    __shared__ int h[NBUCK], base[NBUCK], cur[NBUCK], gbase[NBUCK];
    __shared__ int tmp[256];
    __shared__ unsigned int buf[8192];
    int t = threadIdx.x;
    for (int i = t; i < NBUCK; i += 256) h[i] = 0;
    __syncthreads();
    int e0 = blockIdx.x * 8192, e1 = min(e0 + 8192, ETOT);
    for (int e = e0 + t; e < e1; e += 256) {
        int dst = (e < N_EDGES) ? ei[N_EDGES + e] : (e - N_EDGES);
        atomicAdd(&h[dst >> 8], 1);
    }
    __syncthreads();
    int v = (t < NBUCK) ? h[t] : 0;
    tmp[t] = v;
    __syncthreads();
    for (int off = 1; off < 256; off <<= 1) {
        int u = (t >= off) ? tmp[t - off] : 0;
        __syncthreads();
        tmp[t] += u;
        __syncthreads();
    }
    if (t < NBUCK) { base[t] = tmp[t] - v; cur[t] = tmp[t] - v; }
    __syncthreads();
    for (int e = e0 + t; e < e1; e += 256) {
        int src, dst;
        if (e < N_EDGES) { src = ei[e]; dst = ei[N_EDGES + e]; }
        else             { src = dst = e - N_EDGES; }
        int b = dst >> 8;
        int p = atomicAdd(&cur[b], 1);
        buf[p] = ((unsigned int)b << 24) | ((unsigned int)src << 8) | (unsigned int)(dst & 255);
    }
    __syncthreads();
    if (t < NBUCK) gbase[t] = atomicAdd(&bcursor[t], h[t]);
    __syncthreads();
    int cnt = e1 - e0;
    for (int i = t; i < cnt; i += 256) {
        unsigned int pr = buf[i];
        int b = pr >> 24;
        stage[gbase[b] + (i - base[b])] = pr;
    }
}

// per-bucket exact CSR: rowptr, deg, csr(ushort)
__global__ __launch_bounds__(256) void k_csr(const unsigned int* __restrict__ stage,
                                             const int* __restrict__ bstart,
                                             int* __restrict__ rowptr, int* __restrict__ deg,
                                             unsigned short* __restrict__ csr) {
    __shared__ int cnt[256], cur[256], tmp[256];
    int b = blockIdx.x;
    int t = threadIdx.x;
    cnt[t] = 0;
    __syncthreads();
    int s0 = bstart[b], s1 = bstart[b + 1];
    for (int i = s0 + t; i < s1; i += 256)
        atomicAdd(&cnt[stage[i] & 255], 1);
    __syncthreads();
    int v = cnt[t];
    tmp[t] = v;
    __syncthreads();
    for (int off = 1; off < 256; off <<= 1) {
        int u = (t >= off) ? tmp[t - off] : 0;
        __syncthreads();
        tmp[t] += u;
        __syncthreads();
    }
    int ex = tmp[t] - v;
    int node = b * 256 + t;
    if (node < N_NODES) { rowptr[node] = s0 + ex; deg[node] = v; }
    cur[t] = s0 + ex;
    __syncthreads();
    for (int i = s0 + t; i < s1; i += 256) {
        unsigned int pr = stage[i];
        int p = atomicAdd(&cur[pr & 255], 1);
        csr[p] = (unsigned short)((pr >> 8) & 0xFFFF);
    }
}

// ---------- wide bf16 GEMM: A[nrows,256] x Bt[c,256] -> bf16; 32rows x 128cols per wave ----------
__global__ __launch_bounds__(256) void k_gemm_w(
    const unsigned short* __restrict__ A, const unsigned short* __restrict__ Bt,
    unsigned short* __restrict__ Cout, int nrows, int ncols, int ldc) {
    const int K = 256;
    int lane = threadIdx.x & 63;
    int wave = threadIdx.x >> 6;
    int row0 = blockIdx.x * 128 + wave * 32;
    int col0 = blockIdx.y * 128;
    int ar0 = row0 + (lane & 15); if (ar0 >= nrows) ar0 = nrows - 1;
    int ar1 = row0 + 16 + (lane & 15); if (ar1 >= nrows) ar1 = nrows - 1;
    int ks = (lane >> 4) * 8;
    const unsigned short* Ap0 = A + (size_t)ar0 * K + ks;
    const unsigned short* Ap1 = A + (size_t)ar1 * K + ks;
    f32x4 acc[2][8];
    #pragma unroll
    for (int rt = 0; rt < 2; ++rt)
        #pragma unroll
        for (int ct = 0; ct < 8; ++ct) acc[rt][ct] = {0, 0, 0, 0};
    for (int k = 0; k < K; k += 32) {
        short8 a0 = *(const short8*)(Ap0 + k);
        short8 a1 = *(const short8*)(Ap1 + k);
        #pragma unroll
        for (int ct = 0; ct < 8; ++ct) {
            short8 b = *(const short8*)(Bt + (size_t)(col0 + ct * 16 + (lane & 15)) * K + k + ks);
            acc[0][ct] = __builtin_amdgcn_mfma_f32_16x16x32_bf16(a0, b, acc[0][ct], 0, 0, 0);
            acc[1][ct] = __builtin_amdgcn_mfma_f32_16x16x32_bf16(a1, b, acc[1][ct], 0, 0, 0);
        }
    }
    int cb = lane & 15;
    #pragma unroll
    for (int rt = 0; rt < 2; ++rt) {
        int rbase = row0 + rt * 16 + (lane >> 4) * 4;
        #pragma unroll
        for (int ct = 0; ct < 8; ++ct) {
            int cc = col0 + ct * 16 + cb;
            #pragma unroll
            for (int j = 0; j < 4; ++j) {
                float v = (cc < ncols) ? acc[rt][ct][j] : 0.f;
                Cout[(size_t)(rbase + j) * ldc + cc] = f2b(v);
            }
        }
    }
}

// ---------- narrow bf16 GEMM (64 cols) for layer 2 ----------
__global__ __launch_bounds__(256) void k_gemm_b(
    const unsigned short* __restrict__ A, const unsigned short* __restrict__ Bt,
    unsigned short* __restrict__ Cout, int nrows, int ncols, int ldc) {
    const int K = 256;
    int lane = threadIdx.x & 63;
    int wave = threadIdx.x >> 6;
    int row0 = blockIdx.x * 128 + wave * 32;
    int col0 = 0;
    int ar0 = row0 + (lane & 15); if (ar0 >= nrows) ar0 = nrows - 1;
    int ar1 = row0 + 16 + (lane & 15); if (ar1 >= nrows) ar1 = nrows - 1;
    int ks = (lane >> 4) * 8;
    const unsigned short* Ap0 = A + (size_t)ar0 * K + ks;
    const unsigned short* Ap1 = A + (size_t)ar1 * K + ks;
    f32x4 acc[2][4] = {{{0,0,0,0},{0,0,0,0},{0,0,0,0},{0,0,0,0}},
                       {{0,0,0,0},{0,0,0,0},{0,0,0,0},{0,0,0,0}}};
    for (int k = 0; k < K; k += 32) {
        short8 a0 = *(const short8*)(Ap0 + k);
        short8 a1 = *(const short8*)(Ap1 + k);
        #pragma unroll
        for (int ct = 0; ct < 4; ++ct) {
            short8 b = *(const short8*)(Bt + (size_t)(col0 + ct * 16 + (lane & 15)) * K + k + ks);
            acc[0][ct] = __builtin_amdgcn_mfma_f32_16x16x32_bf16(a0, b, acc[0][ct], 0, 0, 0);
            acc[1][ct] = __builtin_amdgcn_mfma_f32_16x16x32_bf16(a1, b, acc[1][ct], 0, 0, 0);
        }
    }
    int cb = lane & 15;
    #pragma unroll
    for (int rt = 0; rt < 2; ++rt) {
        int rbase = row0 + rt * 16 + (lane >> 4) * 4;
        #pragma unroll
        for (int ct = 0; ct < 4; ++ct) {
            int cc = col0 + ct * 16 + cb;
            #pragma unroll
            for (int j = 0; j < 4; ++j) {
                float v = (cc < ncols) ? acc[rt][ct][j] : 0.f;
                Cout[(size_t)(rbase + j) * ldc + cc] = f2b(v);
            }
        }
    }
}

// ---------- fused: x f32 -> xb bf16 + layer-0 attention logits ----------
template <int NC>
__global__ __launch_bounds__(256) void k_splitatt(
    const float* __restrict__ x, const float* __restrict__ u,
    unsigned short* __restrict__ xb,
    float* __restrict__ asrc, float* __restrict__ adst) {
    int lane = threadIdx.x & 63;
    int node = blockIdx.x * 4 + (threadIdx.x >> 6);
    if (node >= N_NODES) return;
    int k0 = lane * 4;
    float4 v = *(const float4*)(x + (size_t)node * 256 + k0);
    float xv[4] = {v.x, v.y, v.z, v.w};
    ushort4 w;
    w.x = f2b(v.x); w.y = f2b(v.y); w.z = f2b(v.z); w.w = f2b(v.w);
    *(ushort4*)(xb + (size_t)node * 256 + k0) = w;
    float acc[NC];
    #pragma unroll
    for (int j = 0; j < NC; ++j) acc[j] = 0.f;
    #pragma unroll
    for (int i = 0; i < 4; ++i)
        #pragma unroll
        for (int j = 0; j < NC; ++j)
            acc[j] += xv[i] * u[(size_t)(k0 + i) * NC + j];
    #pragma unroll
    for (int off = 32; off > 0; off >>= 1)
        #pragma unroll
        for (int j = 0; j < NC; ++j)
            acc[j] += __shfl_xor(acc[j], off);
    if (lane == 0) {
        const int H = NC / 2;
        #pragma unroll
        for (int h = 0; h < H; ++h) {
            asrc[(size_t)node * H + h] = acc[h];
            adst[(size_t)node * H + h] = acc[H + h];
        }
    }
}

// ---------- per-node softmax stats: minv[node][2h] = m, [2h+1] = 1/s ----------
template <int H>
__global__ __launch_bounds__(256) void k_ms(
    const float* __restrict__ asrc, const float* __restrict__ adst,
    const int* __restrict__ rowptr, const int* __restrict__ deg,
    const unsigned short* __restrict__ csr, float* __restrict__ minv) {
    int lane = threadIdx.x & 63;
    int node = blockIdx.x * 4 + (threadIdx.x >> 6);
    if (node >= N_NODES) return;
    int ptr = rowptr[node], dg = deg[node];
    float adr[H], m[H], s[H];
    #pragma unroll
    for (int h = 0; h < H; ++h) { adr[h] = adst[node * H + h]; m[h] = -1e30f; s[h] = 0.f; }
    for (int i = lane; i < dg; i += 64) {
        int sn = csr[ptr + i];
        float ev[H];
        if (H == 8) {
            float4 qa = *(const float4*)(asrc + (size_t)sn * 8);
            float4 qb = *(const float4*)(asrc + (size_t)sn * 8 + 4);
            ev[0] = qa.x; ev[1] = qa.y; ev[2] = qa.z; ev[3] = qa.w;
            ev[4] = qb.x; ev[5] = qb.y; ev[6] = qb.z; ev[7] = qb.w;
        } else {
            ev[0] = asrc[sn];
        }
        #pragma unroll
        for (int h = 0; h < H; ++h) {
            float e = ev[h] + adr[h];
            e = (e >= 0.f) ? e : 0.2f * e;
            float mn = fmaxf(m[h], e);
            s[h] = s[h] * __expf(m[h] - mn) + __expf(e - mn);
            m[h] = mn;
        }
    }
    #pragma unroll
    for (int off = 32; off > 0; off >>= 1) {
        #pragma unroll
        for (int h = 0; h < H; ++h) {
            float mo = __shfl_xor(m[h], off);
            float so = __shfl_xor(s[h], off);
            float mn = fmaxf(m[h], mo);
            s[h] = s[h] * __expf(m[h] - mn) + so * __expf(mo - mn);
            m[h] = mn;
        }
    }
    if (lane == 0) {
        #pragma unroll
        for (int h = 0; h < H; ++h) {
            minv[(size_t)node * 2 * H + 2 * h] = m[h];
            minv[(size_t)node * 2 * H + 2 * h + 1] = 1.0f / s[h];
        }
    }
}

// ---------- gather-aggregate 256ch: inline alpha, 2 edges/iter, depth-2 pipeline ----------
template <int H, bool FUSE>
__global__ __launch_bounds__(256) void k_gather(
    const unsigned short* __restrict__ xp,     // bf16 [NP,256]
    const float* __restrict__ asrc, const float* __restrict__ adst,
    const float* __restrict__ minv,            // [N, 2H]
    const int* __restrict__ rowptr, const int* __restrict__ deg,
    const unsigned short* __restrict__ csr,
    const float* __restrict__ bias,            // f32 [256]
    const float* __restrict__ un,              // f32 [256*2] (next-layer u) or null
    unsigned short* __restrict__ o,            // bf16 [NP,256]
    float* __restrict__ asn, float* __restrict__ adn) {
    int lane = threadIdx.x & 63;
    int node = blockIdx.x * 4 + (threadIdx.x >> 6);
    if (node >= N_NODES) return;
    int ptr = rowptr[node], dg = deg[node];
    int half = lane >> 5, l5 = lane & 31;
    int cbase = l5 * 8;
    int head = (H == 8) ? (l5 >> 2) : 0;
    float ad = adst[(size_t)node * H + head];
    float2 mi = *(const float2*)(minv + (size_t)node * 2 * H + 2 * head);
    float m = mi.x, inv = mi.y;
    float acc[8] = {0,0,0,0,0,0,0,0};
    int dge = (dg + 1) & ~1;
    int i = half;
    int ci = ptr + min(i, dg - 1);
    int sn0 = csr[ci];
    float e0 = asrc[(size_t)sn0 * H + head];
    short8 v0 = *(const short8*)(xp + (size_t)sn0 * 256 + cbase);
    bool ok0 = (i < dg);
    while (i < dge) {
        int in = i + 2;
        int cn = ptr + min(in, dg - 1);
        int sn1 = csr[cn];
        float e1 = asrc[(size_t)sn1 * H + head];
        short8 v1 = *(const short8*)(xp + (size_t)sn1 * 256 + cbase);
        float e = e0 + ad;
        e = (e >= 0.f) ? e : 0.2f * e;
        float a0 = ok0 ? __expf(e - m) * inv : 0.f;
        #pragma unroll
        for (int j = 0; j < 8; ++j) acc[j] += a0 * b2f((unsigned short)v0[j]);
        i = in; e0 = e1; v0 = v1; ok0 = (in < dg);
    }
    #pragma unroll
    for (int j = 0; j < 8; ++j) acc[j] += __shfl_xor(acc[j], 32);
    if (half) return;
    float sN = 0.f, dN = 0.f;
    #pragma unroll
    for (int j = 0; j < 8; ++j) {
        int c = cbase + j;
        float v = acc[j] + bias[c];
        v = (v > 0.f) ? v : (__expf(v) - 1.f);   // ELU
        o[(size_t)node * 256 + c] = f2b(v);
        if (FUSE) {
            sN += v * un[c * 2];
            dN += v * un[c * 2 + 1];
        }
    }
    if (FUSE) {
        #pragma unroll
        for (int off = 16; off > 0; off >>= 1) {
            sN += __shfl_xor(sN, off);
            dN += __shfl_xor(dN, off);
        }
        if (l5 == 0) { asn[node] = sN; adn[node] = dN; }
    }
}

// ---------- final gather: 64 padded bf16 ch, inline alpha, 4 edges/iter + log_softmax ----------
__global__ __launch_bounds__(256) void k_gf(
    const unsigned short* __restrict__ xp,     // bf16 [NP,64]
    const float* __restrict__ asrc, const float* __restrict__ adst,
    const float* __restrict__ minv,            // [N,2]
    const int* __restrict__ rowptr, const int* __restrict__ deg,
    const unsigned short* __restrict__ csr,
    const float* __restrict__ bias,            // f32 [40]
    float* __restrict__ out) {                 // f32 [N,40]
    int lane = threadIdx.x & 63;
    int node = blockIdx.x * 4 + (threadIdx.x >> 6);
    if (node >= N_NODES) return;
    int ptr = rowptr[node], dg = deg[node];
    int g = lane >> 4, l4 = lane & 15;
    int cbase = l4 * 4;
    float ad = adst[node];
    float2 mi = *(const float2*)(minv + (size_t)node * 2);
    float m = mi.x, inv = mi.y;
    float acc[4] = {0,0,0,0};
    int dge = (dg + 3) & ~3;
    int i = g;
    int ci = ptr + min(i, dg - 1);
    int sn0 = csr[ci];
    float e0 = asrc[sn0];
    ushort4 v0 = *(const ushort4*)(xp + (size_t)sn0 * 64 + cbase);
    bool ok0 = (i < dg);
    while (i < dge) {
        int in = i + 4;
        int cn = ptr + min(in, dg - 1);
        int sn1 = csr[cn];
        float e1 = asrc[sn1];
        ushort4 v1 = *(const ushort4*)(xp + (size_t)sn1 * 64 + cbase);
        float e = e0 + ad;
        e = (e >= 0.f) ? e : 0.2f * e;
        float a0 = ok0 ? __expf(e - m) * inv : 0.f;
        acc[0] += a0 * b2f(v0.x);
        acc[1] += a0 * b2f(v0.y);
        acc[2] += a0 * b2f(v0.z);
        acc[3] += a0 * b2f(v0.w);
        i = in; e0 = e1; v0 = v1; ok0 = (in < dg);
    }
    #pragma unroll
    for (int j = 0; j < 4; ++j) {
        acc[j] += __shfl_xor(acc[j], 16);
        acc[j] += __shfl_xor(acc[j], 32);
    }
    if (lane >= 16) return;
    float val[4], mx = -1e30f;
    #pragma unroll
    for (int j = 0; j < 4; ++j) {
        int c = cbase + j;
        val[j] = (c < 40) ? acc[j] + bias[c] : -1e30f;
        mx = fmaxf(mx, val[j]);
    }
    #pragma unroll
    for (int off = 8; off > 0; off >>= 1) mx = fmaxf(mx, __shfl_xor(mx, off));
    float ex = 0.f;
    #pragma unroll
    for (int j = 0; j < 4; ++j) {
        int c = cbase + j;
        if (c < 40) ex += __expf(val[j] - mx);
    }
    #pragma unroll
    for (int off = 8; off > 0; off >>= 1) ex += __shfl_xor(ex, off);
    float lse = __logf(ex);
    #pragma unroll
    for (int j = 0; j < 4; ++j) {
        int c = cbase + j;
        if (c < 40) out[(size_t)node * 40 + c] = val[j] - mx - lse;
    }
}

extern "C" void kernel_launch(void* const* d_in, const int* in_sizes, int n_in,
                              void* d_out, int out_size, void* d_ws, size_t ws_size,
                              hipStream_t stream) {
    const float* x   = (const float*)d_in[0];
    const int*   ei  = (const int*)d_in[1];
    const float* W0  = (const float*)d_in[2];
    const float* as0 = (const float*)d_in[3];
    const float* ad0 = (const float*)d_in[4];
    const float* b0  = (const float*)d_in[5];
    const float* W1  = (const float*)d_in[6];
    const float* as1 = (const float*)d_in[7];
    const float* ad1 = (const float*)d_in[8];
    const float* b1  = (const float*)d_in[9];
    const float* W2  = (const float*)d_in[10];
    const float* as2 = (const float*)d_in[11];
    const float* ad2 = (const float*)d_in[12];
    const float* b2  = (const float*)d_in[13];
    float* out = (float*)d_out;

    char* p = (char*)d_ws;
    auto carve = [&](size_t bytes) -> char* {
        char* r = p; p += (bytes + 255) & ~(size_t)255; return r;
    };
    unsigned short* xb   = (unsigned short*)carve((size_t)NP * 256 * 2);  // x bf16, later h2
    unsigned short* xpb  = (unsigned short*)carve((size_t)NP * 256 * 2);  // gemm out (messages)
    unsigned short* h    = (unsigned short*)carve((size_t)NP * 256 * 2);  // h1
    unsigned short* xp2b = (unsigned short*)carve((size_t)NP * 64 * 2);
    unsigned short* Wt0  = (unsigned short*)carve(256 * 256 * 2);
    unsigned short* Wt1  = (unsigned short*)carve(256 * 256 * 2);
    unsigned short* Wt2  = (unsigned short*)carve(64 * 256 * 2);
    float* u0 = (float*)carve(256 * 16 * 4);
    float* u1 = (float*)carve(256 * 2 * 4);
    float* u2 = (float*)carve(256 * 2 * 4);
    float* asrc0 = (float*)carve((size_t)N_NODES * 8 * 4);
    float* adst0 = (float*)carve((size_t)N_NODES * 8 * 4);
    float* asrc1 = (float*)carve((size_t)N_NODES * 4);
    float* adst1 = (float*)carve((size_t)N_NODES * 4);
    float* asrc2 = (float*)carve((size_t)N_NODES * 4);
    float* adst2 = (float*)carve((size_t)N_NODES * 4);
    float* minv0 = (float*)carve((size_t)N_NODES * 16 * 4);
    float* minv1 = (float*)carve((size_t)N_NODES * 2 * 4);
    float* minv2 = (float*)carve((size_t)N_NODES * 2 * 4);
    int* deg    = (int*)carve((size_t)N_NODES * 4);
    int* rowptr = (int*)carve((size_t)N_NODES * 4);
    int* bcnt   = (int*)carve((size_t)NBUCK * 4);
    int* bstart = (int*)carve((size_t)(NBUCK + 1) * 4);
    int* bcursor= (int*)carve((size_t)NBUCK * 4);
    unsigned int* stage = (unsigned int*)carve((size_t)ETOT * 4);
    unsigned short* csr = (unsigned short*)carve((size_t)ETOT * 2);

    hipMemsetAsync(bcnt, 0, (size_t)NBUCK * 4, stream);
    hipMemsetAsync(Wt2, 0, 64 * 256 * 2, stream);  // zero pad cols 40..63

    k_tb<<<(256 * 256 + 255) / 256, 256, 0, stream>>>(W0, Wt0, 256, 256);
    k_tb<<<(256 * 256 + 255) / 256, 256, 0, stream>>>(W1, Wt1, 256, 256);
    k_tb<<<(256 * 40 + 255) / 256, 256, 0, stream>>>(W2, Wt2, 256, 40);

    k_mku<<<(256 * 16 + 255) / 256, 256, 0, stream>>>(W0, as0, ad0, u0, 256, 32, 8);
    k_mku<<<(256 * 2 + 255) / 256, 256, 0, stream>>>(W1, as1, ad1, u1, 256, 256, 1);
    k_mku<<<(256 * 2 + 255) / 256, 256, 0, stream>>>(W2, as2, ad2, u2, 256, 40, 1);

    k_bcount<<<(ETOT + 4095) / 4096, 256, 0, stream>>>(ei, bcnt);
    k_bscan<<<1, 256, 0, stream>>>(bcnt, bstart, bcursor);
    k_bscatter<<<(ETOT + 8191) / 8192, 256, 0, stream>>>(ei, bcursor, stage);
    k_csr<<<NBUCK, 256, 0, stream>>>(stage, bstart, rowptr, deg, csr);

    dim3 gg(NP / 128, 2);
    dim3 gn(N_NODES / 4);
    // layer 0
    k_splitatt<16><<<gn, 256, 0, stream>>>(x, u0, xb, asrc0, adst0);
    k_gemm_w<<<gg, 256, 0, stream>>>(xb, Wt0, xpb, N_NODES, 256, 256);
    k_ms<8><<<gn, 256, 0, stream>>>(asrc0, adst0, rowptr, deg, csr, minv0);
    k_gather<8, true><<<gn, 256, 0, stream>>>(xpb, asrc0, adst0, minv0, rowptr, deg, csr,
                                              b0, u1, h, asrc1, adst1);
    // layer 1
    k_gemm_w<<<gg, 256, 0, stream>>>(h, Wt1, xpb, N_NODES, 256, 256);
    k_ms<1><<<gn, 256, 0, stream>>>(asrc1, adst1, rowptr, deg, csr, minv1);
    k_gather<1, true><<<gn, 256, 0, stream>>>(xpb, asrc1, adst1, minv1, rowptr, deg, csr,
                                              b1, u2, xb, asrc2, adst2);
    // layer 2
    dim3 g2(NP / 128);
    k_gemm_b<<<g2, 256, 0, stream>>>(xb, Wt2, xp2b, N_NODES, 40, 64);
    k_ms<1><<<gn, 256, 0, stream>>>(asrc2, adst2, rowptr, deg, csr, minv2);
    k_gf<<<gn, 256, 0, stream>>>(xp2b, asrc2, adst2, minv2, rowptr, deg, csr, b2, out);
}

// Round 7
// 632.496 us; speedup vs baseline: 2.1839x; 1.1416x over previous
//
#include <hip/hip_runtime.h>
#include <hip/hip_bf16.h>

#define N_NODES 50000
#define N_EDGES 1600000
#define ETOT (N_EDGES + N_NODES)
#define NP 50048   // N padded for GEMM row tiles (391 * 128)
#define NBUCK 196  // dst >> 8 buckets (50000/256)

typedef __attribute__((ext_vector_type(8))) short short8;
typedef __attribute__((ext_vector_type(4))) float f32x4;

__device__ __forceinline__ float b2f(unsigned short u) {
    union { unsigned int i; float f; } v; v.i = ((unsigned int)u) << 16; return v.f;
}
__device__ __forceinline__ unsigned short f2b(float f) {
    union { float f; unsigned int i; } v; v.f = f;
    unsigned int r = v.i + 0x7FFF + ((v.i >> 16) & 1);  // RNE
    return (unsigned short)(r >> 16);
}

// ---------- weight transpose to bf16: W f32 [K,C] -> Wt bf16 [C,K] ----------
__global__ void k_tb(const float* __restrict__ W, unsigned short* __restrict__ Wt,
                     int K, int C) {
    int idx = blockIdx.x * 256 + threadIdx.x;
    if (idx >= K * C) return;
    int k = idx / C, c = idx - k * C;
    Wt[c * K + k] = f2b(W[idx]);
}

// ---------- attention projection vectors ----------
__global__ void k_mku(const float* __restrict__ W, const float* __restrict__ attS,
                      const float* __restrict__ attD, float* __restrict__ u,
                      int K, int C, int H) {
    int idx = blockIdx.x * 256 + threadIdx.x;
    int NC = 2 * H;
    if (idx >= K * NC) return;
    int k = idx / NC, j = idx - k * NC;
    int h = (j < H) ? j : j - H;
    const float* av = ((j < H) ? attS : attD) + h * C;
    const float* wr = W + (size_t)k * (C * H) + h * C;
    float s = 0.f;
    for (int c = 0; c < C; ++c) s += wr[c] * av[c];
    u[idx] = s;
}

// ---------- CSR build: bucketed, low write-amplification ----------
__global__ __launch_bounds__(256) void k_bcount(const int* __restrict__ ei,
                                                int* __restrict__ bcnt) {
    __shared__ int h[NBUCK];
    for (int i = threadIdx.x; i < NBUCK; i += 256) h[i] = 0;
    __syncthreads();
    int e0 = blockIdx.x * 4096, e1 = min(e0 + 4096, ETOT);
    for (int e = e0 + threadIdx.x; e < e1; e += 256) {
        int dst = (e < N_EDGES) ? ei[N_EDGES + e] : (e - N_EDGES);
        atomicAdd(&h[dst >> 8], 1);
    }
    __syncthreads();
    for (int i = threadIdx.x; i < NBUCK; i += 256)
        if (h[i]) atomicAdd(&bcnt[i], h[i]);
}

__global__ void k_bscan(const int* __restrict__ bcnt, int* __restrict__ bstart,
                        int* __restrict__ bcursor) {
    __shared__ int tmp[256];
    int t = threadIdx.x;
    int v = (t < NBUCK) ? bcnt[t] : 0;
    tmp[t] = v;
    __syncthreads();
    for (int off = 1; off < 256; off <<= 1) {
        int u = (t >= off) ? tmp[t - off] : 0;
        __syncthreads();
        tmp[t] += u;
        __syncthreads();
    }
    int ex = tmp[t] - v;
    if (t < NBUCK) { bstart[t] = ex; bcursor[t] = ex; }
    if (t == 0) bstart[NBUCK] = ETOT;
}

// LDS-binned scatter of packed (bucket<<24 | src<<8 | dst&255) into bucket-grouped staging
__global__ __launch_bounds__(256) void k_bscatter(const int* __restrict__ ei,
                                                  int* __restrict__ bcursor,
                                                  unsigned int* __restrict__ stage) {
    __shared__ int h[NBUCK], base[NBUCK], cur[NBUCK], gbase[NBUCK];
    __shared__ int tmp[256];
    __shared__ unsigned int buf[8192];
    int t = threadIdx.x;
    for (int i = t; i < NBUCK; i += 256) h[i] = 0;
    __syncthreads();
    int e0 = blockIdx.x * 8192, e1 = min(e0 + 8192, ETOT);
    for (int e = e0 + t; e < e1; e += 256) {
        int dst = (e < N_EDGES) ? ei[N_EDGES + e] : (e - N_EDGES);
        atomicAdd(&h[dst >> 8], 1);
    }
    __syncthreads();
    int v = (t < NBUCK) ? h[t] : 0;
    tmp[t] = v;
    __syncthreads();
    for (int off = 1; off < 256; off <<= 1) {
        int u = (t >= off) ? tmp[t - off] : 0;
        __syncthreads();
        tmp[t] += u;
        __syncthreads();
    }
    if (t < NBUCK) { base[t] = tmp[t] - v; cur[t] = tmp[t] - v; }
    __syncthreads();
    for (int e = e0 + t; e < e1; e += 256) {
        int src, dst;
        if (e < N_EDGES) { src = ei[e]; dst = ei[N_EDGES + e]; }
        else             { src = dst = e - N_EDGES; }
        int b = dst >> 8;
        int p = atomicAdd(&cur[b], 1);
        buf[p] = ((unsigned int)b << 24) | ((unsigned int)src << 8) | (unsigned int)(dst & 255);
    }
    __syncthreads();
    if (t < NBUCK) gbase[t] = atomicAdd(&bcursor[t], h[t]);
    __syncthreads();
    int cnt = e1 - e0;
    for (int i = t; i < cnt; i += 256) {
        unsigned int pr = buf[i];
        int b = pr >> 24;
        stage[gbase[b] + (i - base[b])] = pr;
    }
}

// per-bucket exact CSR: rowptr, deg, csr(ushort)
__global__ __launch_bounds__(256) void k_csr(const unsigned int* __restrict__ stage,
                                             const int* __restrict__ bstart,
                                             int* __restrict__ rowptr, int* __restrict__ deg,
                                             unsigned short* __restrict__ csr) {
    __shared__ int cnt[256], cur[256], tmp[256];
    int b = blockIdx.x;
    int t = threadIdx.x;
    cnt[t] = 0;
    __syncthreads();
    int s0 = bstart[b], s1 = bstart[b + 1];
    for (int i = s0 + t; i < s1; i += 256)
        atomicAdd(&cnt[stage[i] & 255], 1);
    __syncthreads();
    int v = cnt[t];
    tmp[t] = v;
    __syncthreads();
    for (int off = 1; off < 256; off <<= 1) {
        int u = (t >= off) ? tmp[t - off] : 0;
        __syncthreads();
        tmp[t] += u;
        __syncthreads();
    }
    int ex = tmp[t] - v;
    int node = b * 256 + t;
    if (node < N_NODES) { rowptr[node] = s0 + ex; deg[node] = v; }
    cur[t] = s0 + ex;
    __syncthreads();
    for (int i = s0 + t; i < s1; i += 256) {
        unsigned int pr = stage[i];
        int p = atomicAdd(&cur[pr & 255], 1);
        csr[p] = (unsigned short)((pr >> 8) & 0xFFFF);
    }
}

// ---------- wide bf16 GEMM: A[nrows,256] x Bt[c,256] -> bf16; 32rows x 128cols per wave ----------
__global__ __launch_bounds__(256) void k_gemm_w(
    const unsigned short* __restrict__ A, const unsigned short* __restrict__ Bt,
    unsigned short* __restrict__ Cout, int nrows, int ncols, int ldc) {
    const int K = 256;
    int lane = threadIdx.x & 63;
    int wave = threadIdx.x >> 6;
    int row0 = blockIdx.x * 128 + wave * 32;
    int col0 = blockIdx.y * 128;
    int ar0 = row0 + (lane & 15); if (ar0 >= nrows) ar0 = nrows - 1;
    int ar1 = row0 + 16 + (lane & 15); if (ar1 >= nrows) ar1 = nrows - 1;
    int ks = (lane >> 4) * 8;
    const unsigned short* Ap0 = A + (size_t)ar0 * K + ks;
    const unsigned short* Ap1 = A + (size_t)ar1 * K + ks;
    f32x4 acc[2][8];
    #pragma unroll
    for (int rt = 0; rt < 2; ++rt)
        #pragma unroll
        for (int ct = 0; ct < 8; ++ct) acc[rt][ct] = {0, 0, 0, 0};
    for (int k = 0; k < K; k += 32) {
        short8 a0 = *(const short8*)(Ap0 + k);
        short8 a1 = *(const short8*)(Ap1 + k);
        #pragma unroll
        for (int ct = 0; ct < 8; ++ct) {
            short8 b = *(const short8*)(Bt + (size_t)(col0 + ct * 16 + (lane & 15)) * K + k + ks);
            acc[0][ct] = __builtin_amdgcn_mfma_f32_16x16x32_bf16(a0, b, acc[0][ct], 0, 0, 0);
            acc[1][ct] = __builtin_amdgcn_mfma_f32_16x16x32_bf16(a1, b, acc[1][ct], 0, 0, 0);
        }
    }
    int cb = lane & 15;
    #pragma unroll
    for (int rt = 0; rt < 2; ++rt) {
        int rbase = row0 + rt * 16 + (lane >> 4) * 4;
        #pragma unroll
        for (int ct = 0; ct < 8; ++ct) {
            int cc = col0 + ct * 16 + cb;
            #pragma unroll
            for (int j = 0; j < 4; ++j) {
                float v = (cc < ncols) ? acc[rt][ct][j] : 0.f;
                Cout[(size_t)(rbase + j) * ldc + cc] = f2b(v);
            }
        }
    }
}

// ---------- narrow bf16 GEMM (64 cols) for layer 2 ----------
__global__ __launch_bounds__(256) void k_gemm_b(
    const unsigned short* __restrict__ A, const unsigned short* __restrict__ Bt,
    unsigned short* __restrict__ Cout, int nrows, int ncols, int ldc) {
    const int K = 256;
    int lane = threadIdx.x & 63;
    int wave = threadIdx.x >> 6;
    int row0 = blockIdx.x * 128 + wave * 32;
    int col0 = 0;
    int ar0 = row0 + (lane & 15); if (ar0 >= nrows) ar0 = nrows - 1;
    int ar1 = row0 + 16 + (lane & 15); if (ar1 >= nrows) ar1 = nrows - 1;
    int ks = (lane >> 4) * 8;
    const unsigned short* Ap0 = A + (size_t)ar0 * K + ks;
    const unsigned short* Ap1 = A + (size_t)ar1 * K + ks;
    f32x4 acc[2][4] = {{{0,0,0,0},{0,0,0,0},{0,0,0,0},{0,0,0,0}},
                       {{0,0,0,0},{0,0,0,0},{0,0,0,0},{0,0,0,0}}};
    for (int k = 0; k < K; k += 32) {
        short8 a0 = *(const short8*)(Ap0 + k);
        short8 a1 = *(const short8*)(Ap1 + k);
        #pragma unroll
        for (int ct = 0; ct < 4; ++ct) {
            short8 b = *(const short8*)(Bt + (size_t)(col0 + ct * 16 + (lane & 15)) * K + k + ks);
            acc[0][ct] = __builtin_amdgcn_mfma_f32_16x16x32_bf16(a0, b, acc[0][ct], 0, 0, 0);
            acc[1][ct] = __builtin_amdgcn_mfma_f32_16x16x32_bf16(a1, b, acc[1][ct], 0, 0, 0);
        }
    }
    int cb = lane & 15;
    #pragma unroll
    for (int rt = 0; rt < 2; ++rt) {
        int rbase = row0 + rt * 16 + (lane >> 4) * 4;
        #pragma unroll
        for (int ct = 0; ct < 4; ++ct) {
            int cc = col0 + ct * 16 + cb;
            #pragma unroll
            for (int j = 0; j < 4; ++j) {
                float v = (cc < ncols) ? acc[rt][ct][j] : 0.f;
                Cout[(size_t)(rbase + j) * ldc + cc] = f2b(v);
            }
        }
    }
}

// ---------- fused: x f32 -> xb bf16 + layer-0 attention logits ----------
template <int NC>
__global__ __launch_bounds__(256) void k_splitatt(
    const float* __restrict__ x, const float* __restrict__ u,
    unsigned short* __restrict__ xb,
    float* __restrict__ asrc, float* __restrict__ adst) {
    int lane = threadIdx.x & 63;
    int node = blockIdx.x * 4 + (threadIdx.x >> 6);
    if (node >= N_NODES) return;
    int k0 = lane * 4;
    float4 v = *(const float4*)(x + (size_t)node * 256 + k0);
    float xv[4] = {v.x, v.y, v.z, v.w};
    ushort4 w;
    w.x = f2b(v.x); w.y = f2b(v.y); w.z = f2b(v.z); w.w = f2b(v.w);
    *(ushort4*)(xb + (size_t)node * 256 + k0) = w;
    float acc[NC];
    #pragma unroll
    for (int j = 0; j < NC; ++j) acc[j] = 0.f;
    #pragma unroll
    for (int i = 0; i < 4; ++i)
        #pragma unroll
        for (int j = 0; j < NC; ++j)
            acc[j] += xv[i] * u[(size_t)(k0 + i) * NC + j];
    #pragma unroll
    for (int off = 32; off > 0; off >>= 1)
        #pragma unroll
        for (int j = 0; j < NC; ++j)
            acc[j] += __shfl_xor(acc[j], off);
    if (lane == 0) {
        const int H = NC / 2;
        #pragma unroll
        for (int h = 0; h < H; ++h) {
            asrc[(size_t)node * H + h] = acc[h];
            adst[(size_t)node * H + h] = acc[H + h];
        }
    }
}

// ---------- gather-aggregate 256ch: unnormalized softmax inline, single pass ----------
template <int H, bool FUSE>
__global__ __launch_bounds__(256) void k_gather(
    const unsigned short* __restrict__ xp,     // bf16 [NP,256]
    const float* __restrict__ asrc, const float* __restrict__ adst,
    const int* __restrict__ rowptr, const int* __restrict__ deg,
    const unsigned short* __restrict__ csr,
    const float* __restrict__ bias,            // f32 [256]
    const float* __restrict__ un,              // f32 [256*2] (next-layer u) or null
    unsigned short* __restrict__ o,            // bf16 [NP,256]
    float* __restrict__ asn, float* __restrict__ adn) {
    int lane = threadIdx.x & 63;
    int node = blockIdx.x * 4 + (threadIdx.x >> 6);
    if (node >= N_NODES) return;
    int ptr = rowptr[node], dg = deg[node];
    int half = lane >> 5, l5 = lane & 31;
    int cbase = l5 * 8;
    int head = (H == 8) ? (l5 >> 2) : 0;
    float ad = adst[(size_t)node * H + head];
    float acc[8] = {0,0,0,0,0,0,0,0};
    float den = 0.f;
    int dge = (dg + 1) & ~1;
    int i = half;
    int ci = ptr + min(i, dg - 1);
    int sn0 = csr[ci];
    float e0 = asrc[(size_t)sn0 * H + head];
    short8 v0 = *(const short8*)(xp + (size_t)sn0 * 256 + cbase);
    bool ok0 = (i < dg);
    while (i < dge) {
        int in = i + 2;
        int cn = ptr + min(in, dg - 1);
        int sn1 = csr[cn];
        float e1 = asrc[(size_t)sn1 * H + head];
        short8 v1 = *(const short8*)(xp + (size_t)sn1 * 256 + cbase);
        float e = e0 + ad;
        e = (e >= 0.f) ? e : 0.2f * e;
        float a0 = ok0 ? __expf(fminf(e, 70.f)) : 0.f;
        den += a0;
        #pragma unroll
        for (int j = 0; j < 8; ++j) acc[j] += a0 * b2f((unsigned short)v0[j]);
        i = in; e0 = e1; v0 = v1; ok0 = (in < dg);
    }
    den += __shfl_xor(den, 32);
    #pragma unroll
    for (int j = 0; j < 8; ++j) acc[j] += __shfl_xor(acc[j], 32);
    if (half) return;
    float inv = 1.0f / den;
    float sN = 0.f, dN = 0.f;
    #pragma unroll
    for (int j = 0; j < 8; ++j) {
        int c = cbase + j;
        float v = acc[j] * inv + bias[c];
        v = (v > 0.f) ? v : (__expf(v) - 1.f);   // ELU
        o[(size_t)node * 256 + c] = f2b(v);
        if (FUSE) {
            sN += v * un[c * 2];
            dN += v * un[c * 2 + 1];
        }
    }
    if (FUSE) {
        #pragma unroll
        for (int off = 16; off > 0; off >>= 1) {
            sN += __shfl_xor(sN, off);
            dN += __shfl_xor(dN, off);
        }
        if (l5 == 0) { asn[node] = sN; adn[node] = dN; }
    }
}

// ---------- final gather: 64 padded bf16 ch, unnormalized softmax + log_softmax ----------
__global__ __launch_bounds__(256) void k_gf(
    const unsigned short* __restrict__ xp,     // bf16 [NP,64]
    const float* __restrict__ asrc, const float* __restrict__ adst,
    const int* __restrict__ rowptr, const int* __restrict__ deg,
    const unsigned short* __restrict__ csr,
    const float* __restrict__ bias,            // f32 [40]
    float* __restrict__ out) {                 // f32 [N,40]
    int lane = threadIdx.x & 63;
    int node = blockIdx.x * 4 + (threadIdx.x >> 6);
    if (node >= N_NODES) return;
    int ptr = rowptr[node], dg = deg[node];
    int g = lane >> 4, l4 = lane & 15;
    int cbase = l4 * 4;
    float ad = adst[node];
    float acc[4] = {0,0,0,0};
    float den = 0.f;
    int dge = (dg + 3) & ~3;
    int i = g;
    int ci = ptr + min(i, dg - 1);
    int sn0 = csr[ci];
    float e0 = asrc[sn0];
    ushort4 v0 = *(const ushort4*)(xp + (size_t)sn0 * 64 + cbase);
    bool ok0 = (i < dg);
    while (i < dge) {
        int in = i + 4;
        int cn = ptr + min(in, dg - 1);
        int sn1 = csr[cn];
        float e1 = asrc[sn1];
        ushort4 v1 = *(const ushort4*)(xp + (size_t)sn1 * 64 + cbase);
        float e = e0 + ad;
        e = (e >= 0.f) ? e : 0.2f * e;
        float a0 = ok0 ? __expf(fminf(e, 70.f)) : 0.f;
        den += a0;
        acc[0] += a0 * b2f(v0.x);
        acc[1] += a0 * b2f(v0.y);
        acc[2] += a0 * b2f(v0.z);
        acc[3] += a0 * b2f(v0.w);
        i = in; e0 = e1; v0 = v1; ok0 = (in < dg);
    }
    den += __shfl_xor(den, 16);
    den += __shfl_xor(den, 32);
    #pragma unroll
    for (int j = 0; j < 4; ++j) {
        acc[j] += __shfl_xor(acc[j], 16);
        acc[j] += __shfl_xor(acc[j], 32);
    }
    if (lane >= 16) return;
    float inv = 1.0f / den;
    float val[4], mx = -1e30f;
    #pragma unroll
    for (int j = 0; j < 4; ++j) {
        int c = cbase + j;
        val[j] = (c < 40) ? acc[j] * inv + bias[c] : -1e30f;
        mx = fmaxf(mx, val[j]);
    }
    #pragma unroll
    for (int off = 8; off > 0; off >>= 1) mx = fmaxf(mx, __shfl_xor(mx, off));
    float ex = 0.f;
    #pragma unroll
    for (int j = 0; j < 4; ++j) {
        int c = cbase + j;
        if (c < 40) ex += __expf(val[j] - mx);
    }
    #pragma unroll
    for (int off = 8; off > 0; off >>= 1) ex += __shfl_xor(ex, off);
    float lse = __logf(ex);
    #pragma unroll
    for (int j = 0; j < 4; ++j) {
        int c = cbase + j;
        if (c < 40) out[(size_t)node * 40 + c] = val[j] - mx - lse;
    }
}

extern "C" void kernel_launch(void* const* d_in, const int* in_sizes, int n_in,
                              void* d_out, int out_size, void* d_ws, size_t ws_size,
                              hipStream_t stream) {
    const float* x   = (const float*)d_in[0];
    const int*   ei  = (const int*)d_in[1];
    const float* W0  = (const float*)d_in[2];
    const float* as0 = (const float*)d_in[3];
    const float* ad0 = (const float*)d_in[4];
    const float* b0  = (const float*)d_in[5];
    const float* W1  = (const float*)d_in[6];
    const float* as1 = (const float*)d_in[7];
    const float* ad1 = (const float*)d_in[8];
    const float* b1  = (const float*)d_in[9];
    const float* W2  = (const float*)d_in[10];
    const float* as2 = (const float*)d_in[11];
    const float* ad2 = (const float*)d_in[12];
    const float* b2  = (const float*)d_in[13];
    float* out = (float*)d_out;

    char* p = (char*)d_ws;
    auto carve = [&](size_t bytes) -> char* {
        char* r = p; p += (bytes + 255) & ~(size_t)255; return r;
    };
    unsigned short* xb   = (unsigned short*)carve((size_t)NP * 256 * 2);  // x bf16, later h2
    unsigned short* xpb  = (unsigned short*)carve((size_t)NP * 256 * 2);  // gemm out (messages)
    unsigned short* h    = (unsigned short*)carve((size_t)NP * 256 * 2);  // h1
    unsigned short* xp2b = (unsigned short*)carve((size_t)NP * 64 * 2);
    unsigned short* Wt0  = (unsigned short*)carve(256 * 256 * 2);
    unsigned short* Wt1  = (unsigned short*)carve(256 * 256 * 2);
    unsigned short* Wt2  = (unsigned short*)carve(64 * 256 * 2);
    float* u0 = (float*)carve(256 * 16 * 4);
    float* u1 = (float*)carve(256 * 2 * 4);
    float* u2 = (float*)carve(256 * 2 * 4);
    float* asrc0 = (float*)carve((size_t)N_NODES * 8 * 4);
    float* adst0 = (float*)carve((size_t)N_NODES * 8 * 4);
    float* asrc1 = (float*)carve((size_t)N_NODES * 4);
    float* adst1 = (float*)carve((size_t)N_NODES * 4);
    float* asrc2 = (float*)carve((size_t)N_NODES * 4);
    float* adst2 = (float*)carve((size_t)N_NODES * 4);
    int* deg    = (int*)carve((size_t)N_NODES * 4);
    int* rowptr = (int*)carve((size_t)N_NODES * 4);
    int* bcnt   = (int*)carve((size_t)NBUCK * 4);
    int* bstart = (int*)carve((size_t)(NBUCK + 1) * 4);
    int* bcursor= (int*)carve((size_t)NBUCK * 4);
    unsigned int* stage = (unsigned int*)carve((size_t)ETOT * 4);
    unsigned short* csr = (unsigned short*)carve((size_t)ETOT * 2);

    hipMemsetAsync(bcnt, 0, (size_t)NBUCK * 4, stream);
    hipMemsetAsync(Wt2, 0, 64 * 256 * 2, stream);  // zero pad cols 40..63

    k_tb<<<(256 * 256 + 255) / 256, 256, 0, stream>>>(W0, Wt0, 256, 256);
    k_tb<<<(256 * 256 + 255) / 256, 256, 0, stream>>>(W1, Wt1, 256, 256);
    k_tb<<<(256 * 40 + 255) / 256, 256, 0, stream>>>(W2, Wt2, 256, 40);

    k_mku<<<(256 * 16 + 255) / 256, 256, 0, stream>>>(W0, as0, ad0, u0, 256, 32, 8);
    k_mku<<<(256 * 2 + 255) / 256, 256, 0, stream>>>(W1, as1, ad1, u1, 256, 256, 1);
    k_mku<<<(256 * 2 + 255) / 256, 256, 0, stream>>>(W2, as2, ad2, u2, 256, 40, 1);

    k_bcount<<<(ETOT + 4095) / 4096, 256, 0, stream>>>(ei, bcnt);
    k_bscan<<<1, 256, 0, stream>>>(bcnt, bstart, bcursor);
    k_bscatter<<<(ETOT + 8191) / 8192, 256, 0, stream>>>(ei, bcursor, stage);
    k_csr<<<NBUCK, 256, 0, stream>>>(stage, bstart, rowptr, deg, csr);

    dim3 gg(NP / 128, 2);
    dim3 gn(N_NODES / 4);
    // layer 0
    k_splitatt<16><<<gn, 256, 0, stream>>>(x, u0, xb, asrc0, adst0);
    k_gemm_w<<<gg, 256, 0, stream>>>(xb, Wt0, xpb, N_NODES, 256, 256);
    k_gather<8, true><<<gn, 256, 0, stream>>>(xpb, asrc0, adst0, rowptr, deg, csr,
                                              b0, u1, h, asrc1, adst1);
    // layer 1
    k_gemm_w<<<gg, 256, 0, stream>>>(h, Wt1, xpb, N_NODES, 256, 256);
    k_gather<1, true><<<gn, 256, 0, stream>>>(xpb, asrc1, adst1, rowptr, deg, csr,
                                              b1, u2, xb, asrc2, adst2);
    // layer 2
    dim3 g2(NP / 128);
    k_gemm_b<<<g2, 256, 0, stream>>>(xb, Wt2, xp2b, N_NODES, 40, 64);
    k_gf<<<gn, 256, 0, stream>>>(xp2b, asrc2, adst2, rowptr, deg, csr, b2, out);
}

// Round 8
// 577.288 us; speedup vs baseline: 2.3927x; 1.0956x over previous
//
#include <hip/hip_runtime.h>
#include <hip/hip_bf16.h>

#define N_NODES 50000
#define N_EDGES 1600000
#define ETOT (N_EDGES + N_NODES)
#define NP 50048   // N padded for GEMM row tiles (391 * 128)
#define NBUCK 196  // dst >> 8 buckets (50000/256)

typedef __attribute__((ext_vector_type(8))) short short8;
typedef __attribute__((ext_vector_type(4))) float f32x4;

__device__ __forceinline__ float b2f(unsigned short u) {
    union { unsigned int i; float f; } v; v.i = ((unsigned int)u) << 16; return v.f;
}
__device__ __forceinline__ unsigned short f2b(float f) {
    union { float f; unsigned int i; } v; v.f = f;
    unsigned int r = v.i + 0x7FFF + ((v.i >> 16) & 1);  // RNE
    return (unsigned short)(r >> 16);
}

// ---------- weight transpose to bf16: W f32 [K,C] -> Wt bf16 [C,K] ----------
__global__ void k_tb(const float* __restrict__ W, unsigned short* __restrict__ Wt,
                     int K, int C) {
    int idx = blockIdx.x * 256 + threadIdx.x;
    if (idx >= K * C) return;
    int k = idx / C, c = idx - k * C;
    Wt[c * K + k] = f2b(W[idx]);
}

// ---------- attention projection vectors, wave-parallel ----------
// layer 0: W [256, 8*32], u0[k*16 + h] = src head h, [k*16+8+h] = dst head h
__global__ __launch_bounds__(256) void k_mku0(const float* __restrict__ W,
                                              const float* __restrict__ attS,
                                              const float* __restrict__ attD,
                                              float* __restrict__ u) {
    int lane = threadIdx.x & 63;
    int k = blockIdx.x * 4 + (threadIdx.x >> 6);
    if (k >= 256) return;
    int h = lane >> 3, c0 = lane & 7;
    const float* wr = W + (size_t)k * 256 + h * 32;
    float ss = 0.f, sd = 0.f;
    #pragma unroll
    for (int t = 0; t < 4; ++t) {
        int c = c0 + t * 8;
        float w = wr[c];
        ss += w * attS[h * 32 + c];
        sd += w * attD[h * 32 + c];
    }
    #pragma unroll
    for (int off = 1; off < 8; off <<= 1) {
        ss += __shfl_xor(ss, off);
        sd += __shfl_xor(sd, off);
    }
    if (c0 == 0) { u[k * 16 + h] = ss; u[k * 16 + 8 + h] = sd; }
}

// H=1 layers: u[k*2] = src, u[k*2+1] = dst; K=256 rows, C cols
__global__ __launch_bounds__(256) void k_mku1(const float* __restrict__ W,
                                              const float* __restrict__ attS,
                                              const float* __restrict__ attD,
                                              float* __restrict__ u, int C) {
    int lane = threadIdx.x & 63;
    int k = blockIdx.x * 4 + (threadIdx.x >> 6);
    if (k >= 256) return;
    const float* wr = W + (size_t)k * C;
    float ss = 0.f, sd = 0.f;
    for (int c = lane; c < C; c += 64) {
        float w = wr[c];
        ss += w * attS[c];
        sd += w * attD[c];
    }
    #pragma unroll
    for (int off = 32; off > 0; off >>= 1) {
        ss += __shfl_xor(ss, off);
        sd += __shfl_xor(sd, off);
    }
    if (lane == 0) { u[k * 2] = ss; u[k * 2 + 1] = sd; }
}

// ---------- CSR build: bucketed, low write-amplification ----------
__global__ __launch_bounds__(256) void k_bcount(const int* __restrict__ ei,
                                                int* __restrict__ bcnt) {
    __shared__ int h[NBUCK];
    for (int i = threadIdx.x; i < NBUCK; i += 256) h[i] = 0;
    __syncthreads();
    int e0 = blockIdx.x * 4096, e1 = min(e0 + 4096, ETOT);
    for (int e = e0 + threadIdx.x; e < e1; e += 256) {
        int dst = (e < N_EDGES) ? ei[N_EDGES + e] : (e - N_EDGES);
        atomicAdd(&h[dst >> 8], 1);
    }
    __syncthreads();
    for (int i = threadIdx.x; i < NBUCK; i += 256)
        if (h[i]) atomicAdd(&bcnt[i], h[i]);
}

__global__ void k_bscan(const int* __restrict__ bcnt, int* __restrict__ bstart,
                        int* __restrict__ bcursor) {
    __shared__ int tmp[256];
    int t = threadIdx.x;
    int v = (t < NBUCK) ? bcnt[t] : 0;
    tmp[t] = v;
    __syncthreads();
    for (int off = 1; off < 256; off <<= 1) {
        int u = (t >= off) ? tmp[t - off] : 0;
        __syncthreads();
        tmp[t] += u;
        __syncthreads();
    }
    int ex = tmp[t] - v;
    if (t < NBUCK) { bstart[t] = ex; bcursor[t] = ex; }
    if (t == 0) bstart[NBUCK] = ETOT;
}

// LDS-binned scatter of packed (bucket<<24 | src<<8 | dst&255) into bucket-grouped staging
__global__ __launch_bounds__(256) void k_bscatter(const int* __restrict__ ei,
                                                  int* __restrict__ bcursor,
                                                  unsigned int* __restrict__ stage) {
    __shared__ int h[NBUCK], base[NBUCK], cur[NBUCK], gbase[NBUCK];
    __shared__ int tmp[256];
    __shared__ unsigned int buf[8192];
    int t = threadIdx.x;
    for (int i = t; i < NBUCK; i += 256) h[i] = 0;
    __syncthreads();
    int e0 = blockIdx.x * 8192, e1 = min(e0 + 8192, ETOT);
    for (int e = e0 + t; e < e1; e += 256) {
        int dst = (e < N_EDGES) ? ei[N_EDGES + e] : (e - N_EDGES);
        atomicAdd(&h[dst >> 8], 1);
    }
    __syncthreads();
    int v = (t < NBUCK) ? h[t] : 0;
    tmp[t] = v;
    __syncthreads();
    for (int off = 1; off < 256; off <<= 1) {
        int u = (t >= off) ? tmp[t - off] : 0;
        __syncthreads();
        tmp[t] += u;
        __syncthreads();
    }
    if (t < NBUCK) { base[t] = tmp[t] - v; cur[t] = tmp[t] - v; }
    __syncthreads();
    for (int e = e0 + t; e < e1; e += 256) {
        int src, dst;
        if (e < N_EDGES) { src = ei[e]; dst = ei[N_EDGES + e]; }
        else             { src = dst = e - N_EDGES; }
        int b = dst >> 8;
        int p = atomicAdd(&cur[b], 1);
        buf[p] = ((unsigned int)b << 24) | ((unsigned int)src << 8) | (unsigned int)(dst & 255);
    }
    __syncthreads();
    if (t < NBUCK) gbase[t] = atomicAdd(&bcursor[t], h[t]);
    __syncthreads();
    int cnt = e1 - e0;
    for (int i = t; i < cnt; i += 256) {
        unsigned int pr = buf[i];
        int b = pr >> 24;
        stage[gbase[b] + (i - base[b])] = pr;
    }
}

// per-bucket exact CSR: rowptr, deg, csr(ushort)
__global__ __launch_bounds__(256) void k_csr(const unsigned int* __restrict__ stage,
                                             const int* __restrict__ bstart,
                                             int* __restrict__ rowptr, int* __restrict__ deg,
                                             unsigned short* __restrict__ csr) {
    __shared__ int cnt[256], cur[256], tmp[256];
    int b = blockIdx.x;
    int t = threadIdx.x;
    cnt[t] = 0;
    __syncthreads();
    int s0 = bstart[b], s1 = bstart[b + 1];
    for (int i = s0 + t; i < s1; i += 256)
        atomicAdd(&cnt[stage[i] & 255], 1);
    __syncthreads();
    int v = cnt[t];
    tmp[t] = v;
    __syncthreads();
    for (int off = 1; off < 256; off <<= 1) {
        int u = (t >= off) ? tmp[t - off] : 0;
        __syncthreads();
        tmp[t] += u;
        __syncthreads();
    }
    int ex = tmp[t] - v;
    int node = b * 256 + t;
    if (node < N_NODES) { rowptr[node] = s0 + ex; deg[node] = v; }
    cur[t] = s0 + ex;
    __syncthreads();
    for (int i = s0 + t; i < s1; i += 256) {
        unsigned int pr = stage[i];
        int p = atomicAdd(&cur[pr & 255], 1);
        csr[p] = (unsigned short)((pr >> 8) & 0xFFFF);
    }
}

// ---------- wide bf16 GEMM: A[nrows,256] x Bt[c,256] -> bf16; 32rows x 128cols per wave ----------
__global__ __launch_bounds__(256) void k_gemm_w(
    const unsigned short* __restrict__ A, const unsigned short* __restrict__ Bt,
    unsigned short* __restrict__ Cout, int nrows, int ncols, int ldc) {
    const int K = 256;
    int lane = threadIdx.x & 63;
    int wave = threadIdx.x >> 6;
    int row0 = blockIdx.x * 128 + wave * 32;
    int col0 = blockIdx.y * 128;
    int ar0 = row0 + (lane & 15); if (ar0 >= nrows) ar0 = nrows - 1;
    int ar1 = row0 + 16 + (lane & 15); if (ar1 >= nrows) ar1 = nrows - 1;
    int ks = (lane >> 4) * 8;
    const unsigned short* Ap0 = A + (size_t)ar0 * K + ks;
    const unsigned short* Ap1 = A + (size_t)ar1 * K + ks;
    f32x4 acc[2][8];
    #pragma unroll
    for (int rt = 0; rt < 2; ++rt)
        #pragma unroll
        for (int ct = 0; ct < 8; ++ct) acc[rt][ct] = {0, 0, 0, 0};
    for (int k = 0; k < K; k += 32) {
        short8 a0 = *(const short8*)(Ap0 + k);
        short8 a1 = *(const short8*)(Ap1 + k);
        #pragma unroll
        for (int ct = 0; ct < 8; ++ct) {
            short8 b = *(const short8*)(Bt + (size_t)(col0 + ct * 16 + (lane & 15)) * K + k + ks);
            acc[0][ct] = __builtin_amdgcn_mfma_f32_16x16x32_bf16(a0, b, acc[0][ct], 0, 0, 0);
            acc[1][ct] = __builtin_amdgcn_mfma_f32_16x16x32_bf16(a1, b, acc[1][ct], 0, 0, 0);
        }
    }
    int cb = lane & 15;
    #pragma unroll
    for (int rt = 0; rt < 2; ++rt) {
        int rbase = row0 + rt * 16 + (lane >> 4) * 4;
        #pragma unroll
        for (int ct = 0; ct < 8; ++ct) {
            int cc = col0 + ct * 16 + cb;
            #pragma unroll
            for (int j = 0; j < 4; ++j) {
                float v = (cc < ncols) ? acc[rt][ct][j] : 0.f;
                Cout[(size_t)(rbase + j) * ldc + cc] = f2b(v);
            }
        }
    }
}

// ---------- narrow bf16 GEMM (64 cols) for layer 2 ----------
__global__ __launch_bounds__(256) void k_gemm_b(
    const unsigned short* __restrict__ A, const unsigned short* __restrict__ Bt,
    unsigned short* __restrict__ Cout, int nrows, int ncols, int ldc) {
    const int K = 256;
    int lane = threadIdx.x & 63;
    int wave = threadIdx.x >> 6;
    int row0 = blockIdx.x * 128 + wave * 32;
    int ar0 = row0 + (lane & 15); if (ar0 >= nrows) ar0 = nrows - 1;
    int ar1 = row0 + 16 + (lane & 15); if (ar1 >= nrows) ar1 = nrows - 1;
    int ks = (lane >> 4) * 8;
    const unsigned short* Ap0 = A + (size_t)ar0 * K + ks;
    const unsigned short* Ap1 = A + (size_t)ar1 * K + ks;
    f32x4 acc[2][4] = {{{0,0,0,0},{0,0,0,0},{0,0,0,0},{0,0,0,0}},
                       {{0,0,0,0},{0,0,0,0},{0,0,0,0},{0,0,0,0}}};
    for (int k = 0; k < K; k += 32) {
        short8 a0 = *(const short8*)(Ap0 + k);
        short8 a1 = *(const short8*)(Ap1 + k);
        #pragma unroll
        for (int ct = 0; ct < 4; ++ct) {
            short8 b = *(const short8*)(Bt + (size_t)(ct * 16 + (lane & 15)) * K + k + ks);
            acc[0][ct] = __builtin_amdgcn_mfma_f32_16x16x32_bf16(a0, b, acc[0][ct], 0, 0, 0);
            acc[1][ct] = __builtin_amdgcn_mfma_f32_16x16x32_bf16(a1, b, acc[1][ct], 0, 0, 0);
        }
    }
    int cb = lane & 15;
    #pragma unroll
    for (int rt = 0; rt < 2; ++rt) {
        int rbase = row0 + rt * 16 + (lane >> 4) * 4;
        #pragma unroll
        for (int ct = 0; ct < 4; ++ct) {
            int cc = ct * 16 + cb;
            #pragma unroll
            for (int j = 0; j < 4; ++j) {
                float v = (cc < ncols) ? acc[rt][ct][j] : 0.f;
                Cout[(size_t)(rbase + j) * ldc + cc] = f2b(v);
            }
        }
    }
}

// ---------- fused: x f32 -> xb bf16 + layer-0 attention logits ----------
template <int NC>
__global__ __launch_bounds__(256) void k_splitatt(
    const float* __restrict__ x, const float* __restrict__ u,
    unsigned short* __restrict__ xb,
    float* __restrict__ asrc, float* __restrict__ adst) {
    int lane = threadIdx.x & 63;
    int node = blockIdx.x * 4 + (threadIdx.x >> 6);
    if (node >= N_NODES) return;
    int k0 = lane * 4;
    float4 v = *(const float4*)(x + (size_t)node * 256 + k0);
    float xv[4] = {v.x, v.y, v.z, v.w};
    ushort4 w;
    w.x = f2b(v.x); w.y = f2b(v.y); w.z = f2b(v.z); w.w = f2b(v.w);
    *(ushort4*)(xb + (size_t)node * 256 + k0) = w;
    float acc[NC];
    #pragma unroll
    for (int j = 0; j < NC; ++j) acc[j] = 0.f;
    #pragma unroll
    for (int i = 0; i < 4; ++i)
        #pragma unroll
        for (int j = 0; j < NC; ++j)
            acc[j] += xv[i] * u[(size_t)(k0 + i) * NC + j];
    #pragma unroll
    for (int off = 32; off > 0; off >>= 1)
        #pragma unroll
        for (int j = 0; j < NC; ++j)
            acc[j] += __shfl_xor(acc[j], off);
    if (lane == 0) {
        const int H = NC / 2;
        #pragma unroll
        for (int h = 0; h < H; ++h) {
            asrc[(size_t)node * H + h] = acc[h];
            adst[(size_t)node * H + h] = acc[H + h];
        }
    }
}

// ---------- gather-aggregate 256ch: 16 lanes/edge, 4 edges in flight ----------
template <int H, bool FUSE>
__global__ __launch_bounds__(256) void k_gather(
    const unsigned short* __restrict__ xp,     // bf16 [NP,256]
    const float* __restrict__ asrc, const float* __restrict__ adst,
    const int* __restrict__ rowptr, const int* __restrict__ deg,
    const unsigned short* __restrict__ csr,
    const float* __restrict__ bias,            // f32 [256]
    const float* __restrict__ un,              // f32 [256*2] (next-layer u) or null
    unsigned short* __restrict__ o,            // bf16 [NP,256]
    float* __restrict__ asn, float* __restrict__ adn) {
    int lane = threadIdx.x & 63;
    int node = blockIdx.x * 4 + (threadIdx.x >> 6);
    if (node >= N_NODES) return;
    int ptr = rowptr[node], dg = deg[node];
    int g = lane >> 4, l4 = lane & 15;
    int cbase = l4 * 16;
    int head = (H == 8) ? (l4 >> 1) : 0;
    float ad = adst[(size_t)node * H + head];
    float acc[16];
    #pragma unroll
    for (int j = 0; j < 16; ++j) acc[j] = 0.f;
    float den = 0.f;
    int dge = (dg + 3) & ~3;
    int i = g;
    int ci = ptr + min(i, dg - 1);
    int sn0 = csr[ci];
    float e0 = asrc[(size_t)sn0 * H + head];
    const unsigned short* xr0 = xp + (size_t)sn0 * 256 + cbase;
    short8 va0 = *(const short8*)(xr0);
    short8 vb0 = *(const short8*)(xr0 + 8);
    bool ok0 = (i < dg);
    while (i < dge) {
        int in = i + 4;
        int cn = ptr + min(in, dg - 1);
        int sn1 = csr[cn];
        float e1 = asrc[(size_t)sn1 * H + head];
        const unsigned short* xr1 = xp + (size_t)sn1 * 256 + cbase;
        short8 va1 = *(const short8*)(xr1);
        short8 vb1 = *(const short8*)(xr1 + 8);
        float e = e0 + ad;
        e = (e >= 0.f) ? e : 0.2f * e;
        float a0 = ok0 ? __expf(fminf(e, 70.f)) : 0.f;
        den += a0;
        #pragma unroll
        for (int j = 0; j < 8; ++j) acc[j] += a0 * b2f((unsigned short)va0[j]);
        #pragma unroll
        for (int j = 0; j < 8; ++j) acc[8 + j] += a0 * b2f((unsigned short)vb0[j]);
        i = in; e0 = e1; va0 = va1; vb0 = vb1; ok0 = (in < dg);
    }
    den += __shfl_xor(den, 16);
    den += __shfl_xor(den, 32);
    #pragma unroll
    for (int j = 0; j < 16; ++j) {
        acc[j] += __shfl_xor(acc[j], 16);
        acc[j] += __shfl_xor(acc[j], 32);
    }
    if (g) return;
    // lanes 0..15: each owns 16 contiguous channels
    float inv = 1.0f / den;
    float sN = 0.f, dN = 0.f;
    short8 w0, w1;
    #pragma unroll
    for (int j = 0; j < 16; ++j) {
        int c = cbase + j;
        float v = acc[j] * inv + bias[c];
        v = (v > 0.f) ? v : (__expf(v) - 1.f);   // ELU
        unsigned short bb = f2b(v);
        if (j < 8) w0[j] = (short)bb; else w1[j - 8] = (short)bb;
        if (FUSE) {
            sN += v * un[c * 2];
            dN += v * un[c * 2 + 1];
        }
    }
    *(short8*)(o + (size_t)node * 256 + cbase) = w0;
    *(short8*)(o + (size_t)node * 256 + cbase + 8) = w1;
    if (FUSE) {
        #pragma unroll
        for (int off = 8; off > 0; off >>= 1) {
            sN += __shfl_xor(sN, off);
            dN += __shfl_xor(dN, off);
        }
        if (l4 == 0) { asn[node] = sN; adn[node] = dN; }
    }
}

// ---------- final gather: 8 lanes/edge, 8 edges in flight + log_softmax ----------
__global__ __launch_bounds__(256) void k_gf(
    const unsigned short* __restrict__ xp,     // bf16 [NP,64]
    const float* __restrict__ asrc, const float* __restrict__ adst,
    const int* __restrict__ rowptr, const int* __restrict__ deg,
    const unsigned short* __restrict__ csr,
    const float* __restrict__ bias,            // f32 [40]
    float* __restrict__ out) {                 // f32 [N,40]
    int lane = threadIdx.x & 63;
    int node = blockIdx.x * 4 + (threadIdx.x >> 6);
    if (node >= N_NODES) return;
    int ptr = rowptr[node], dg = deg[node];
    int g = lane >> 3, l8 = lane & 7;
    int cbase = l8 * 8;
    float ad = adst[node];
    float acc[8] = {0,0,0,0,0,0,0,0};
    float den = 0.f;
    int dge = (dg + 7) & ~7;
    int i = g;
    int ci = ptr + min(i, dg - 1);
    int sn0 = csr[ci];
    float e0 = asrc[sn0];
    short8 v0 = *(const short8*)(xp + (size_t)sn0 * 64 + cbase);
    bool ok0 = (i < dg);
    while (i < dge) {
        int in = i + 8;
        int cn = ptr + min(in, dg - 1);
        int sn1 = csr[cn];
        float e1 = asrc[sn1];
        short8 v1 = *(const short8*)(xp + (size_t)sn1 * 64 + cbase);
        float e = e0 + ad;
        e = (e >= 0.f) ? e : 0.2f * e;
        float a0 = ok0 ? __expf(fminf(e, 70.f)) : 0.f;
        den += a0;
        #pragma unroll
        for (int j = 0; j < 8; ++j) acc[j] += a0 * b2f((unsigned short)v0[j]);
        i = in; e0 = e1; v0 = v1; ok0 = (in < dg);
    }
    den += __shfl_xor(den, 8);
    den += __shfl_xor(den, 16);
    den += __shfl_xor(den, 32);
    #pragma unroll
    for (int j = 0; j < 8; ++j) {
        acc[j] += __shfl_xor(acc[j], 8);
        acc[j] += __shfl_xor(acc[j], 16);
        acc[j] += __shfl_xor(acc[j], 32);
    }
    if (g) return;
    // lanes 0..7: 8 channels each
    float inv = 1.0f / den;
    float val[8], mx = -1e30f;
    #pragma unroll
    for (int j = 0; j < 8; ++j) {
        int c = cbase + j;
        val[j] = (c < 40) ? acc[j] * inv + bias[c] : -1e30f;
        mx = fmaxf(mx, val[j]);
    }
    #pragma unroll
    for (int off = 4; off > 0; off >>= 1) mx = fmaxf(mx, __shfl_xor(mx, off));
    float ex = 0.f;
    #pragma unroll
    for (int j = 0; j < 8; ++j) {
        int c = cbase + j;
        if (c < 40) ex += __expf(val[j] - mx);
    }
    #pragma unroll
    for (int off = 4; off > 0; off >>= 1) ex += __shfl_xor(ex, off);
    float lse = __logf(ex);
    #pragma unroll
    for (int j = 0; j < 8; ++j) {
        int c = cbase + j;
        if (c < 40) out[(size_t)node * 40 + c] = val[j] - mx - lse;
    }
}

extern "C" void kernel_launch(void* const* d_in, const int* in_sizes, int n_in,
                              void* d_out, int out_size, void* d_ws, size_t ws_size,
                              hipStream_t stream) {
    const float* x   = (const float*)d_in[0];
    const int*   ei  = (const int*)d_in[1];
    const float* W0  = (const float*)d_in[2];
    const float* as0 = (const float*)d_in[3];
    const float* ad0 = (const float*)d_in[4];
    const float* b0  = (const float*)d_in[5];
    const float* W1  = (const float*)d_in[6];
    const float* as1 = (const float*)d_in[7];
    const float* ad1 = (const float*)d_in[8];
    const float* b1  = (const float*)d_in[9];
    const float* W2  = (const float*)d_in[10];
    const float* as2 = (const float*)d_in[11];
    const float* ad2 = (const float*)d_in[12];
    const float* b2  = (const float*)d_in[13];
    float* out = (float*)d_out;

    char* p = (char*)d_ws;
    auto carve = [&](size_t bytes) -> char* {
        char* r = p; p += (bytes + 255) & ~(size_t)255; return r;
    };
    unsigned short* xb   = (unsigned short*)carve((size_t)NP * 256 * 2);  // x bf16, later h2
    unsigned short* xpb  = (unsigned short*)carve((size_t)NP * 256 * 2);  // gemm out (messages)
    unsigned short* h    = (unsigned short*)carve((size_t)NP * 256 * 2);  // h1
    unsigned short* xp2b = (unsigned short*)carve((size_t)NP * 64 * 2);
    unsigned short* Wt0  = (unsigned short*)carve(256 * 256 * 2);
    unsigned short* Wt1  = (unsigned short*)carve(256 * 256 * 2);
    unsigned short* Wt2  = (unsigned short*)carve(64 * 256 * 2);
    float* u0 = (float*)carve(256 * 16 * 4);
    float* u1 = (float*)carve(256 * 2 * 4);
    float* u2 = (float*)carve(256 * 2 * 4);
    float* asrc0 = (float*)carve((size_t)N_NODES * 8 * 4);
    float* adst0 = (float*)carve((size_t)N_NODES * 8 * 4);
    float* asrc1 = (float*)carve((size_t)N_NODES * 4);
    float* adst1 = (float*)carve((size_t)N_NODES * 4);
    float* asrc2 = (float*)carve((size_t)N_NODES * 4);
    float* adst2 = (float*)carve((size_t)N_NODES * 4);
    int* deg    = (int*)carve((size_t)N_NODES * 4);
    int* rowptr = (int*)carve((size_t)N_NODES * 4);
    int* bcnt   = (int*)carve((size_t)NBUCK * 4);
    int* bstart = (int*)carve((size_t)(NBUCK + 1) * 4);
    int* bcursor= (int*)carve((size_t)NBUCK * 4);
    unsigned int* stage = (unsigned int*)carve((size_t)ETOT * 4);
    unsigned short* csr = (unsigned short*)carve((size_t)ETOT * 2);

    hipMemsetAsync(bcnt, 0, (size_t)NBUCK * 4, stream);
    hipMemsetAsync(Wt2, 0, 64 * 256 * 2, stream);  // zero pad cols 40..63

    k_tb<<<(256 * 256 + 255) / 256, 256, 0, stream>>>(W0, Wt0, 256, 256);
    k_tb<<<(256 * 256 + 255) / 256, 256, 0, stream>>>(W1, Wt1, 256, 256);
    k_tb<<<(256 * 40 + 255) / 256, 256, 0, stream>>>(W2, Wt2, 256, 40);

    k_mku0<<<64, 256, 0, stream>>>(W0, as0, ad0, u0);
    k_mku1<<<64, 256, 0, stream>>>(W1, as1, ad1, u1, 256);
    k_mku1<<<64, 256, 0, stream>>>(W2, as2, ad2, u2, 40);

    k_bcount<<<(ETOT + 4095) / 4096, 256, 0, stream>>>(ei, bcnt);
    k_bscan<<<1, 256, 0, stream>>>(bcnt, bstart, bcursor);
    k_bscatter<<<(ETOT + 8191) / 8192, 256, 0, stream>>>(ei, bcursor, stage);
    k_csr<<<NBUCK, 256, 0, stream>>>(stage, bstart, rowptr, deg, csr);

    dim3 gg(NP / 128, 2);
    dim3 gn(N_NODES / 4);
    // layer 0
    k_splitatt<16><<<gn, 256, 0, stream>>>(x, u0, xb, asrc0, adst0);
    k_gemm_w<<<gg, 256, 0, stream>>>(xb, Wt0, xpb, N_NODES, 256, 256);
    k_gather<8, true><<<gn, 256, 0, stream>>>(xpb, asrc0, adst0, rowptr, deg, csr,
                                              b0, u1, h, asrc1, adst1);
    // layer 1
    k_gemm_w<<<gg, 256, 0, stream>>>(h, Wt1, xpb, N_NODES, 256, 256);
    k_gather<1, true><<<gn, 256, 0, stream>>>(xpb, asrc1, adst1, rowptr, deg, csr,
                                              b1, u2, xb, asrc2, adst2);
    // layer 2
    dim3 g2(NP / 128);
    k_gemm_b<<<g2, 256, 0, stream>>>(xb, Wt2, xp2b, N_NODES, 40, 64);
    k_gf<<<gn, 256, 0, stream>>>(xp2b, asrc2, adst2, rowptr, deg, csr, b2, out);
}

// Round 9
// 531.831 us; speedup vs baseline: 2.5973x; 1.0855x over previous
//
#include <hip/hip_runtime.h>
#include <hip/hip_bf16.h>

#define N_NODES 50000
#define N_EDGES 1600000
#define ETOT (N_EDGES + N_NODES)
#define NP 50048   // N padded for GEMM row tiles (391 * 128)
#define NBUCK 196  // dst >> 8 buckets (50000/256)

typedef __attribute__((ext_vector_type(8))) short short8;
typedef __attribute__((ext_vector_type(4))) float f32x4;
typedef __attribute__((ext_vector_type(2))) float f32x2;

__device__ __forceinline__ float b2f(unsigned short u) {
    union { unsigned int i; float f; } v; v.i = ((unsigned int)u) << 16; return v.f;
}
__device__ __forceinline__ unsigned short f2b(float f) {
    union { float f; unsigned int i; } v; v.f = f;
    unsigned int r = v.i + 0x7FFF + ((v.i >> 16) & 1);  // RNE
    return (unsigned short)(r >> 16);
}
__device__ __forceinline__ unsigned char f2q(float f) {
    // f32 -> fp8 e4m3 (OCP) via HW packed convert
    int r = __builtin_amdgcn_cvt_pk_fp8_f32(f, f, 0, false);
    return (unsigned char)(r & 0xFF);
}

// ---------- weight transpose to bf16: W f32 [K,C] -> Wt bf16 [C,K] ----------
__global__ void k_tb(const float* __restrict__ W, unsigned short* __restrict__ Wt,
                     int K, int C) {
    int idx = blockIdx.x * 256 + threadIdx.x;
    if (idx >= K * C) return;
    int k = idx / C, c = idx - k * C;
    Wt[c * K + k] = f2b(W[idx]);
}

// ---------- attention projection vectors, wave-parallel ----------
__global__ __launch_bounds__(256) void k_mku0(const float* __restrict__ W,
                                              const float* __restrict__ attS,
                                              const float* __restrict__ attD,
                                              float* __restrict__ u) {
    int lane = threadIdx.x & 63;
    int k = blockIdx.x * 4 + (threadIdx.x >> 6);
    if (k >= 256) return;
    int h = lane >> 3, c0 = lane & 7;
    const float* wr = W + (size_t)k * 256 + h * 32;
    float ss = 0.f, sd = 0.f;
    #pragma unroll
    for (int t = 0; t < 4; ++t) {
        int c = c0 + t * 8;
        float w = wr[c];
        ss += w * attS[h * 32 + c];
        sd += w * attD[h * 32 + c];
    }
    #pragma unroll
    for (int off = 1; off < 8; off <<= 1) {
        ss += __shfl_xor(ss, off);
        sd += __shfl_xor(sd, off);
    }
    if (c0 == 0) { u[k * 16 + h] = ss; u[k * 16 + 8 + h] = sd; }
}

__global__ __launch_bounds__(256) void k_mku1(const float* __restrict__ W,
                                              const float* __restrict__ attS,
                                              const float* __restrict__ attD,
                                              float* __restrict__ u, int C) {
    int lane = threadIdx.x & 63;
    int k = blockIdx.x * 4 + (threadIdx.x >> 6);
    if (k >= 256) return;
    const float* wr = W + (size_t)k * C;
    float ss = 0.f, sd = 0.f;
    for (int c = lane; c < C; c += 64) {
        float w = wr[c];
        ss += w * attS[c];
        sd += w * attD[c];
    }
    #pragma unroll
    for (int off = 32; off > 0; off >>= 1) {
        ss += __shfl_xor(ss, off);
        sd += __shfl_xor(sd, off);
    }
    if (lane == 0) { u[k * 2] = ss; u[k * 2 + 1] = sd; }
}

// ---------- CSR build: bucketed, low write-amplification ----------
__global__ __launch_bounds__(256) void k_bcount(const int* __restrict__ ei,
                                                int* __restrict__ bcnt) {
    __shared__ int h[NBUCK];
    for (int i = threadIdx.x; i < NBUCK; i += 256) h[i] = 0;
    __syncthreads();
    int e0 = blockIdx.x * 4096, e1 = min(e0 + 4096, ETOT);
    for (int e = e0 + threadIdx.x; e < e1; e += 256) {
        int dst = (e < N_EDGES) ? ei[N_EDGES + e] : (e - N_EDGES);
        atomicAdd(&h[dst >> 8], 1);
    }
    __syncthreads();
    for (int i = threadIdx.x; i < NBUCK; i += 256)
        if (h[i]) atomicAdd(&bcnt[i], h[i]);
}

__global__ void k_bscan(const int* __restrict__ bcnt, int* __restrict__ bstart,
                        int* __restrict__ bcursor) {
    __shared__ int tmp[256];
    int t = threadIdx.x;
    int v = (t < NBUCK) ? bcnt[t] : 0;
    tmp[t] = v;
    __syncthreads();
    for (int off = 1; off < 256; off <<= 1) {
        int u = (t >= off) ? tmp[t - off] : 0;
        __syncthreads();
        tmp[t] += u;
        __syncthreads();
    }
    int ex = tmp[t] - v;
    if (t < NBUCK) { bstart[t] = ex; bcursor[t] = ex; }
    if (t == 0) bstart[NBUCK] = ETOT;
}

__global__ __launch_bounds__(256) void k_bscatter(const int* __restrict__ ei,
                                                  int* __restrict__ bcursor,
                                                  unsigned int* __restrict__ stage) {
    __shared__ int h[NBUCK], base[NBUCK], cur[NBUCK], gbase[NBUCK];
    __shared__ int tmp[256];
    __shared__ unsigned int buf[8192];
    int t = threadIdx.x;
    for (int i = t; i < NBUCK; i += 256) h[i] = 0;
    __syncthreads();
    int e0 = blockIdx.x * 8192, e1 = min(e0 + 8192, ETOT);
    for (int e = e0 + t; e < e1; e += 256) {
        int dst = (e < N_EDGES) ? ei[N_EDGES + e] : (e - N_EDGES);
        atomicAdd(&h[dst >> 8], 1);
    }
    __syncthreads();
    int v = (t < NBUCK) ? h[t] : 0;
    tmp[t] = v;
    __syncthreads();
    for (int off = 1; off < 256; off <<= 1) {
        int u = (t >= off) ? tmp[t - off] : 0;
        __syncthreads();
        tmp[t] += u;
        __syncthreads();
    }
    if (t < NBUCK) { base[t] = tmp[t] - v; cur[t] = tmp[t] - v; }
    __syncthreads();
    for (int e = e0 + t; e < e1; e += 256) {
        int src, dst;
        if (e < N_EDGES) { src = ei[e]; dst = ei[N_EDGES + e]; }
        else             { src = dst = e - N_EDGES; }
        int b = dst >> 8;
        int p = atomicAdd(&cur[b], 1);
        buf[p] = ((unsigned int)b << 24) | ((unsigned int)src << 8) | (unsigned int)(dst & 255);
    }
    __syncthreads();
    if (t < NBUCK) gbase[t] = atomicAdd(&bcursor[t], h[t]);
    __syncthreads();
    int cnt = e1 - e0;
    for (int i = t; i < cnt; i += 256) {
        unsigned int pr = buf[i];
        int b = pr >> 24;
        stage[gbase[b] + (i - base[b])] = pr;
    }
}

__global__ __launch_bounds__(256) void k_csr(const unsigned int* __restrict__ stage,
                                             const int* __restrict__ bstart,
                                             int* __restrict__ rowptr, int* __restrict__ deg,
                                             unsigned short* __restrict__ csr) {
    __shared__ int cnt[256], cur[256], tmp[256];
    int b = blockIdx.x;
    int t = threadIdx.x;
    cnt[t] = 0;
    __syncthreads();
    int s0 = bstart[b], s1 = bstart[b + 1];
    for (int i = s0 + t; i < s1; i += 256)
        atomicAdd(&cnt[stage[i] & 255], 1);
    __syncthreads();
    int v = cnt[t];
    tmp[t] = v;
    __syncthreads();
    for (int off = 1; off < 256; off <<= 1) {
        int u = (t >= off) ? tmp[t - off] : 0;
        __syncthreads();
        tmp[t] += u;
        __syncthreads();
    }
    int ex = tmp[t] - v;
    int node = b * 256 + t;
    if (node < N_NODES) { rowptr[node] = s0 + ex; deg[node] = v; }
    cur[t] = s0 + ex;
    __syncthreads();
    for (int i = s0 + t; i < s1; i += 256) {
        unsigned int pr = stage[i];
        int p = atomicAdd(&cur[pr & 255], 1);
        csr[p] = (unsigned short)((pr >> 8) & 0xFFFF);
    }
}

// ---------- wide bf16 GEMM: 32rows x 128cols per wave; optional fp8 output ----------
template <bool FP8OUT>
__global__ __launch_bounds__(256) void k_gemm_w(
    const unsigned short* __restrict__ A, const unsigned short* __restrict__ Bt,
    void* __restrict__ Cout, int nrows, int ncols, int ldc) {
    const int K = 256;
    int lane = threadIdx.x & 63;
    int wave = threadIdx.x >> 6;
    int row0 = blockIdx.x * 128 + wave * 32;
    int col0 = blockIdx.y * 128;
    int ar0 = row0 + (lane & 15); if (ar0 >= nrows) ar0 = nrows - 1;
    int ar1 = row0 + 16 + (lane & 15); if (ar1 >= nrows) ar1 = nrows - 1;
    int ks = (lane >> 4) * 8;
    const unsigned short* Ap0 = A + (size_t)ar0 * K + ks;
    const unsigned short* Ap1 = A + (size_t)ar1 * K + ks;
    f32x4 acc[2][8];
    #pragma unroll
    for (int rt = 0; rt < 2; ++rt)
        #pragma unroll
        for (int ct = 0; ct < 8; ++ct) acc[rt][ct] = {0, 0, 0, 0};
    for (int k = 0; k < K; k += 32) {
        short8 a0 = *(const short8*)(Ap0 + k);
        short8 a1 = *(const short8*)(Ap1 + k);
        #pragma unroll
        for (int ct = 0; ct < 8; ++ct) {
            short8 b = *(const short8*)(Bt + (size_t)(col0 + ct * 16 + (lane & 15)) * K + k + ks);
            acc[0][ct] = __builtin_amdgcn_mfma_f32_16x16x32_bf16(a0, b, acc[0][ct], 0, 0, 0);
            acc[1][ct] = __builtin_amdgcn_mfma_f32_16x16x32_bf16(a1, b, acc[1][ct], 0, 0, 0);
        }
    }
    int cb = lane & 15;
    #pragma unroll
    for (int rt = 0; rt < 2; ++rt) {
        int rbase = row0 + rt * 16 + (lane >> 4) * 4;
        #pragma unroll
        for (int ct = 0; ct < 8; ++ct) {
            int cc = col0 + ct * 16 + cb;
            #pragma unroll
            for (int j = 0; j < 4; ++j) {
                float v = (cc < ncols) ? acc[rt][ct][j] : 0.f;
                if (FP8OUT)
                    ((unsigned char*)Cout)[(size_t)(rbase + j) * ldc + cc] = f2q(v);
                else
                    ((unsigned short*)Cout)[(size_t)(rbase + j) * ldc + cc] = f2b(v);
            }
        }
    }
}

// ---------- narrow bf16 GEMM (64 cols) for layer 2 ----------
__global__ __launch_bounds__(256) void k_gemm_b(
    const unsigned short* __restrict__ A, const unsigned short* __restrict__ Bt,
    unsigned short* __restrict__ Cout, int nrows, int ncols, int ldc) {
    const int K = 256;
    int lane = threadIdx.x & 63;
    int wave = threadIdx.x >> 6;
    int row0 = blockIdx.x * 128 + wave * 32;
    int ar0 = row0 + (lane & 15); if (ar0 >= nrows) ar0 = nrows - 1;
    int ar1 = row0 + 16 + (lane & 15); if (ar1 >= nrows) ar1 = nrows - 1;
    int ks = (lane >> 4) * 8;
    const unsigned short* Ap0 = A + (size_t)ar0 * K + ks;
    const unsigned short* Ap1 = A + (size_t)ar1 * K + ks;
    f32x4 acc[2][4] = {{{0,0,0,0},{0,0,0,0},{0,0,0,0},{0,0,0,0}},
                       {{0,0,0,0},{0,0,0,0},{0,0,0,0},{0,0,0,0}}};
    for (int k = 0; k < K; k += 32) {
        short8 a0 = *(const short8*)(Ap0 + k);
        short8 a1 = *(const short8*)(Ap1 + k);
        #pragma unroll
        for (int ct = 0; ct < 4; ++ct) {
            short8 b = *(const short8*)(Bt + (size_t)(ct * 16 + (lane & 15)) * K + k + ks);
            acc[0][ct] = __builtin_amdgcn_mfma_f32_16x16x32_bf16(a0, b, acc[0][ct], 0, 0, 0);
            acc[1][ct] = __builtin_amdgcn_mfma_f32_16x16x32_bf16(a1, b, acc[1][ct], 0, 0, 0);
        }
    }
    int cb = lane & 15;
    #pragma unroll
    for (int rt = 0; rt < 2; ++rt) {
        int rbase = row0 + rt * 16 + (lane >> 4) * 4;
        #pragma unroll
        for (int ct = 0; ct < 4; ++ct) {
            int cc = ct * 16 + cb;
            #pragma unroll
            for (int j = 0; j < 4; ++j) {
                float v = (cc < ncols) ? acc[rt][ct][j] : 0.f;
                Cout[(size_t)(rbase + j) * ldc + cc] = f2b(v);
            }
        }
    }
}

// ---------- fused: x f32 -> xb bf16 + layer-0 attention logits ----------
template <int NC>
__global__ __launch_bounds__(256) void k_splitatt(
    const float* __restrict__ x, const float* __restrict__ u,
    unsigned short* __restrict__ xb,
    float* __restrict__ asrc, float* __restrict__ adst) {
    int lane = threadIdx.x & 63;
    int node = blockIdx.x * 4 + (threadIdx.x >> 6);
    if (node >= N_NODES) return;
    int k0 = lane * 4;
    float4 v = *(const float4*)(x + (size_t)node * 256 + k0);
    float xv[4] = {v.x, v.y, v.z, v.w};
    ushort4 w;
    w.x = f2b(v.x); w.y = f2b(v.y); w.z = f2b(v.z); w.w = f2b(v.w);
    *(ushort4*)(xb + (size_t)node * 256 + k0) = w;
    float acc[NC];
    #pragma unroll
    for (int j = 0; j < NC; ++j) acc[j] = 0.f;
    #pragma unroll
    for (int i = 0; i < 4; ++i)
        #pragma unroll
        for (int j = 0; j < NC; ++j)
            acc[j] += xv[i] * u[(size_t)(k0 + i) * NC + j];
    #pragma unroll
    for (int off = 32; off > 0; off >>= 1)
        #pragma unroll
        for (int j = 0; j < NC; ++j)
            acc[j] += __shfl_xor(acc[j], off);
    if (lane == 0) {
        const int H = NC / 2;
        #pragma unroll
        for (int h = 0; h < H; ++h) {
            asrc[(size_t)node * H + h] = acc[h];
            adst[(size_t)node * H + h] = acc[H + h];
        }
    }
}

// ---------- layer-0 gather: fp8 messages, 16 lanes/edge, 4 edges in flight ----------
__global__ __launch_bounds__(256) void k_gather8q(
    const unsigned char* __restrict__ xq,      // fp8 [NP,256]
    const float* __restrict__ asrc, const float* __restrict__ adst,  // [N,8]
    const int* __restrict__ rowptr, const int* __restrict__ deg,
    const unsigned short* __restrict__ csr,
    const float* __restrict__ bias,            // f32 [256]
    const float* __restrict__ un,              // f32 [256*2] (next-layer u)
    unsigned short* __restrict__ o,            // bf16 [NP,256]
    float* __restrict__ asn, float* __restrict__ adn) {
    int lane = threadIdx.x & 63;
    int node = blockIdx.x * 4 + (threadIdx.x >> 6);
    if (node >= N_NODES) return;
    int ptr = rowptr[node], dg = deg[node];
    int g = lane >> 4, l4 = lane & 15;
    int cbase = l4 * 16;
    int head = l4 >> 1;
    float ad = adst[(size_t)node * 8 + head];
    float acc[16];
    #pragma unroll
    for (int j = 0; j < 16; ++j) acc[j] = 0.f;
    float den = 0.f;
    int dge = (dg + 3) & ~3;
    int i = g;
    int ci = ptr + min(i, dg - 1);
    int sn0 = csr[ci];
    float e0 = asrc[(size_t)sn0 * 8 + head];
    uint4 v0 = *(const uint4*)(xq + (size_t)sn0 * 256 + cbase);
    bool ok0 = (i < dg);
    while (i < dge) {
        int in = i + 4;
        int cn = ptr + min(in, dg - 1);
        int sn1 = csr[cn];
        float e1 = asrc[(size_t)sn1 * 8 + head];
        uint4 v1 = *(const uint4*)(xq + (size_t)sn1 * 256 + cbase);
        float e = e0 + ad;
        e = (e >= 0.f) ? e : 0.2f * e;
        float a0 = ok0 ? __expf(fminf(e, 70.f)) : 0.f;
        den += a0;
        f32x2 f;
        f = __builtin_amdgcn_cvt_pk_f32_fp8(v0.x, false); acc[0] += a0 * f.x;  acc[1] += a0 * f.y;
        f = __builtin_amdgcn_cvt_pk_f32_fp8(v0.x, true);  acc[2] += a0 * f.x;  acc[3] += a0 * f.y;
        f = __builtin_amdgcn_cvt_pk_f32_fp8(v0.y, false); acc[4] += a0 * f.x;  acc[5] += a0 * f.y;
        f = __builtin_amdgcn_cvt_pk_f32_fp8(v0.y, true);  acc[6] += a0 * f.x;  acc[7] += a0 * f.y;
        f = __builtin_amdgcn_cvt_pk_f32_fp8(v0.z, false); acc[8] += a0 * f.x;  acc[9] += a0 * f.y;
        f = __builtin_amdgcn_cvt_pk_f32_fp8(v0.z, true);  acc[10] += a0 * f.x; acc[11] += a0 * f.y;
        f = __builtin_amdgcn_cvt_pk_f32_fp8(v0.w, false); acc[12] += a0 * f.x; acc[13] += a0 * f.y;
        f = __builtin_amdgcn_cvt_pk_f32_fp8(v0.w, true);  acc[14] += a0 * f.x; acc[15] += a0 * f.y;
        i = in; e0 = e1; v0 = v1; ok0 = (in < dg);
    }
    den += __shfl_xor(den, 16);
    den += __shfl_xor(den, 32);
    #pragma unroll
    for (int j = 0; j < 16; ++j) {
        acc[j] += __shfl_xor(acc[j], 16);
        acc[j] += __shfl_xor(acc[j], 32);
    }
    if (g) return;
    float inv = 1.0f / den;
    float sN = 0.f, dN = 0.f;
    short8 w0, w1;
    #pragma unroll
    for (int j = 0; j < 16; ++j) {
        int c = cbase + j;
        float v = acc[j] * inv + bias[c];
        v = (v > 0.f) ? v : (__expf(v) - 1.f);   // ELU
        unsigned short bb = f2b(v);
        if (j < 8) w0[j] = (short)bb; else w1[j - 8] = (short)bb;
        sN += v * un[c * 2];
        dN += v * un[c * 2 + 1];
    }
    *(short8*)(o + (size_t)node * 256 + cbase) = w0;
    *(short8*)(o + (size_t)node * 256 + cbase + 8) = w1;
    #pragma unroll
    for (int off = 8; off > 0; off >>= 1) {
        sN += __shfl_xor(sN, off);
        dN += __shfl_xor(dN, off);
    }
    if (l4 == 0) { asn[node] = sN; adn[node] = dN; }
}

// ---------- bf16 gather (layer 1): 16 lanes/edge, 4 edges in flight ----------
template <int H, bool FUSE>
__global__ __launch_bounds__(256) void k_gather(
    const unsigned short* __restrict__ xp,     // bf16 [NP,256]
    const float* __restrict__ asrc, const float* __restrict__ adst,
    const int* __restrict__ rowptr, const int* __restrict__ deg,
    const unsigned short* __restrict__ csr,
    const float* __restrict__ bias,            // f32 [256]
    const float* __restrict__ un,              // f32 [256*2] or null
    unsigned short* __restrict__ o,            // bf16 [NP,256]
    float* __restrict__ asn, float* __restrict__ adn) {
    int lane = threadIdx.x & 63;
    int node = blockIdx.x * 4 + (threadIdx.x >> 6);
    if (node >= N_NODES) return;
    int ptr = rowptr[node], dg = deg[node];
    int g = lane >> 4, l4 = lane & 15;
    int cbase = l4 * 16;
    int head = (H == 8) ? (l4 >> 1) : 0;
    float ad = adst[(size_t)node * H + head];
    float acc[16];
    #pragma unroll
    for (int j = 0; j < 16; ++j) acc[j] = 0.f;
    float den = 0.f;
    int dge = (dg + 3) & ~3;
    int i = g;
    int ci = ptr + min(i, dg - 1);
    int sn0 = csr[ci];
    float e0 = asrc[(size_t)sn0 * H + head];
    const unsigned short* xr0 = xp + (size_t)sn0 * 256 + cbase;
    short8 va0 = *(const short8*)(xr0);
    short8 vb0 = *(const short8*)(xr0 + 8);
    bool ok0 = (i < dg);
    while (i < dge) {
        int in = i + 4;
        int cn = ptr + min(in, dg - 1);
        int sn1 = csr[cn];
        float e1 = asrc[(size_t)sn1 * H + head];
        const unsigned short* xr1 = xp + (size_t)sn1 * 256 + cbase;
        short8 va1 = *(const short8*)(xr1);
        short8 vb1 = *(const short8*)(xr1 + 8);
        float e = e0 + ad;
        e = (e >= 0.f) ? e : 0.2f * e;
        float a0 = ok0 ? __expf(fminf(e, 70.f)) : 0.f;
        den += a0;
        #pragma unroll
        for (int j = 0; j < 8; ++j) acc[j] += a0 * b2f((unsigned short)va0[j]);
        #pragma unroll
        for (int j = 0; j < 8; ++j) acc[8 + j] += a0 * b2f((unsigned short)vb0[j]);
        i = in; e0 = e1; va0 = va1; vb0 = vb1; ok0 = (in < dg);
    }
    den += __shfl_xor(den, 16);
    den += __shfl_xor(den, 32);
    #pragma unroll
    for (int j = 0; j < 16; ++j) {
        acc[j] += __shfl_xor(acc[j], 16);
        acc[j] += __shfl_xor(acc[j], 32);
    }
    if (g) return;
    float inv = 1.0f / den;
    float sN = 0.f, dN = 0.f;
    short8 w0, w1;
    #pragma unroll
    for (int j = 0; j < 16; ++j) {
        int c = cbase + j;
        float v = acc[j] * inv + bias[c];
        v = (v > 0.f) ? v : (__expf(v) - 1.f);   // ELU
        unsigned short bb = f2b(v);
        if (j < 8) w0[j] = (short)bb; else w1[j - 8] = (short)bb;
        if (FUSE) {
            sN += v * un[c * 2];
            dN += v * un[c * 2 + 1];
        }
    }
    *(short8*)(o + (size_t)node * 256 + cbase) = w0;
    *(short8*)(o + (size_t)node * 256 + cbase + 8) = w1;
    if (FUSE) {
        #pragma unroll
        for (int off = 8; off > 0; off >>= 1) {
            sN += __shfl_xor(sN, off);
            dN += __shfl_xor(dN, off);
        }
        if (l4 == 0) { asn[node] = sN; adn[node] = dN; }
    }
}

// ---------- final gather: 8 lanes/edge, 8 edges in flight + log_softmax ----------
__global__ __launch_bounds__(256) void k_gf(
    const unsigned short* __restrict__ xp,     // bf16 [NP,64]
    const float* __restrict__ asrc, const float* __restrict__ adst,
    const int* __restrict__ rowptr, const int* __restrict__ deg,
    const unsigned short* __restrict__ csr,
    const float* __restrict__ bias,            // f32 [40]
    float* __restrict__ out) {                 // f32 [N,40]
    int lane = threadIdx.x & 63;
    int node = blockIdx.x * 4 + (threadIdx.x >> 6);
    if (node >= N_NODES) return;
    int ptr = rowptr[node], dg = deg[node];
    int g = lane >> 3, l8 = lane & 7;
    int cbase = l8 * 8;
    float ad = adst[node];
    float acc[8] = {0,0,0,0,0,0,0,0};
    float den = 0.f;
    int dge = (dg + 7) & ~7;
    int i = g;
    int ci = ptr + min(i, dg - 1);
    int sn0 = csr[ci];
    float e0 = asrc[sn0];
    short8 v0 = *(const short8*)(xp + (size_t)sn0 * 64 + cbase);
    bool ok0 = (i < dg);
    while (i < dge) {
        int in = i + 8;
        int cn = ptr + min(in, dg - 1);
        int sn1 = csr[cn];
        float e1 = asrc[sn1];
        short8 v1 = *(const short8*)(xp + (size_t)sn1 * 64 + cbase);
        float e = e0 + ad;
        e = (e >= 0.f) ? e : 0.2f * e;
        float a0 = ok0 ? __expf(fminf(e, 70.f)) : 0.f;
        den += a0;
        #pragma unroll
        for (int j = 0; j < 8; ++j) acc[j] += a0 * b2f((unsigned short)v0[j]);
        i = in; e0 = e1; v0 = v1; ok0 = (in < dg);
    }
    den += __shfl_xor(den, 8);
    den += __shfl_xor(den, 16);
    den += __shfl_xor(den, 32);
    #pragma unroll
    for (int j = 0; j < 8; ++j) {
        acc[j] += __shfl_xor(acc[j], 8);
        acc[j] += __shfl_xor(acc[j], 16);
        acc[j] += __shfl_xor(acc[j], 32);
    }
    if (g) return;
    float inv = 1.0f / den;
    float val[8], mx = -1e30f;
    #pragma unroll
    for (int j = 0; j < 8; ++j) {
        int c = cbase + j;
        val[j] = (c < 40) ? acc[j] * inv + bias[c] : -1e30f;
        mx = fmaxf(mx, val[j]);
    }
    #pragma unroll
    for (int off = 4; off > 0; off >>= 1) mx = fmaxf(mx, __shfl_xor(mx, off));
    float ex = 0.f;
    #pragma unroll
    for (int j = 0; j < 8; ++j) {
        int c = cbase + j;
        if (c < 40) ex += __expf(val[j] - mx);
    }
    #pragma unroll
    for (int off = 4; off > 0; off >>= 1) ex += __shfl_xor(ex, off);
    float lse = __logf(ex);
    #pragma unroll
    for (int j = 0; j < 8; ++j) {
        int c = cbase + j;
        if (c < 40) out[(size_t)node * 40 + c] = val[j] - mx - lse;
    }
}

extern "C" void kernel_launch(void* const* d_in, const int* in_sizes, int n_in,
                              void* d_out, int out_size, void* d_ws, size_t ws_size,
                              hipStream_t stream) {
    const float* x   = (const float*)d_in[0];
    const int*   ei  = (const int*)d_in[1];
    const float* W0  = (const float*)d_in[2];
    const float* as0 = (const float*)d_in[3];
    const float* ad0 = (const float*)d_in[4];
    const float* b0  = (const float*)d_in[5];
    const float* W1  = (const float*)d_in[6];
    const float* as1 = (const float*)d_in[7];
    const float* ad1 = (const float*)d_in[8];
    const float* b1  = (const float*)d_in[9];
    const float* W2  = (const float*)d_in[10];
    const float* as2 = (const float*)d_in[11];
    const float* ad2 = (const float*)d_in[12];
    const float* b2  = (const float*)d_in[13];
    float* out = (float*)d_out;

    char* p = (char*)d_ws;
    auto carve = [&](size_t bytes) -> char* {
        char* r = p; p += (bytes + 255) & ~(size_t)255; return r;
    };
    unsigned short* xb   = (unsigned short*)carve((size_t)NP * 256 * 2);  // x bf16, later h2
    unsigned short* xpb  = (unsigned short*)carve((size_t)NP * 256 * 2);  // messages (bf16 or fp8)
    unsigned short* h    = (unsigned short*)carve((size_t)NP * 256 * 2);  // h1
    unsigned short* xp2b = (unsigned short*)carve((size_t)NP * 64 * 2);
    unsigned short* Wt0  = (unsigned short*)carve(256 * 256 * 2);
    unsigned short* Wt1  = (unsigned short*)carve(256 * 256 * 2);
    unsigned short* Wt2  = (unsigned short*)carve(64 * 256 * 2);
    float* u0 = (float*)carve(256 * 16 * 4);
    float* u1 = (float*)carve(256 * 2 * 4);
    float* u2 = (float*)carve(256 * 2 * 4);
    float* asrc0 = (float*)carve((size_t)N_NODES * 8 * 4);
    float* adst0 = (float*)carve((size_t)N_NODES * 8 * 4);
    float* asrc1 = (float*)carve((size_t)N_NODES * 4);
    float* adst1 = (float*)carve((size_t)N_NODES * 4);
    float* asrc2 = (float*)carve((size_t)N_NODES * 4);
    float* adst2 = (float*)carve((size_t)N_NODES * 4);
    int* deg    = (int*)carve((size_t)N_NODES * 4);
    int* rowptr = (int*)carve((size_t)N_NODES * 4);
    int* bcnt   = (int*)carve((size_t)NBUCK * 4);
    int* bstart = (int*)carve((size_t)(NBUCK + 1) * 4);
    int* bcursor= (int*)carve((size_t)NBUCK * 4);
    unsigned int* stage = (unsigned int*)carve((size_t)ETOT * 4);
    unsigned short* csr = (unsigned short*)carve((size_t)ETOT * 2);
    unsigned char* xq = (unsigned char*)xpb;   // fp8 layer-0 messages overlay

    hipMemsetAsync(bcnt, 0, (size_t)NBUCK * 4, stream);
    hipMemsetAsync(Wt2, 0, 64 * 256 * 2, stream);  // zero pad cols 40..63

    k_tb<<<(256 * 256 + 255) / 256, 256, 0, stream>>>(W0, Wt0, 256, 256);
    k_tb<<<(256 * 256 + 255) / 256, 256, 0, stream>>>(W1, Wt1, 256, 256);
    k_tb<<<(256 * 40 + 255) / 256, 256, 0, stream>>>(W2, Wt2, 256, 40);

    k_mku0<<<64, 256, 0, stream>>>(W0, as0, ad0, u0);
    k_mku1<<<64, 256, 0, stream>>>(W1, as1, ad1, u1, 256);
    k_mku1<<<64, 256, 0, stream>>>(W2, as2, ad2, u2, 40);

    k_bcount<<<(ETOT + 4095) / 4096, 256, 0, stream>>>(ei, bcnt);
    k_bscan<<<1, 256, 0, stream>>>(bcnt, bstart, bcursor);
    k_bscatter<<<(ETOT + 8191) / 8192, 256, 0, stream>>>(ei, bcursor, stage);
    k_csr<<<NBUCK, 256, 0, stream>>>(stage, bstart, rowptr, deg, csr);

    dim3 gg(NP / 128, 2);
    dim3 gn(N_NODES / 4);
    // layer 0: messages in fp8
    k_splitatt<16><<<gn, 256, 0, stream>>>(x, u0, xb, asrc0, adst0);
    k_gemm_w<true><<<gg, 256, 0, stream>>>(xb, Wt0, xq, N_NODES, 256, 256);
    k_gather8q<<<gn, 256, 0, stream>>>(xq, asrc0, adst0, rowptr, deg, csr,
                                       b0, u1, h, asrc1, adst1);
    // layer 1: messages in bf16
    k_gemm_w<false><<<gg, 256, 0, stream>>>(h, Wt1, xpb, N_NODES, 256, 256);
    k_gather<1, true><<<gn, 256, 0, stream>>>(xpb, asrc1, adst1, rowptr, deg, csr,
                                              b1, u2, xb, asrc2, adst2);
    // layer 2
    dim3 g2(NP / 128);
    k_gemm_b<<<g2, 256, 0, stream>>>(xb, Wt2, xp2b, N_NODES, 40, 64);
    k_gf<<<gn, 256, 0, stream>>>(xp2b, asrc2, adst2, rowptr, deg, csr, b2, out);
}

// Round 10
// 497.227 us; speedup vs baseline: 2.7780x; 1.0696x over previous
//
#include <hip/hip_runtime.h>
#include <hip/hip_bf16.h>

#define N_NODES 50000
#define N_EDGES 1600000
#define ETOT (N_EDGES + N_NODES)
#define NP 50048   // N padded for GEMM row tiles (391 * 128)
#define NBUCK 196  // dst >> 8 buckets (50000/256)

typedef __attribute__((ext_vector_type(8))) short short8;
typedef __attribute__((ext_vector_type(4))) float f32x4;
typedef __attribute__((ext_vector_type(2))) float f32x2;

__device__ __forceinline__ float b2f(unsigned short u) {
    union { unsigned int i; float f; } v; v.i = ((unsigned int)u) << 16; return v.f;
}
__device__ __forceinline__ unsigned short f2b(float f) {
    union { float f; unsigned int i; } v; v.f = f;
    unsigned int r = v.i + 0x7FFF + ((v.i >> 16) & 1);  // RNE
    return (unsigned short)(r >> 16);
}
__device__ __forceinline__ unsigned char f2q(float f) {
    int r = __builtin_amdgcn_cvt_pk_fp8_f32(f, f, 0, false);
    return (unsigned char)(r & 0xFF);
}

// ---------- weight transpose to bf16: W f32 [K,C] -> Wt bf16 [C,K] ----------
__global__ void k_tb(const float* __restrict__ W, unsigned short* __restrict__ Wt,
                     int K, int C) {
    int idx = blockIdx.x * 256 + threadIdx.x;
    if (idx >= K * C) return;
    int k = idx / C, c = idx - k * C;
    Wt[c * K + k] = f2b(W[idx]);
}

// ---------- attention projection vectors, wave-parallel ----------
__global__ __launch_bounds__(256) void k_mku0(const float* __restrict__ W,
                                              const float* __restrict__ attS,
                                              const float* __restrict__ attD,
                                              float* __restrict__ u) {
    int lane = threadIdx.x & 63;
    int k = blockIdx.x * 4 + (threadIdx.x >> 6);
    if (k >= 256) return;
    int h = lane >> 3, c0 = lane & 7;
    const float* wr = W + (size_t)k * 256 + h * 32;
    float ss = 0.f, sd = 0.f;
    #pragma unroll
    for (int t = 0; t < 4; ++t) {
        int c = c0 + t * 8;
        float w = wr[c];
        ss += w * attS[h * 32 + c];
        sd += w * attD[h * 32 + c];
    }
    #pragma unroll
    for (int off = 1; off < 8; off <<= 1) {
        ss += __shfl_xor(ss, off);
        sd += __shfl_xor(sd, off);
    }
    if (c0 == 0) { u[k * 16 + h] = ss; u[k * 16 + 8 + h] = sd; }
}

__global__ __launch_bounds__(256) void k_mku1(const float* __restrict__ W,
                                              const float* __restrict__ attS,
                                              const float* __restrict__ attD,
                                              float* __restrict__ u, int C) {
    int lane = threadIdx.x & 63;
    int k = blockIdx.x * 4 + (threadIdx.x >> 6);
    if (k >= 256) return;
    const float* wr = W + (size_t)k * C;
    float ss = 0.f, sd = 0.f;
    for (int c = lane; c < C; c += 64) {
        float w = wr[c];
        ss += w * attS[c];
        sd += w * attD[c];
    }
    #pragma unroll
    for (int off = 32; off > 0; off >>= 1) {
        ss += __shfl_xor(ss, off);
        sd += __shfl_xor(sd, off);
    }
    if (lane == 0) { u[k * 2] = ss; u[k * 2 + 1] = sd; }
}

// ---------- CSR build: bucketed, low write-amplification ----------
__global__ __launch_bounds__(256) void k_bcount(const int* __restrict__ ei,
                                                int* __restrict__ bcnt) {
    __shared__ int h[NBUCK];
    for (int i = threadIdx.x; i < NBUCK; i += 256) h[i] = 0;
    __syncthreads();
    int e0 = blockIdx.x * 4096, e1 = min(e0 + 4096, ETOT);
    for (int e = e0 + threadIdx.x; e < e1; e += 256) {
        int dst = (e < N_EDGES) ? ei[N_EDGES + e] : (e - N_EDGES);
        atomicAdd(&h[dst >> 8], 1);
    }
    __syncthreads();
    for (int i = threadIdx.x; i < NBUCK; i += 256)
        if (h[i]) atomicAdd(&bcnt[i], h[i]);
}

__global__ void k_bscan(const int* __restrict__ bcnt, int* __restrict__ bstart,
                        int* __restrict__ bcursor) {
    __shared__ int tmp[256];
    int t = threadIdx.x;
    int v = (t < NBUCK) ? bcnt[t] : 0;
    tmp[t] = v;
    __syncthreads();
    for (int off = 1; off < 256; off <<= 1) {
        int u = (t >= off) ? tmp[t - off] : 0;
        __syncthreads();
        tmp[t] += u;
        __syncthreads();
    }
    int ex = tmp[t] - v;
    if (t < NBUCK) { bstart[t] = ex; bcursor[t] = ex; }
    if (t == 0) bstart[NBUCK] = ETOT;
}

__global__ __launch_bounds__(256) void k_bscatter(const int* __restrict__ ei,
                                                  int* __restrict__ bcursor,
                                                  unsigned int* __restrict__ stage) {
    __shared__ int h[NBUCK], base[NBUCK], cur[NBUCK], gbase[NBUCK];
    __shared__ int tmp[256];
    __shared__ unsigned int buf[8192];
    int t = threadIdx.x;
    for (int i = t; i < NBUCK; i += 256) h[i] = 0;
    __syncthreads();
    int e0 = blockIdx.x * 8192, e1 = min(e0 + 8192, ETOT);
    for (int e = e0 + t; e < e1; e += 256) {
        int dst = (e < N_EDGES) ? ei[N_EDGES + e] : (e - N_EDGES);
        atomicAdd(&h[dst >> 8], 1);
    }
    __syncthreads();
    int v = (t < NBUCK) ? h[t] : 0;
    tmp[t] = v;
    __syncthreads();
    for (int off = 1; off < 256; off <<= 1) {
        int u = (t >= off) ? tmp[t - off] : 0;
        __syncthreads();
        tmp[t] += u;
        __syncthreads();
    }
    if (t < NBUCK) { base[t] = tmp[t] - v; cur[t] = tmp[t] - v; }
    __syncthreads();
    for (int e = e0 + t; e < e1; e += 256) {
        int src, dst;
        if (e < N_EDGES) { src = ei[e]; dst = ei[N_EDGES + e]; }
        else             { src = dst = e - N_EDGES; }
        int b = dst >> 8;
        int p = atomicAdd(&cur[b], 1);
        buf[p] = ((unsigned int)b << 24) | ((unsigned int)src << 8) | (unsigned int)(dst & 255);
    }
    __syncthreads();
    if (t < NBUCK) gbase[t] = atomicAdd(&bcursor[t], h[t]);
    __syncthreads();
    int cnt = e1 - e0;
    for (int i = t; i < cnt; i += 256) {
        unsigned int pr = buf[i];
        int b = pr >> 24;
        stage[gbase[b] + (i - base[b])] = pr;
    }
}

__global__ __launch_bounds__(256) void k_csr(const unsigned int* __restrict__ stage,
                                             const int* __restrict__ bstart,
                                             int* __restrict__ rowptr, int* __restrict__ deg,
                                             unsigned short* __restrict__ csr) {
    __shared__ int cnt[256], cur[256], tmp[256];
    int b = blockIdx.x;
    int t = threadIdx.x;
    cnt[t] = 0;
    __syncthreads();
    int s0 = bstart[b], s1 = bstart[b + 1];
    for (int i = s0 + t; i < s1; i += 256)
        atomicAdd(&cnt[stage[i] & 255], 1);
    __syncthreads();
    int v = cnt[t];
    tmp[t] = v;
    __syncthreads();
    for (int off = 1; off < 256; off <<= 1) {
        int u = (t >= off) ? tmp[t - off] : 0;
        __syncthreads();
        tmp[t] += u;
        __syncthreads();
    }
    int ex = tmp[t] - v;
    int node = b * 256 + t;
    if (node < N_NODES) { rowptr[node] = s0 + ex; deg[node] = v; }
    cur[t] = s0 + ex;
    __syncthreads();
    for (int i = s0 + t; i < s1; i += 256) {
        unsigned int pr = stage[i];
        int p = atomicAdd(&cur[pr & 255], 1);
        csr[p] = (unsigned short)((pr >> 8) & 0xFFFF);
    }
}

// ---------- wide bf16 GEMM: 32rows x 128cols per wave; optional fp8 output ----------
template <bool FP8OUT>
__global__ __launch_bounds__(256) void k_gemm_w(
    const unsigned short* __restrict__ A, const unsigned short* __restrict__ Bt,
    void* __restrict__ Cout, int nrows, int ncols, int ldc) {
    const int K = 256;
    int lane = threadIdx.x & 63;
    int wave = threadIdx.x >> 6;
    int row0 = blockIdx.x * 128 + wave * 32;
    int col0 = blockIdx.y * 128;
    int ar0 = row0 + (lane & 15); if (ar0 >= nrows) ar0 = nrows - 1;
    int ar1 = row0 + 16 + (lane & 15); if (ar1 >= nrows) ar1 = nrows - 1;
    int ks = (lane >> 4) * 8;
    const unsigned short* Ap0 = A + (size_t)ar0 * K + ks;
    const unsigned short* Ap1 = A + (size_t)ar1 * K + ks;
    f32x4 acc[2][8];
    #pragma unroll
    for (int rt = 0; rt < 2; ++rt)
        #pragma unroll
        for (int ct = 0; ct < 8; ++ct) acc[rt][ct] = {0, 0, 0, 0};
    for (int k = 0; k < K; k += 32) {
        short8 a0 = *(const short8*)(Ap0 + k);
        short8 a1 = *(const short8*)(Ap1 + k);
        #pragma unroll
        for (int ct = 0; ct < 8; ++ct) {
            short8 b = *(const short8*)(Bt + (size_t)(col0 + ct * 16 + (lane & 15)) * K + k + ks);
            acc[0][ct] = __builtin_amdgcn_mfma_f32_16x16x32_bf16(a0, b, acc[0][ct], 0, 0, 0);
            acc[1][ct] = __builtin_amdgcn_mfma_f32_16x16x32_bf16(a1, b, acc[1][ct], 0, 0, 0);
        }
    }
    int cb = lane & 15;
    #pragma unroll
    for (int rt = 0; rt < 2; ++rt) {
        int rbase = row0 + rt * 16 + (lane >> 4) * 4;
        #pragma unroll
        for (int ct = 0; ct < 8; ++ct) {
            int cc = col0 + ct * 16 + cb;
            #pragma unroll
            for (int j = 0; j < 4; ++j) {
                float v = (cc < ncols) ? acc[rt][ct][j] : 0.f;
                if (FP8OUT)
                    ((unsigned char*)Cout)[(size_t)(rbase + j) * ldc + cc] = f2q(v);
                else
                    ((unsigned short*)Cout)[(size_t)(rbase + j) * ldc + cc] = f2b(v);
            }
        }
    }
}

// ---------- narrow bf16 GEMM (64 cols) for layer 2 ----------
__global__ __launch_bounds__(256) void k_gemm_b(
    const unsigned short* __restrict__ A, const unsigned short* __restrict__ Bt,
    unsigned short* __restrict__ Cout, int nrows, int ncols, int ldc) {
    const int K = 256;
    int lane = threadIdx.x & 63;
    int wave = threadIdx.x >> 6;
    int row0 = blockIdx.x * 128 + wave * 32;
    int ar0 = row0 + (lane & 15); if (ar0 >= nrows) ar0 = nrows - 1;
    int ar1 = row0 + 16 + (lane & 15); if (ar1 >= nrows) ar1 = nrows - 1;
    int ks = (lane >> 4) * 8;
    const unsigned short* Ap0 = A + (size_t)ar0 * K + ks;
    const unsigned short* Ap1 = A + (size_t)ar1 * K + ks;
    f32x4 acc[2][4] = {{{0,0,0,0},{0,0,0,0},{0,0,0,0},{0,0,0,0}},
                       {{0,0,0,0},{0,0,0,0},{0,0,0,0},{0,0,0,0}}};
    for (int k = 0; k < K; k += 32) {
        short8 a0 = *(const short8*)(Ap0 + k);
        short8 a1 = *(const short8*)(Ap1 + k);
        #pragma unroll
        for (int ct = 0; ct < 4; ++ct) {
            short8 b = *(const short8*)(Bt + (size_t)(ct * 16 + (lane & 15)) * K + k + ks);
            acc[0][ct] = __builtin_amdgcn_mfma_f32_16x16x32_bf16(a0, b, acc[0][ct], 0, 0, 0);
            acc[1][ct] = __builtin_amdgcn_mfma_f32_16x16x32_bf16(a1, b, acc[1][ct], 0, 0, 0);
        }
    }
    int cb = lane & 15;
    #pragma unroll
    for (int rt = 0; rt < 2; ++rt) {
        int rbase = row0 + rt * 16 + (lane >> 4) * 4;
        #pragma unroll
        for (int ct = 0; ct < 4; ++ct) {
            int cc = ct * 16 + cb;
            #pragma unroll
            for (int j = 0; j < 4; ++j) {
                float v = (cc < ncols) ? acc[rt][ct][j] : 0.f;
                Cout[(size_t)(rbase + j) * ldc + cc] = f2b(v);
            }
        }
    }
}

// ---------- fused: x f32 -> xb bf16 + layer-0 attention logits ----------
template <int NC>
__global__ __launch_bounds__(256) void k_splitatt(
    const float* __restrict__ x, const float* __restrict__ u,
    unsigned short* __restrict__ xb,
    float* __restrict__ asrc, float* __restrict__ adst) {
    int lane = threadIdx.x & 63;
    int node = blockIdx.x * 4 + (threadIdx.x >> 6);
    if (node >= N_NODES) return;
    int k0 = lane * 4;
    float4 v = *(const float4*)(x + (size_t)node * 256 + k0);
    float xv[4] = {v.x, v.y, v.z, v.w};
    ushort4 w;
    w.x = f2b(v.x); w.y = f2b(v.y); w.z = f2b(v.z); w.w = f2b(v.w);
    *(ushort4*)(xb + (size_t)node * 256 + k0) = w;
    float acc[NC];
    #pragma unroll
    for (int j = 0; j < NC; ++j) acc[j] = 0.f;
    #pragma unroll
    for (int i = 0; i < 4; ++i)
        #pragma unroll
        for (int j = 0; j < NC; ++j)
            acc[j] += xv[i] * u[(size_t)(k0 + i) * NC + j];
    #pragma unroll
    for (int off = 32; off > 0; off >>= 1)
        #pragma unroll
        for (int j = 0; j < NC; ++j)
            acc[j] += __shfl_xor(acc[j], off);
    if (lane == 0) {
        const int H = NC / 2;
        #pragma unroll
        for (int h = 0; h < H; ++h) {
            asrc[(size_t)node * H + h] = acc[h];
            adst[(size_t)node * H + h] = acc[H + h];
        }
    }
}

// ---------- fp8 gather (layers 0 & 1): 16 lanes/edge, 4 edges in flight ----------
template <int H>
__global__ __launch_bounds__(256) void k_gatherq(
    const unsigned char* __restrict__ xq,      // fp8 [NP,256]
    const float* __restrict__ asrc, const float* __restrict__ adst,  // [N,H]
    const int* __restrict__ rowptr, const int* __restrict__ deg,
    const unsigned short* __restrict__ csr,
    const float* __restrict__ bias,            // f32 [256]
    const float* __restrict__ un,              // f32 [256*2] (next-layer u)
    unsigned short* __restrict__ o,            // bf16 [NP,256]
    float* __restrict__ asn, float* __restrict__ adn) {
    int lane = threadIdx.x & 63;
    int node = blockIdx.x * 4 + (threadIdx.x >> 6);
    if (node >= N_NODES) return;
    int ptr = rowptr[node], dg = deg[node];
    int g = lane >> 4, l4 = lane & 15;
    int cbase = l4 * 16;
    int head = (H == 8) ? (l4 >> 1) : 0;
    float ad = adst[(size_t)node * H + head];
    float acc[16];
    #pragma unroll
    for (int j = 0; j < 16; ++j) acc[j] = 0.f;
    float den = 0.f;
    int dge = (dg + 3) & ~3;
    int i = g;
    int ci = ptr + min(i, dg - 1);
    int sn0 = csr[ci];
    float e0 = asrc[(size_t)sn0 * H + head];
    uint4 v0 = *(const uint4*)(xq + (size_t)sn0 * 256 + cbase);
    bool ok0 = (i < dg);
    while (i < dge) {
        int in = i + 4;
        int cn = ptr + min(in, dg - 1);
        int sn1 = csr[cn];
        float e1 = asrc[(size_t)sn1 * H + head];
        uint4 v1 = *(const uint4*)(xq + (size_t)sn1 * 256 + cbase);
        float e = e0 + ad;
        e = (e >= 0.f) ? e : 0.2f * e;
        float a0 = ok0 ? __expf(fminf(e, 70.f)) : 0.f;
        den += a0;
        f32x2 f;
        f = __builtin_amdgcn_cvt_pk_f32_fp8(v0.x, false); acc[0] += a0 * f.x;  acc[1] += a0 * f.y;
        f = __builtin_amdgcn_cvt_pk_f32_fp8(v0.x, true);  acc[2] += a0 * f.x;  acc[3] += a0 * f.y;
        f = __builtin_amdgcn_cvt_pk_f32_fp8(v0.y, false); acc[4] += a0 * f.x;  acc[5] += a0 * f.y;
        f = __builtin_amdgcn_cvt_pk_f32_fp8(v0.y, true);  acc[6] += a0 * f.x;  acc[7] += a0 * f.y;
        f = __builtin_amdgcn_cvt_pk_f32_fp8(v0.z, false); acc[8] += a0 * f.x;  acc[9] += a0 * f.y;
        f = __builtin_amdgcn_cvt_pk_f32_fp8(v0.z, true);  acc[10] += a0 * f.x; acc[11] += a0 * f.y;
        f = __builtin_amdgcn_cvt_pk_f32_fp8(v0.w, false); acc[12] += a0 * f.x; acc[13] += a0 * f.y;
        f = __builtin_amdgcn_cvt_pk_f32_fp8(v0.w, true);  acc[14] += a0 * f.x; acc[15] += a0 * f.y;
        i = in; e0 = e1; v0 = v1; ok0 = (in < dg);
    }
    den += __shfl_xor(den, 16);
    den += __shfl_xor(den, 32);
    #pragma unroll
    for (int j = 0; j < 16; ++j) {
        acc[j] += __shfl_xor(acc[j], 16);
        acc[j] += __shfl_xor(acc[j], 32);
    }
    if (g) return;
    float inv = 1.0f / den;
    float sN = 0.f, dN = 0.f;
    short8 w0, w1;
    #pragma unroll
    for (int j = 0; j < 16; ++j) {
        int c = cbase + j;
        float v = acc[j] * inv + bias[c];
        v = (v > 0.f) ? v : (__expf(v) - 1.f);   // ELU
        unsigned short bb = f2b(v);
        if (j < 8) w0[j] = (short)bb; else w1[j - 8] = (short)bb;
        sN += v * un[c * 2];
        dN += v * un[c * 2 + 1];
    }
    *(short8*)(o + (size_t)node * 256 + cbase) = w0;
    *(short8*)(o + (size_t)node * 256 + cbase + 8) = w1;
    #pragma unroll
    for (int off = 8; off > 0; off >>= 1) {
        sN += __shfl_xor(sN, off);
        dN += __shfl_xor(dN, off);
    }
    if (l4 == 0) { asn[node] = sN; adn[node] = dN; }
}

// ---------- final gather: 8 lanes/edge, 8 edges in flight + log_softmax ----------
__global__ __launch_bounds__(256) void k_gf(
    const unsigned short* __restrict__ xp,     // bf16 [NP,64]
    const float* __restrict__ asrc, const float* __restrict__ adst,
    const int* __restrict__ rowptr, const int* __restrict__ deg,
    const unsigned short* __restrict__ csr,
    const float* __restrict__ bias,            // f32 [40]
    float* __restrict__ out) {                 // f32 [N,40]
    int lane = threadIdx.x & 63;
    int node = blockIdx.x * 4 + (threadIdx.x >> 6);
    if (node >= N_NODES) return;
    int ptr = rowptr[node], dg = deg[node];
    int g = lane >> 3, l8 = lane & 7;
    int cbase = l8 * 8;
    float ad = adst[node];
    float acc[8] = {0,0,0,0,0,0,0,0};
    float den = 0.f;
    int dge = (dg + 7) & ~7;
    int i = g;
    int ci = ptr + min(i, dg - 1);
    int sn0 = csr[ci];
    float e0 = asrc[sn0];
    short8 v0 = *(const short8*)(xp + (size_t)sn0 * 64 + cbase);
    bool ok0 = (i < dg);
    while (i < dge) {
        int in = i + 8;
        int cn = ptr + min(in, dg - 1);
        int sn1 = csr[cn];
        float e1 = asrc[sn1];
        short8 v1 = *(const short8*)(xp + (size_t)sn1 * 64 + cbase);
        float e = e0 + ad;
        e = (e >= 0.f) ? e : 0.2f * e;
        float a0 = ok0 ? __expf(fminf(e, 70.f)) : 0.f;
        den += a0;
        #pragma unroll
        for (int j = 0; j < 8; ++j) acc[j] += a0 * b2f((unsigned short)v0[j]);
        i = in; e0 = e1; v0 = v1; ok0 = (in < dg);
    }
    den += __shfl_xor(den, 8);
    den += __shfl_xor(den, 16);
    den += __shfl_xor(den, 32);
    #pragma unroll
    for (int j = 0; j < 8; ++j) {
        acc[j] += __shfl_xor(acc[j], 8);
        acc[j] += __shfl_xor(acc[j], 16);
        acc[j] += __shfl_xor(acc[j], 32);
    }
    if (g) return;
    float inv = 1.0f / den;
    float val[8], mx = -1e30f;
    #pragma unroll
    for (int j = 0; j < 8; ++j) {
        int c = cbase + j;
        val[j] = (c < 40) ? acc[j] * inv + bias[c] : -1e30f;
        mx = fmaxf(mx, val[j]);
    }
    #pragma unroll
    for (int off = 4; off > 0; off >>= 1) mx = fmaxf(mx, __shfl_xor(mx, off));
    float ex = 0.f;
    #pragma unroll
    for (int j = 0; j < 8; ++j) {
        int c = cbase + j;
        if (c < 40) ex += __expf(val[j] - mx);
    }
    #pragma unroll
    for (int off = 4; off > 0; off >>= 1) ex += __shfl_xor(ex, off);
    float lse = __logf(ex);
    #pragma unroll
    for (int j = 0; j < 8; ++j) {
        int c = cbase + j;
        if (c < 40) out[(size_t)node * 40 + c] = val[j] - mx - lse;
    }
}

extern "C" void kernel_launch(void* const* d_in, const int* in_sizes, int n_in,
                              void* d_out, int out_size, void* d_ws, size_t ws_size,
                              hipStream_t stream) {
    const float* x   = (const float*)d_in[0];
    const int*   ei  = (const int*)d_in[1];
    const float* W0  = (const float*)d_in[2];
    const float* as0 = (const float*)d_in[3];
    const float* ad0 = (const float*)d_in[4];
    const float* b0  = (const float*)d_in[5];
    const float* W1  = (const float*)d_in[6];
    const float* as1 = (const float*)d_in[7];
    const float* ad1 = (const float*)d_in[8];
    const float* b1  = (const float*)d_in[9];
    const float* W2  = (const float*)d_in[10];
    const float* as2 = (const float*)d_in[11];
    const float* ad2 = (const float*)d_in[12];
    const float* b2  = (const float*)d_in[13];
    float* out = (float*)d_out;

    char* p = (char*)d_ws;
    auto carve = [&](size_t bytes) -> char* {
        char* r = p; p += (bytes + 255) & ~(size_t)255; return r;
    };
    unsigned short* xb   = (unsigned short*)carve((size_t)NP * 256 * 2);  // x bf16, later h2
    unsigned short* xpb  = (unsigned short*)carve((size_t)NP * 256 * 2);  // messages (fp8 overlay)
    unsigned short* h    = (unsigned short*)carve((size_t)NP * 256 * 2);  // h1
    unsigned short* xp2b = (unsigned short*)carve((size_t)NP * 64 * 2);
    unsigned short* Wt0  = (unsigned short*)carve(256 * 256 * 2);
    unsigned short* Wt1  = (unsigned short*)carve(256 * 256 * 2);
    unsigned short* Wt2  = (unsigned short*)carve(64 * 256 * 2);
    float* u0 = (float*)carve(256 * 16 * 4);
    float* u1 = (float*)carve(256 * 2 * 4);
    float* u2 = (float*)carve(256 * 2 * 4);
    float* asrc0 = (float*)carve((size_t)N_NODES * 8 * 4);
    float* adst0 = (float*)carve((size_t)N_NODES * 8 * 4);
    float* asrc1 = (float*)carve((size_t)N_NODES * 4);
    float* adst1 = (float*)carve((size_t)N_NODES * 4);
    float* asrc2 = (float*)carve((size_t)N_NODES * 4);
    float* adst2 = (float*)carve((size_t)N_NODES * 4);
    int* deg    = (int*)carve((size_t)N_NODES * 4);
    int* rowptr = (int*)carve((size_t)N_NODES * 4);
    int* bcnt   = (int*)carve((size_t)NBUCK * 4);
    int* bstart = (int*)carve((size_t)(NBUCK + 1) * 4);
    int* bcursor= (int*)carve((size_t)NBUCK * 4);
    unsigned int* stage = (unsigned int*)carve((size_t)ETOT * 4);
    unsigned short* csr = (unsigned short*)carve((size_t)ETOT * 2);
    unsigned char* xq = (unsigned char*)xpb;   // fp8 messages overlay (layers 0 and 1)

    hipMemsetAsync(bcnt, 0, (size_t)NBUCK * 4, stream);
    hipMemsetAsync(Wt2, 0, 64 * 256 * 2, stream);  // zero pad cols 40..63

    k_tb<<<(256 * 256 + 255) / 256, 256, 0, stream>>>(W0, Wt0, 256, 256);
    k_tb<<<(256 * 256 + 255) / 256, 256, 0, stream>>>(W1, Wt1, 256, 256);
    k_tb<<<(256 * 40 + 255) / 256, 256, 0, stream>>>(W2, Wt2, 256, 40);

    k_mku0<<<64, 256, 0, stream>>>(W0, as0, ad0, u0);
    k_mku1<<<64, 256, 0, stream>>>(W1, as1, ad1, u1, 256);
    k_mku1<<<64, 256, 0, stream>>>(W2, as2, ad2, u2, 40);

    k_bcount<<<(ETOT + 4095) / 4096, 256, 0, stream>>>(ei, bcnt);
    k_bscan<<<1, 256, 0, stream>>>(bcnt, bstart, bcursor);
    k_bscatter<<<(ETOT + 8191) / 8192, 256, 0, stream>>>(ei, bcursor, stage);
    k_csr<<<NBUCK, 256, 0, stream>>>(stage, bstart, rowptr, deg, csr);

    dim3 gg(NP / 128, 2);
    dim3 gn(N_NODES / 4);
    // layer 0: messages in fp8
    k_splitatt<16><<<gn, 256, 0, stream>>>(x, u0, xb, asrc0, adst0);
    k_gemm_w<true><<<gg, 256, 0, stream>>>(xb, Wt0, xq, N_NODES, 256, 256);
    k_gatherq<8><<<gn, 256, 0, stream>>>(xq, asrc0, adst0, rowptr, deg, csr,
                                         b0, u1, h, asrc1, adst1);
    // layer 1: messages in fp8
    k_gemm_w<true><<<gg, 256, 0, stream>>>(h, Wt1, xq, N_NODES, 256, 256);
    k_gatherq<1><<<gn, 256, 0, stream>>>(xq, asrc1, adst1, rowptr, deg, csr,
                                         b1, u2, xb, asrc2, adst2);
    // layer 2
    dim3 g2(NP / 128);
    k_gemm_b<<<g2, 256, 0, stream>>>(xb, Wt2, xp2b, N_NODES, 40, 64);
    k_gf<<<gn, 256, 0, stream>>>(xp2b, asrc2, adst2, rowptr, deg, csr, b2, out);
}

// Round 11
// 430.011 us; speedup vs baseline: 3.2123x; 1.1563x over previous
//
#include <hip/hip_runtime.h>
#include <hip/hip_bf16.h>

#define N_NODES 50000
#define N_EDGES 1600000
#define ETOT (N_EDGES + N_NODES)
#define NP 50048   // N padded for GEMM row tiles (391 * 128)
#define NBUCK 196  // dst >> 8 buckets (50000/256)

typedef __attribute__((ext_vector_type(8))) short short8;
typedef __attribute__((ext_vector_type(4))) float f32x4;
typedef __attribute__((ext_vector_type(2))) float f32x2;

__device__ __forceinline__ float b2f(unsigned short u) {
    union { unsigned int i; float f; } v; v.i = ((unsigned int)u) << 16; return v.f;
}
__device__ __forceinline__ unsigned short f2b(float f) {
    union { float f; unsigned int i; } v; v.f = f;
    unsigned int r = v.i + 0x7FFF + ((v.i >> 16) & 1);  // RNE
    return (unsigned short)(r >> 16);
}
__device__ __forceinline__ unsigned char f2q(float f) {
    int r = __builtin_amdgcn_cvt_pk_fp8_f32(f, f, 0, false);
    return (unsigned char)(r & 0xFF);
}

// ---------- weight transpose to bf16: W f32 [K,C] -> Wt bf16 [C,K] ----------
__global__ void k_tb(const float* __restrict__ W, unsigned short* __restrict__ Wt,
                     int K, int C) {
    int idx = blockIdx.x * 256 + threadIdx.x;
    if (idx >= K * C) return;
    int k = idx / C, c = idx - k * C;
    Wt[c * K + k] = f2b(W[idx]);
}

// ---------- layer-0 attention projection -> bf16 Bt layout [16, 256] ----------
// u0t[h*256+k] = sum_c W0[k, h*32+c]*attS[h,c]; u0t[(8+h)*256+k] = ... attD
__global__ __launch_bounds__(256) void k_mku0(const float* __restrict__ W,
                                              const float* __restrict__ attS,
                                              const float* __restrict__ attD,
                                              unsigned short* __restrict__ u0t) {
    int lane = threadIdx.x & 63;
    int k = blockIdx.x * 4 + (threadIdx.x >> 6);
    if (k >= 256) return;
    int h = lane >> 3, c0 = lane & 7;
    const float* wr = W + (size_t)k * 256 + h * 32;
    float ss = 0.f, sd = 0.f;
    #pragma unroll
    for (int t = 0; t < 4; ++t) {
        int c = c0 + t * 8;
        float w = wr[c];
        ss += w * attS[h * 32 + c];
        sd += w * attD[h * 32 + c];
    }
    #pragma unroll
    for (int off = 1; off < 8; off <<= 1) {
        ss += __shfl_xor(ss, off);
        sd += __shfl_xor(sd, off);
    }
    if (c0 == 0) {
        u0t[(size_t)h * 256 + k] = f2b(ss);
        u0t[(size_t)(8 + h) * 256 + k] = f2b(sd);
    }
}

__global__ __launch_bounds__(256) void k_mku1(const float* __restrict__ W,
                                              const float* __restrict__ attS,
                                              const float* __restrict__ attD,
                                              float* __restrict__ u, int C) {
    int lane = threadIdx.x & 63;
    int k = blockIdx.x * 4 + (threadIdx.x >> 6);
    if (k >= 256) return;
    const float* wr = W + (size_t)k * C;
    float ss = 0.f, sd = 0.f;
    for (int c = lane; c < C; c += 64) {
        float w = wr[c];
        ss += w * attS[c];
        sd += w * attD[c];
    }
    #pragma unroll
    for (int off = 32; off > 0; off >>= 1) {
        ss += __shfl_xor(ss, off);
        sd += __shfl_xor(sd, off);
    }
    if (lane == 0) { u[k * 2] = ss; u[k * 2 + 1] = sd; }
}

// ---------- CSR build: bucketed, low write-amplification ----------
__global__ __launch_bounds__(256) void k_bcount(const int* __restrict__ ei,
                                                int* __restrict__ bcnt) {
    __shared__ int h[NBUCK];
    for (int i = threadIdx.x; i < NBUCK; i += 256) h[i] = 0;
    __syncthreads();
    int e0 = blockIdx.x * 4096, e1 = min(e0 + 4096, ETOT);
    for (int e = e0 + threadIdx.x; e < e1; e += 256) {
        int dst = (e < N_EDGES) ? ei[N_EDGES + e] : (e - N_EDGES);
        atomicAdd(&h[dst >> 8], 1);
    }
    __syncthreads();
    for (int i = threadIdx.x; i < NBUCK; i += 256)
        if (h[i]) atomicAdd(&bcnt[i], h[i]);
}

__global__ void k_bscan(const int* __restrict__ bcnt, int* __restrict__ bstart,
                        int* __restrict__ bcursor) {
    __shared__ int tmp[256];
    int t = threadIdx.x;
    int v = (t < NBUCK) ? bcnt[t] : 0;
    tmp[t] = v;
    __syncthreads();
    for (int off = 1; off < 256; off <<= 1) {
        int u = (t >= off) ? tmp[t - off] : 0;
        __syncthreads();
        tmp[t] += u;
        __syncthreads();
    }
    int ex = tmp[t] - v;
    if (t < NBUCK) { bstart[t] = ex; bcursor[t] = ex; }
    if (t == 0) bstart[NBUCK] = ETOT;
}

__global__ __launch_bounds__(256) void k_bscatter(const int* __restrict__ ei,
                                                  int* __restrict__ bcursor,
                                                  unsigned int* __restrict__ stage) {
    __shared__ int h[NBUCK], base[NBUCK], cur[NBUCK], gbase[NBUCK];
    __shared__ int tmp[256];
    __shared__ unsigned int buf[8192];
    int t = threadIdx.x;
    for (int i = t; i < NBUCK; i += 256) h[i] = 0;
    __syncthreads();
    int e0 = blockIdx.x * 8192, e1 = min(e0 + 8192, ETOT);
    for (int e = e0 + t; e < e1; e += 256) {
        int dst = (e < N_EDGES) ? ei[N_EDGES + e] : (e - N_EDGES);
        atomicAdd(&h[dst >> 8], 1);
    }
    __syncthreads();
    int v = (t < NBUCK) ? h[t] : 0;
    tmp[t] = v;
    __syncthreads();
    for (int off = 1; off < 256; off <<= 1) {
        int u = (t >= off) ? tmp[t - off] : 0;
        __syncthreads();
        tmp[t] += u;
        __syncthreads();
    }
    if (t < NBUCK) { base[t] = tmp[t] - v; cur[t] = tmp[t] - v; }
    __syncthreads();
    for (int e = e0 + t; e < e1; e += 256) {
        int src, dst;
        if (e < N_EDGES) { src = ei[e]; dst = ei[N_EDGES + e]; }
        else             { src = dst = e - N_EDGES; }
        int b = dst >> 8;
        int p = atomicAdd(&cur[b], 1);
        buf[p] = ((unsigned int)b << 24) | ((unsigned int)src << 8) | (unsigned int)(dst & 255);
    }
    __syncthreads();
    if (t < NBUCK) gbase[t] = atomicAdd(&bcursor[t], h[t]);
    __syncthreads();
    int cnt = e1 - e0;
    for (int i = t; i < cnt; i += 256) {
        unsigned int pr = buf[i];
        int b = pr >> 24;
        stage[gbase[b] + (i - base[b])] = pr;
    }
}

__global__ __launch_bounds__(256) void k_csr(const unsigned int* __restrict__ stage,
                                             const int* __restrict__ bstart,
                                             int* __restrict__ rowptr, int* __restrict__ deg,
                                             unsigned short* __restrict__ csr) {
    __shared__ int cnt[256], cur[256], tmp[256];
    int b = blockIdx.x;
    int t = threadIdx.x;
    cnt[t] = 0;
    __syncthreads();
    int s0 = bstart[b], s1 = bstart[b + 1];
    for (int i = s0 + t; i < s1; i += 256)
        atomicAdd(&cnt[stage[i] & 255], 1);
    __syncthreads();
    int v = cnt[t];
    tmp[t] = v;
    __syncthreads();
    for (int off = 1; off < 256; off <<= 1) {
        int u = (t >= off) ? tmp[t - off] : 0;
        __syncthreads();
        tmp[t] += u;
        __syncthreads();
    }
    int ex = tmp[t] - v;
    int node = b * 256 + t;
    if (node < N_NODES) { rowptr[node] = s0 + ex; deg[node] = v; }
    cur[t] = s0 + ex;
    __syncthreads();
    for (int i = s0 + t; i < s1; i += 256) {
        unsigned int pr = stage[i];
        int p = atomicAdd(&cur[pr & 255], 1);
        csr[p] = (unsigned short)((pr >> 8) & 0xFFFF);
    }
}

// ---------- wide bf16 GEMM: 32rows x 128cols per wave; optional fp8 output ----------
template <bool FP8OUT>
__global__ __launch_bounds__(256) void k_gemm_w(
    const unsigned short* __restrict__ A, const unsigned short* __restrict__ Bt,
    void* __restrict__ Cout, int nrows, int ncols, int ldc) {
    const int K = 256;
    int lane = threadIdx.x & 63;
    int wave = threadIdx.x >> 6;
    int row0 = blockIdx.x * 128 + wave * 32;
    int col0 = blockIdx.y * 128;
    int ar0 = row0 + (lane & 15); if (ar0 >= nrows) ar0 = nrows - 1;
    int ar1 = row0 + 16 + (lane & 15); if (ar1 >= nrows) ar1 = nrows - 1;
    int ks = (lane >> 4) * 8;
    const unsigned short* Ap0 = A + (size_t)ar0 * K + ks;
    const unsigned short* Ap1 = A + (size_t)ar1 * K + ks;
    f32x4 acc[2][8];
    #pragma unroll
    for (int rt = 0; rt < 2; ++rt)
        #pragma unroll
        for (int ct = 0; ct < 8; ++ct) acc[rt][ct] = {0, 0, 0, 0};
    for (int k = 0; k < K; k += 32) {
        short8 a0 = *(const short8*)(Ap0 + k);
        short8 a1 = *(const short8*)(Ap1 + k);
        #pragma unroll
        for (int ct = 0; ct < 8; ++ct) {
            short8 b = *(const short8*)(Bt + (size_t)(col0 + ct * 16 + (lane & 15)) * K + k + ks);
            acc[0][ct] = __builtin_amdgcn_mfma_f32_16x16x32_bf16(a0, b, acc[0][ct], 0, 0, 0);
            acc[1][ct] = __builtin_amdgcn_mfma_f32_16x16x32_bf16(a1, b, acc[1][ct], 0, 0, 0);
        }
    }
    int cb = lane & 15;
    #pragma unroll
    for (int rt = 0; rt < 2; ++rt) {
        int rbase = row0 + rt * 16 + (lane >> 4) * 4;
        #pragma unroll
        for (int ct = 0; ct < 8; ++ct) {
            int cc = col0 + ct * 16 + cb;
            #pragma unroll
            for (int j = 0; j < 4; ++j) {
                float v = (cc < ncols) ? acc[rt][ct][j] : 0.f;
                if (FP8OUT)
                    ((unsigned char*)Cout)[(size_t)(rbase + j) * ldc + cc] = f2q(v);
                else
                    ((unsigned short*)Cout)[(size_t)(rbase + j) * ldc + cc] = f2b(v);
            }
        }
    }
}

// ---------- narrow bf16 GEMM (64 cols) for layer 2 ----------
__global__ __launch_bounds__(256) void k_gemm_b(
    const unsigned short* __restrict__ A, const unsigned short* __restrict__ Bt,
    unsigned short* __restrict__ Cout, int nrows, int ncols, int ldc) {
    const int K = 256;
    int lane = threadIdx.x & 63;
    int wave = threadIdx.x >> 6;
    int row0 = blockIdx.x * 128 + wave * 32;
    int ar0 = row0 + (lane & 15); if (ar0 >= nrows) ar0 = nrows - 1;
    int ar1 = row0 + 16 + (lane & 15); if (ar1 >= nrows) ar1 = nrows - 1;
    int ks = (lane >> 4) * 8;
    const unsigned short* Ap0 = A + (size_t)ar0 * K + ks;
    const unsigned short* Ap1 = A + (size_t)ar1 * K + ks;
    f32x4 acc[2][4] = {{{0,0,0,0},{0,0,0,0},{0,0,0,0},{0,0,0,0}},
                       {{0,0,0,0},{0,0,0,0},{0,0,0,0},{0,0,0,0}}};
    for (int k = 0; k < K; k += 32) {
        short8 a0 = *(const short8*)(Ap0 + k);
        short8 a1 = *(const short8*)(Ap1 + k);
        #pragma unroll
        for (int ct = 0; ct < 4; ++ct) {
            short8 b = *(const short8*)(Bt + (size_t)(ct * 16 + (lane & 15)) * K + k + ks);
            acc[0][ct] = __builtin_amdgcn_mfma_f32_16x16x32_bf16(a0, b, acc[0][ct], 0, 0, 0);
            acc[1][ct] = __builtin_amdgcn_mfma_f32_16x16x32_bf16(a1, b, acc[1][ct], 0, 0, 0);
        }
    }
    int cb = lane & 15;
    #pragma unroll
    for (int rt = 0; rt < 2; ++rt) {
        int rbase = row0 + rt * 16 + (lane >> 4) * 4;
        #pragma unroll
        for (int ct = 0; ct < 4; ++ct) {
            int cc = ct * 16 + cb;
            #pragma unroll
            for (int j = 0; j < 4; ++j) {
                float v = (cc < ncols) ? acc[rt][ct][j] : 0.f;
                Cout[(size_t)(rbase + j) * ldc + cc] = f2b(v);
            }
        }
    }
}

// ---------- tiny MFMA GEMM: xb[NP,256] x u0t[16,256] -> f32 att0[NP,16] ----------
__global__ __launch_bounds__(256) void k_gemm_att(
    const unsigned short* __restrict__ A, const unsigned short* __restrict__ Bt,
    float* __restrict__ Cout, int nrows) {
    const int K = 256;
    int lane = threadIdx.x & 63;
    int wave = threadIdx.x >> 6;
    int row0 = blockIdx.x * 128 + wave * 32;
    int ar0 = row0 + (lane & 15); if (ar0 >= nrows) ar0 = nrows - 1;
    int ar1 = row0 + 16 + (lane & 15); if (ar1 >= nrows) ar1 = nrows - 1;
    int ks = (lane >> 4) * 8;
    const unsigned short* Ap0 = A + (size_t)ar0 * K + ks;
    const unsigned short* Ap1 = A + (size_t)ar1 * K + ks;
    f32x4 acc[2] = {{0,0,0,0},{0,0,0,0}};
    for (int k = 0; k < K; k += 32) {
        short8 a0 = *(const short8*)(Ap0 + k);
        short8 a1 = *(const short8*)(Ap1 + k);
        short8 b = *(const short8*)(Bt + (size_t)(lane & 15) * K + k + ks);
        acc[0] = __builtin_amdgcn_mfma_f32_16x16x32_bf16(a0, b, acc[0], 0, 0, 0);
        acc[1] = __builtin_amdgcn_mfma_f32_16x16x32_bf16(a1, b, acc[1], 0, 0, 0);
    }
    int cb = lane & 15;
    #pragma unroll
    for (int rt = 0; rt < 2; ++rt) {
        int rbase = row0 + rt * 16 + (lane >> 4) * 4;
        #pragma unroll
        for (int j = 0; j < 4; ++j)
            Cout[(size_t)(rbase + j) * 16 + cb] = acc[rt][j];
    }
}

// ---------- x f32 -> xb bf16, streaming ----------
__global__ __launch_bounds__(256) void k_split(const float* __restrict__ x,
                                               unsigned short* __restrict__ xb) {
    int idx = blockIdx.x * 256 + threadIdx.x;
    if (idx >= N_NODES * 64) return;
    float4 v = *(const float4*)(x + (size_t)idx * 4);
    ushort4 w;
    w.x = f2b(v.x); w.y = f2b(v.y); w.z = f2b(v.z); w.w = f2b(v.w);
    *(ushort4*)(xb + (size_t)idx * 4) = w;
}

// ---------- fp8 gather (layers 0 & 1): 16 lanes/edge, 4 edges in flight ----------
// H==8: asrc/adst point into att0 with row stride 16 (adst = att0 + 8).
template <int H>
__global__ __launch_bounds__(256) void k_gatherq(
    const unsigned char* __restrict__ xq,      // fp8 [NP,256]
    const float* __restrict__ asrc, const float* __restrict__ adst,
    const int* __restrict__ rowptr, const int* __restrict__ deg,
    const unsigned short* __restrict__ csr,
    const float* __restrict__ bias,            // f32 [256]
    const float* __restrict__ un,              // f32 [256*2] (next-layer u)
    unsigned short* __restrict__ o,            // bf16 [NP,256]
    float* __restrict__ asn, float* __restrict__ adn) {
    constexpr int SS = (H == 8) ? 16 : 1;
    int lane = threadIdx.x & 63;
    int node = blockIdx.x * 4 + (threadIdx.x >> 6);
    if (node >= N_NODES) return;
    int ptr = rowptr[node], dg = deg[node];
    int g = lane >> 4, l4 = lane & 15;
    int cbase = l4 * 16;
    int head = (H == 8) ? (l4 >> 1) : 0;
    float ad = adst[(size_t)node * SS + head];
    float acc[16];
    #pragma unroll
    for (int j = 0; j < 16; ++j) acc[j] = 0.f;
    float den = 0.f;
    int dge = (dg + 3) & ~3;
    int i = g;
    int ci = ptr + min(i, dg - 1);
    int sn0 = csr[ci];
    float e0 = asrc[(size_t)sn0 * SS + head];
    uint4 v0 = *(const uint4*)(xq + (size_t)sn0 * 256 + cbase);
    bool ok0 = (i < dg);
    while (i < dge) {
        int in = i + 4;
        int cn = ptr + min(in, dg - 1);
        int sn1 = csr[cn];
        float e1 = asrc[(size_t)sn1 * SS + head];
        uint4 v1 = *(const uint4*)(xq + (size_t)sn1 * 256 + cbase);
        float e = e0 + ad;
        e = (e >= 0.f) ? e : 0.2f * e;
        float a0 = ok0 ? __expf(fminf(e, 70.f)) : 0.f;
        den += a0;
        f32x2 f;
        f = __builtin_amdgcn_cvt_pk_f32_fp8(v0.x, false); acc[0] += a0 * f.x;  acc[1] += a0 * f.y;
        f = __builtin_amdgcn_cvt_pk_f32_fp8(v0.x, true);  acc[2] += a0 * f.x;  acc[3] += a0 * f.y;
        f = __builtin_amdgcn_cvt_pk_f32_fp8(v0.y, false); acc[4] += a0 * f.x;  acc[5] += a0 * f.y;
        f = __builtin_amdgcn_cvt_pk_f32_fp8(v0.y, true);  acc[6] += a0 * f.x;  acc[7] += a0 * f.y;
        f = __builtin_amdgcn_cvt_pk_f32_fp8(v0.z, false); acc[8] += a0 * f.x;  acc[9] += a0 * f.y;
        f = __builtin_amdgcn_cvt_pk_f32_fp8(v0.z, true);  acc[10] += a0 * f.x; acc[11] += a0 * f.y;
        f = __builtin_amdgcn_cvt_pk_f32_fp8(v0.w, false); acc[12] += a0 * f.x; acc[13] += a0 * f.y;
        f = __builtin_amdgcn_cvt_pk_f32_fp8(v0.w, true);  acc[14] += a0 * f.x; acc[15] += a0 * f.y;
        i = in; e0 = e1; v0 = v1; ok0 = (in < dg);
    }
    den += __shfl_xor(den, 16);
    den += __shfl_xor(den, 32);
    #pragma unroll
    for (int j = 0; j < 16; ++j) {
        acc[j] += __shfl_xor(acc[j], 16);
        acc[j] += __shfl_xor(acc[j], 32);
    }
    if (g) return;
    float inv = 1.0f / den;
    float sN = 0.f, dN = 0.f;
    short8 w0, w1;
    #pragma unroll
    for (int j = 0; j < 16; ++j) {
        int c = cbase + j;
        float v = acc[j] * inv + bias[c];
        v = (v > 0.f) ? v : (__expf(v) - 1.f);   // ELU
        unsigned short bb = f2b(v);
        if (j < 8) w0[j] = (short)bb; else w1[j - 8] = (short)bb;
        sN += v * un[c * 2];
        dN += v * un[c * 2 + 1];
    }
    *(short8*)(o + (size_t)node * 256 + cbase) = w0;
    *(short8*)(o + (size_t)node * 256 + cbase + 8) = w1;
    #pragma unroll
    for (int off = 8; off > 0; off >>= 1) {
        sN += __shfl_xor(sN, off);
        dN += __shfl_xor(dN, off);
    }
    if (l4 == 0) { asn[node] = sN; adn[node] = dN; }
}

// ---------- final gather: 8 lanes/edge, 8 edges in flight + log_softmax ----------
__global__ __launch_bounds__(256) void k_gf(
    const unsigned short* __restrict__ xp,     // bf16 [NP,64]
    const float* __restrict__ asrc, const float* __restrict__ adst,
    const int* __restrict__ rowptr, const int* __restrict__ deg,
    const unsigned short* __restrict__ csr,
    const float* __restrict__ bias,            // f32 [40]
    float* __restrict__ out) {                 // f32 [N,40]
    int lane = threadIdx.x & 63;
    int node = blockIdx.x * 4 + (threadIdx.x >> 6);
    if (node >= N_NODES) return;
    int ptr = rowptr[node], dg = deg[node];
    int g = lane >> 3, l8 = lane & 7;
    int cbase = l8 * 8;
    float ad = adst[node];
    float acc[8] = {0,0,0,0,0,0,0,0};
    float den = 0.f;
    int dge = (dg + 7) & ~7;
    int i = g;
    int ci = ptr + min(i, dg - 1);
    int sn0 = csr[ci];
    float e0 = asrc[sn0];
    short8 v0 = *(const short8*)(xp + (size_t)sn0 * 64 + cbase);
    bool ok0 = (i < dg);
    while (i < dge) {
        int in = i + 8;
        int cn = ptr + min(in, dg - 1);
        int sn1 = csr[cn];
        float e1 = asrc[sn1];
        short8 v1 = *(const short8*)(xp + (size_t)sn1 * 64 + cbase);
        float e = e0 + ad;
        e = (e >= 0.f) ? e : 0.2f * e;
        float a0 = ok0 ? __expf(fminf(e, 70.f)) : 0.f;
        den += a0;
        #pragma unroll
        for (int j = 0; j < 8; ++j) acc[j] += a0 * b2f((unsigned short)v0[j]);
        i = in; e0 = e1; v0 = v1; ok0 = (in < dg);
    }
    den += __shfl_xor(den, 8);
    den += __shfl_xor(den, 16);
    den += __shfl_xor(den, 32);
    #pragma unroll
    for (int j = 0; j < 8; ++j) {
        acc[j] += __shfl_xor(acc[j], 8);
        acc[j] += __shfl_xor(acc[j], 16);
        acc[j] += __shfl_xor(acc[j], 32);
    }
    if (g) return;
    float inv = 1.0f / den;
    float val[8], mx = -1e30f;
    #pragma unroll
    for (int j = 0; j < 8; ++j) {
        int c = cbase + j;
        val[j] = (c < 40) ? acc[j] * inv + bias[c] : -1e30f;
        mx = fmaxf(mx, val[j]);
    }
    #pragma unroll
    for (int off = 4; off > 0; off >>= 1) mx = fmaxf(mx, __shfl_xor(mx, off));
    float ex = 0.f;
    #pragma unroll
    for (int j = 0; j < 8; ++j) {
        int c = cbase + j;
        if (c < 40) ex += __expf(val[j] - mx);
    }
    #pragma unroll
    for (int off = 4; off > 0; off >>= 1) ex += __shfl_xor(ex, off);
    float lse = __logf(ex);
    #pragma unroll
    for (int j = 0; j < 8; ++j) {
        int c = cbase + j;
        if (c < 40) out[(size_t)node * 40 + c] = val[j] - mx - lse;
    }
}

extern "C" void kernel_launch(void* const* d_in, const int* in_sizes, int n_in,
                              void* d_out, int out_size, void* d_ws, size_t ws_size,
                              hipStream_t stream) {
    const float* x   = (const float*)d_in[0];
    const int*   ei  = (const int*)d_in[1];
    const float* W0  = (const float*)d_in[2];
    const float* as0 = (const float*)d_in[3];
    const float* ad0 = (const float*)d_in[4];
    const float* b0  = (const float*)d_in[5];
    const float* W1  = (const float*)d_in[6];
    const float* as1 = (const float*)d_in[7];
    const float* ad1 = (const float*)d_in[8];
    const float* b1  = (const float*)d_in[9];
    const float* W2  = (const float*)d_in[10];
    const float* as2 = (const float*)d_in[11];
    const float* ad2 = (const float*)d_in[12];
    const float* b2  = (const float*)d_in[13];
    float* out = (float*)d_out;

    char* p = (char*)d_ws;
    auto carve = [&](size_t bytes) -> char* {
        char* r = p; p += (bytes + 255) & ~(size_t)255; return r;
    };
    unsigned short* xb   = (unsigned short*)carve((size_t)NP * 256 * 2);  // x bf16, later h2
    unsigned short* xpb  = (unsigned short*)carve((size_t)NP * 256 * 2);  // messages (fp8 overlay)
    unsigned short* h    = (unsigned short*)carve((size_t)NP * 256 * 2);  // h1
    unsigned short* xp2b = (unsigned short*)carve((size_t)NP * 64 * 2);
    unsigned short* Wt0  = (unsigned short*)carve(256 * 256 * 2);
    unsigned short* Wt1  = (unsigned short*)carve(256 * 256 * 2);
    unsigned short* Wt2  = (unsigned short*)carve(64 * 256 * 2);
    unsigned short* u0t  = (unsigned short*)carve(16 * 256 * 2);
    float* att0 = (float*)carve((size_t)NP * 16 * 4);
    float* u1 = (float*)carve(256 * 2 * 4);
    float* u2 = (float*)carve(256 * 2 * 4);
    float* asrc1 = (float*)carve((size_t)N_NODES * 4);
    float* adst1 = (float*)carve((size_t)N_NODES * 4);
    float* asrc2 = (float*)carve((size_t)N_NODES * 4);
    float* adst2 = (float*)carve((size_t)N_NODES * 4);
    int* deg    = (int*)carve((size_t)N_NODES * 4);
    int* rowptr = (int*)carve((size_t)N_NODES * 4);
    int* bcnt   = (int*)carve((size_t)NBUCK * 4);
    int* bstart = (int*)carve((size_t)(NBUCK + 1) * 4);
    int* bcursor= (int*)carve((size_t)NBUCK * 4);
    unsigned int* stage = (unsigned int*)carve((size_t)ETOT * 4);
    unsigned short* csr = (unsigned short*)carve((size_t)ETOT * 2);
    unsigned char* xq = (unsigned char*)xpb;   // fp8 messages overlay (layers 0 and 1)

    hipMemsetAsync(bcnt, 0, (size_t)NBUCK * 4, stream);
    hipMemsetAsync(Wt2, 0, 64 * 256 * 2, stream);  // zero pad cols 40..63

    k_tb<<<(256 * 256 + 255) / 256, 256, 0, stream>>>(W0, Wt0, 256, 256);
    k_tb<<<(256 * 256 + 255) / 256, 256, 0, stream>>>(W1, Wt1, 256, 256);
    k_tb<<<(256 * 40 + 255) / 256, 256, 0, stream>>>(W2, Wt2, 256, 40);

    k_mku0<<<64, 256, 0, stream>>>(W0, as0, ad0, u0t);
    k_mku1<<<64, 256, 0, stream>>>(W1, as1, ad1, u1, 256);
    k_mku1<<<64, 256, 0, stream>>>(W2, as2, ad2, u2, 40);

    k_bcount<<<(ETOT + 4095) / 4096, 256, 0, stream>>>(ei, bcnt);
    k_bscan<<<1, 256, 0, stream>>>(bcnt, bstart, bcursor);
    k_bscatter<<<(ETOT + 8191) / 8192, 256, 0, stream>>>(ei, bcursor, stage);
    k_csr<<<NBUCK, 256, 0, stream>>>(stage, bstart, rowptr, deg, csr);

    dim3 gg(NP / 128, 2);
    dim3 gn(N_NODES / 4);
    dim3 g1(NP / 128);
    // layer 0: messages in fp8; logits via narrow MFMA GEMM
    k_split<<<(N_NODES * 64 + 255) / 256, 256, 0, stream>>>(x, xb);
    k_gemm_att<<<g1, 256, 0, stream>>>(xb, u0t, att0, N_NODES);
    k_gemm_w<true><<<gg, 256, 0, stream>>>(xb, Wt0, xq, N_NODES, 256, 256);
    k_gatherq<8><<<gn, 256, 0, stream>>>(xq, att0, att0 + 8, rowptr, deg, csr,
                                         b0, u1, h, asrc1, adst1);
    // layer 1: messages in fp8
    k_gemm_w<true><<<gg, 256, 0, stream>>>(h, Wt1, xq, N_NODES, 256, 256);
    k_gatherq<1><<<gn, 256, 0, stream>>>(xq, asrc1, adst1, rowptr, deg, csr,
                                         b1, u2, xb, asrc2, adst2);
    // layer 2
    k_gemm_b<<<g1, 256, 0, stream>>>(xb, Wt2, xp2b, N_NODES, 40, 64);
    k_gf<<<gn, 256, 0, stream>>>(xp2b, asrc2, adst2, rowptr, deg, csr, b2, out);
}

// Round 12
// 412.139 us; speedup vs baseline: 3.3516x; 1.0434x over previous
//
#include <hip/hip_runtime.h>
#include <hip/hip_bf16.h>

#define N_NODES 50000
#define N_EDGES 1600000
#define ETOT (N_EDGES + N_NODES)
#define NP 50048   // N padded for GEMM row tiles (391 * 128)
#define NBUCK 196  // dst >> 8 buckets (50000/256)

typedef __attribute__((ext_vector_type(8))) short short8;
typedef __attribute__((ext_vector_type(4))) float f32x4;
typedef __attribute__((ext_vector_type(2))) float f32x2;

__device__ __forceinline__ float b2f(unsigned short u) {
    union { unsigned int i; float f; } v; v.i = ((unsigned int)u) << 16; return v.f;
}
__device__ __forceinline__ unsigned short f2b(float f) {
    union { float f; unsigned int i; } v; v.f = f;
    unsigned int r = v.i + 0x7FFF + ((v.i >> 16) & 1);  // RNE
    return (unsigned short)(r >> 16);
}
__device__ __forceinline__ unsigned char f2q(float f) {
    int r = __builtin_amdgcn_cvt_pk_fp8_f32(f, f, 0, false);
    return (unsigned char)(r & 0xFF);
}

// ---------- weight transpose to bf16: W f32 [K,C] -> Wt bf16 [C,K] ----------
__global__ void k_tb(const float* __restrict__ W, unsigned short* __restrict__ Wt,
                     int K, int C) {
    int idx = blockIdx.x * 256 + threadIdx.x;
    if (idx >= K * C) return;
    int k = idx / C, c = idx - k * C;
    Wt[c * K + k] = f2b(W[idx]);
}

// ---------- layer-0 attention projection -> bf16 Bt layout [16, 256] ----------
__global__ __launch_bounds__(256) void k_mku0(const float* __restrict__ W,
                                              const float* __restrict__ attS,
                                              const float* __restrict__ attD,
                                              unsigned short* __restrict__ u0t) {
    int lane = threadIdx.x & 63;
    int k = blockIdx.x * 4 + (threadIdx.x >> 6);
    if (k >= 256) return;
    int h = lane >> 3, c0 = lane & 7;
    const float* wr = W + (size_t)k * 256 + h * 32;
    float ss = 0.f, sd = 0.f;
    #pragma unroll
    for (int t = 0; t < 4; ++t) {
        int c = c0 + t * 8;
        float w = wr[c];
        ss += w * attS[h * 32 + c];
        sd += w * attD[h * 32 + c];
    }
    #pragma unroll
    for (int off = 1; off < 8; off <<= 1) {
        ss += __shfl_xor(ss, off);
        sd += __shfl_xor(sd, off);
    }
    if (c0 == 0) {
        u0t[(size_t)h * 256 + k] = f2b(ss);
        u0t[(size_t)(8 + h) * 256 + k] = f2b(sd);
    }
}

__global__ __launch_bounds__(256) void k_mku1(const float* __restrict__ W,
                                              const float* __restrict__ attS,
                                              const float* __restrict__ attD,
                                              float* __restrict__ u, int C) {
    int lane = threadIdx.x & 63;
    int k = blockIdx.x * 4 + (threadIdx.x >> 6);
    if (k >= 256) return;
    const float* wr = W + (size_t)k * C;
    float ss = 0.f, sd = 0.f;
    for (int c = lane; c < C; c += 64) {
        float w = wr[c];
        ss += w * attS[c];
        sd += w * attD[c];
    }
    #pragma unroll
    for (int off = 32; off > 0; off >>= 1) {
        ss += __shfl_xor(ss, off);
        sd += __shfl_xor(sd, off);
    }
    if (lane == 0) { u[k * 2] = ss; u[k * 2 + 1] = sd; }
}

// ---------- CSR build: bucketed, low write-amplification ----------
__global__ __launch_bounds__(256) void k_bcount(const int* __restrict__ ei,
                                                int* __restrict__ bcnt) {
    __shared__ int h[NBUCK];
    for (int i = threadIdx.x; i < NBUCK; i += 256) h[i] = 0;
    __syncthreads();
    int e0 = blockIdx.x * 4096, e1 = min(e0 + 4096, ETOT);
    for (int e = e0 + threadIdx.x; e < e1; e += 256) {
        int dst = (e < N_EDGES) ? ei[N_EDGES + e] : (e - N_EDGES);
        atomicAdd(&h[dst >> 8], 1);
    }
    __syncthreads();
    for (int i = threadIdx.x; i < NBUCK; i += 256)
        if (h[i]) atomicAdd(&bcnt[i], h[i]);
}

__global__ void k_bscan(const int* __restrict__ bcnt, int* __restrict__ bstart,
                        int* __restrict__ bcursor) {
    __shared__ int tmp[256];
    int t = threadIdx.x;
    int v = (t < NBUCK) ? bcnt[t] : 0;
    tmp[t] = v;
    __syncthreads();
    for (int off = 1; off < 256; off <<= 1) {
        int u = (t >= off) ? tmp[t - off] : 0;
        __syncthreads();
        tmp[t] += u;
        __syncthreads();
    }
    int ex = tmp[t] - v;
    if (t < NBUCK) { bstart[t] = ex; bcursor[t] = ex; }
    if (t == 0) bstart[NBUCK] = ETOT;
}

__global__ __launch_bounds__(256) void k_bscatter(const int* __restrict__ ei,
                                                  int* __restrict__ bcursor,
                                                  unsigned int* __restrict__ stage) {
    __shared__ int h[NBUCK], base[NBUCK], cur[NBUCK], gbase[NBUCK];
    __shared__ int tmp[256];
    __shared__ unsigned int buf[8192];
    int t = threadIdx.x;
    for (int i = t; i < NBUCK; i += 256) h[i] = 0;
    __syncthreads();
    int e0 = blockIdx.x * 8192, e1 = min(e0 + 8192, ETOT);
    for (int e = e0 + t; e < e1; e += 256) {
        int dst = (e < N_EDGES) ? ei[N_EDGES + e] : (e - N_EDGES);
        atomicAdd(&h[dst >> 8], 1);
    }
    __syncthreads();
    int v = (t < NBUCK) ? h[t] : 0;
    tmp[t] = v;
    __syncthreads();
    for (int off = 1; off < 256; off <<= 1) {
        int u = (t >= off) ? tmp[t - off] : 0;
        __syncthreads();
        tmp[t] += u;
        __syncthreads();
    }
    if (t < NBUCK) { base[t] = tmp[t] - v; cur[t] = tmp[t] - v; }
    __syncthreads();
    for (int e = e0 + t; e < e1; e += 256) {
        int src, dst;
        if (e < N_EDGES) { src = ei[e]; dst = ei[N_EDGES + e]; }
        else             { src = dst = e - N_EDGES; }
        int b = dst >> 8;
        int p = atomicAdd(&cur[b], 1);
        buf[p] = ((unsigned int)b << 24) | ((unsigned int)src << 8) | (unsigned int)(dst & 255);
    }
    __syncthreads();
    if (t < NBUCK) gbase[t] = atomicAdd(&bcursor[t], h[t]);
    __syncthreads();
    int cnt = e1 - e0;
    for (int i = t; i < cnt; i += 256) {
        unsigned int pr = buf[i];
        int b = pr >> 24;
        stage[gbase[b] + (i - base[b])] = pr;
    }
}

__global__ __launch_bounds__(256) void k_csr(const unsigned int* __restrict__ stage,
                                             const int* __restrict__ bstart,
                                             int* __restrict__ rowptr, int* __restrict__ deg,
                                             unsigned short* __restrict__ csr) {
    __shared__ int cnt[256], cur[256], tmp[256];
    int b = blockIdx.x;
    int t = threadIdx.x;
    cnt[t] = 0;
    __syncthreads();
    int s0 = bstart[b], s1 = bstart[b + 1];
    for (int i = s0 + t; i < s1; i += 256)
        atomicAdd(&cnt[stage[i] & 255], 1);
    __syncthreads();
    int v = cnt[t];
    tmp[t] = v;
    __syncthreads();
    for (int off = 1; off < 256; off <<= 1) {
        int u = (t >= off) ? tmp[t - off] : 0;
        __syncthreads();
        tmp[t] += u;
        __syncthreads();
    }
    int ex = tmp[t] - v;
    int node = b * 256 + t;
    if (node < N_NODES) { rowptr[node] = s0 + ex; deg[node] = v; }
    cur[t] = s0 + ex;
    __syncthreads();
    for (int i = s0 + t; i < s1; i += 256) {
        unsigned int pr = stage[i];
        int p = atomicAdd(&cur[pr & 255], 1);
        csr[p] = (unsigned short)((pr >> 8) & 0xFFFF);
    }
}

// ---------- wide bf16 GEMM: 32rows x 128cols per wave; fp8 out; optional fused att ----------
template <bool ATT>
__global__ __launch_bounds__(256) void k_gemm_w(
    const unsigned short* __restrict__ A, const unsigned short* __restrict__ Bt,
    unsigned char* __restrict__ Cout,
    const unsigned short* __restrict__ But,    // bf16 [16,256] or null
    float* __restrict__ Catt,                  // f32 [NP,16] or null
    int nrows, int ldc) {
    const int K = 256;
    int lane = threadIdx.x & 63;
    int wave = threadIdx.x >> 6;
    int row0 = blockIdx.x * 128 + wave * 32;
    int col0 = blockIdx.y * 128;
    bool doAtt = ATT && (blockIdx.y == 0);
    int ar0 = row0 + (lane & 15); if (ar0 >= nrows) ar0 = nrows - 1;
    int ar1 = row0 + 16 + (lane & 15); if (ar1 >= nrows) ar1 = nrows - 1;
    int ks = (lane >> 4) * 8;
    const unsigned short* Ap0 = A + (size_t)ar0 * K + ks;
    const unsigned short* Ap1 = A + (size_t)ar1 * K + ks;
    f32x4 acc[2][8];
    f32x4 aat[2] = {{0,0,0,0},{0,0,0,0}};
    #pragma unroll
    for (int rt = 0; rt < 2; ++rt)
        #pragma unroll
        for (int ct = 0; ct < 8; ++ct) acc[rt][ct] = {0, 0, 0, 0};
    for (int k = 0; k < K; k += 32) {
        short8 a0 = *(const short8*)(Ap0 + k);
        short8 a1 = *(const short8*)(Ap1 + k);
        #pragma unroll
        for (int ct = 0; ct < 8; ++ct) {
            short8 b = *(const short8*)(Bt + (size_t)(col0 + ct * 16 + (lane & 15)) * K + k + ks);
            acc[0][ct] = __builtin_amdgcn_mfma_f32_16x16x32_bf16(a0, b, acc[0][ct], 0, 0, 0);
            acc[1][ct] = __builtin_amdgcn_mfma_f32_16x16x32_bf16(a1, b, acc[1][ct], 0, 0, 0);
        }
        if (doAtt) {
            short8 b = *(const short8*)(But + (size_t)(lane & 15) * K + k + ks);
            aat[0] = __builtin_amdgcn_mfma_f32_16x16x32_bf16(a0, b, aat[0], 0, 0, 0);
            aat[1] = __builtin_amdgcn_mfma_f32_16x16x32_bf16(a1, b, aat[1], 0, 0, 0);
        }
    }
    int cb = lane & 15;
    #pragma unroll
    for (int rt = 0; rt < 2; ++rt) {
        int rbase = row0 + rt * 16 + (lane >> 4) * 4;
        #pragma unroll
        for (int ct = 0; ct < 8; ++ct) {
            int cc = col0 + ct * 16 + cb;
            #pragma unroll
            for (int j = 0; j < 4; ++j)
                Cout[(size_t)(rbase + j) * ldc + cc] = f2q(acc[rt][ct][j]);
        }
        if (doAtt) {
            #pragma unroll
            for (int j = 0; j < 4; ++j)
                Catt[(size_t)(rbase + j) * 16 + cb] = aat[rt][j];
        }
    }
}

// ---------- narrow bf16 GEMM (64 cols), fp8 output, for layer 2 ----------
__global__ __launch_bounds__(256) void k_gemm_b(
    const unsigned short* __restrict__ A, const unsigned short* __restrict__ Bt,
    unsigned char* __restrict__ Cout, int nrows, int ncols, int ldc) {
    const int K = 256;
    int lane = threadIdx.x & 63;
    int wave = threadIdx.x >> 6;
    int row0 = blockIdx.x * 128 + wave * 32;
    int ar0 = row0 + (lane & 15); if (ar0 >= nrows) ar0 = nrows - 1;
    int ar1 = row0 + 16 + (lane & 15); if (ar1 >= nrows) ar1 = nrows - 1;
    int ks = (lane >> 4) * 8;
    const unsigned short* Ap0 = A + (size_t)ar0 * K + ks;
    const unsigned short* Ap1 = A + (size_t)ar1 * K + ks;
    f32x4 acc[2][4] = {{{0,0,0,0},{0,0,0,0},{0,0,0,0},{0,0,0,0}},
                       {{0,0,0,0},{0,0,0,0},{0,0,0,0},{0,0,0,0}}};
    for (int k = 0; k < K; k += 32) {
        short8 a0 = *(const short8*)(Ap0 + k);
        short8 a1 = *(const short8*)(Ap1 + k);
        #pragma unroll
        for (int ct = 0; ct < 4; ++ct) {
            short8 b = *(const short8*)(Bt + (size_t)(ct * 16 + (lane & 15)) * K + k + ks);
            acc[0][ct] = __builtin_amdgcn_mfma_f32_16x16x32_bf16(a0, b, acc[0][ct], 0, 0, 0);
            acc[1][ct] = __builtin_amdgcn_mfma_f32_16x16x32_bf16(a1, b, acc[1][ct], 0, 0, 0);
        }
    }
    int cb = lane & 15;
    #pragma unroll
    for (int rt = 0; rt < 2; ++rt) {
        int rbase = row0 + rt * 16 + (lane >> 4) * 4;
        #pragma unroll
        for (int ct = 0; ct < 4; ++ct) {
            int cc = ct * 16 + cb;
            #pragma unroll
            for (int j = 0; j < 4; ++j) {
                float v = (cc < ncols) ? acc[rt][ct][j] : 0.f;
                Cout[(size_t)(rbase + j) * ldc + cc] = f2q(v);
            }
        }
    }
}

// ---------- x f32 -> xb bf16, streaming ----------
__global__ __launch_bounds__(256) void k_split(const float* __restrict__ x,
                                               unsigned short* __restrict__ xb) {
    int idx = blockIdx.x * 256 + threadIdx.x;
    if (idx >= N_NODES * 64) return;
    float4 v = *(const float4*)(x + (size_t)idx * 4);
    ushort4 w;
    w.x = f2b(v.x); w.y = f2b(v.y); w.z = f2b(v.z); w.w = f2b(v.w);
    *(ushort4*)(xb + (size_t)idx * 4) = w;
}

// ---------- fp8 gather (layers 0 & 1): 16 lanes/edge, 4 edges in flight ----------
// H==8: asrc/adst point into att0 with row stride 16 (adst = att0 + 8).
template <int H>
__global__ __launch_bounds__(256) void k_gatherq(
    const unsigned char* __restrict__ xq,      // fp8 [NP,256]
    const float* __restrict__ asrc, const float* __restrict__ adst,
    const int* __restrict__ rowptr, const int* __restrict__ deg,
    const unsigned short* __restrict__ csr,
    const float* __restrict__ bias,            // f32 [256]
    const float* __restrict__ un,              // f32 [256*2] (next-layer u)
    unsigned short* __restrict__ o,            // bf16 [NP,256]
    float* __restrict__ asn, float* __restrict__ adn) {
    constexpr int SS = (H == 8) ? 16 : 1;
    int lane = threadIdx.x & 63;
    int node = blockIdx.x * 4 + (threadIdx.x >> 6);
    if (node >= N_NODES) return;
    int ptr = rowptr[node], dg = deg[node];
    int g = lane >> 4, l4 = lane & 15;
    int cbase = l4 * 16;
    int head = (H == 8) ? (l4 >> 1) : 0;
    float ad = adst[(size_t)node * SS + head];
    float acc[16];
    #pragma unroll
    for (int j = 0; j < 16; ++j) acc[j] = 0.f;
    float den = 0.f;
    int dge = (dg + 3) & ~3;
    int i = g;
    int ci = ptr + min(i, dg - 1);
    int sn0 = csr[ci];
    float e0 = asrc[(size_t)sn0 * SS + head];
    uint4 v0 = *(const uint4*)(xq + (size_t)sn0 * 256 + cbase);
    bool ok0 = (i < dg);
    while (i < dge) {
        int in = i + 4;
        int cn = ptr + min(in, dg - 1);
        int sn1 = csr[cn];
        float e1 = asrc[(size_t)sn1 * SS + head];
        uint4 v1 = *(const uint4*)(xq + (size_t)sn1 * 256 + cbase);
        float e = e0 + ad;
        e = (e >= 0.f) ? e : 0.2f * e;
        float a0 = ok0 ? __expf(fminf(e, 70.f)) : 0.f;
        den += a0;
        f32x2 f;
        f = __builtin_amdgcn_cvt_pk_f32_fp8(v0.x, false); acc[0] += a0 * f.x;  acc[1] += a0 * f.y;
        f = __builtin_amdgcn_cvt_pk_f32_fp8(v0.x, true);  acc[2] += a0 * f.x;  acc[3] += a0 * f.y;
        f = __builtin_amdgcn_cvt_pk_f32_fp8(v0.y, false); acc[4] += a0 * f.x;  acc[5] += a0 * f.y;
        f = __builtin_amdgcn_cvt_pk_f32_fp8(v0.y, true);  acc[6] += a0 * f.x;  acc[7] += a0 * f.y;
        f = __builtin_amdgcn_cvt_pk_f32_fp8(v0.z, false); acc[8] += a0 * f.x;  acc[9] += a0 * f.y;
        f = __builtin_amdgcn_cvt_pk_f32_fp8(v0.z, true);  acc[10] += a0 * f.x; acc[11] += a0 * f.y;
        f = __builtin_amdgcn_cvt_pk_f32_fp8(v0.w, false); acc[12] += a0 * f.x; acc[13] += a0 * f.y;
        f = __builtin_amdgcn_cvt_pk_f32_fp8(v0.w, true);  acc[14] += a0 * f.x; acc[15] += a0 * f.y;
        i = in; e0 = e1; v0 = v1; ok0 = (in < dg);
    }
    den += __shfl_xor(den, 16);
    den += __shfl_xor(den, 32);
    #pragma unroll
    for (int j = 0; j < 16; ++j) {
        acc[j] += __shfl_xor(acc[j], 16);
        acc[j] += __shfl_xor(acc[j], 32);
    }
    if (g) return;
    float inv = 1.0f / den;
    float sN = 0.f, dN = 0.f;
    short8 w0, w1;
    #pragma unroll
    for (int j = 0; j < 16; ++j) {
        int c = cbase + j;
        float v = acc[j] * inv + bias[c];
        v = (v > 0.f) ? v : (__expf(v) - 1.f);   // ELU
        unsigned short bb = f2b(v);
        if (j < 8) w0[j] = (short)bb; else w1[j - 8] = (short)bb;
        sN += v * un[c * 2];
        dN += v * un[c * 2 + 1];
    }
    *(short8*)(o + (size_t)node * 256 + cbase) = w0;
    *(short8*)(o + (size_t)node * 256 + cbase + 8) = w1;
    #pragma unroll
    for (int off = 8; off > 0; off >>= 1) {
        sN += __shfl_xor(sN, off);
        dN += __shfl_xor(dN, off);
    }
    if (l4 == 0) { asn[node] = sN; adn[node] = dN; }
}

// ---------- final gather: fp8 messages, 8 lanes/edge + log_softmax ----------
__global__ __launch_bounds__(256) void k_gf(
    const unsigned char* __restrict__ xq,      // fp8 [NP,64]
    const float* __restrict__ asrc, const float* __restrict__ adst,
    const int* __restrict__ rowptr, const int* __restrict__ deg,
    const unsigned short* __restrict__ csr,
    const float* __restrict__ bias,            // f32 [40]
    float* __restrict__ out) {                 // f32 [N,40]
    int lane = threadIdx.x & 63;
    int node = blockIdx.x * 4 + (threadIdx.x >> 6);
    if (node >= N_NODES) return;
    int ptr = rowptr[node], dg = deg[node];
    int g = lane >> 3, l8 = lane & 7;
    int cbase = l8 * 8;
    float ad = adst[node];
    float acc[8] = {0,0,0,0,0,0,0,0};
    float den = 0.f;
    int dge = (dg + 7) & ~7;
    int i = g;
    int ci = ptr + min(i, dg - 1);
    int sn0 = csr[ci];
    float e0 = asrc[sn0];
    uint2 v0 = *(const uint2*)(xq + (size_t)sn0 * 64 + cbase);
    bool ok0 = (i < dg);
    while (i < dge) {
        int in = i + 8;
        int cn = ptr + min(in, dg - 1);
        int sn1 = csr[cn];
        float e1 = asrc[sn1];
        uint2 v1 = *(const uint2*)(xq + (size_t)sn1 * 64 + cbase);
        float e = e0 + ad;
        e = (e >= 0.f) ? e : 0.2f * e;
        float a0 = ok0 ? __expf(fminf(e, 70.f)) : 0.f;
        den += a0;
        f32x2 f;
        f = __builtin_amdgcn_cvt_pk_f32_fp8(v0.x, false); acc[0] += a0 * f.x; acc[1] += a0 * f.y;
        f = __builtin_amdgcn_cvt_pk_f32_fp8(v0.x, true);  acc[2] += a0 * f.x; acc[3] += a0 * f.y;
        f = __builtin_amdgcn_cvt_pk_f32_fp8(v0.y, false); acc[4] += a0 * f.x; acc[5] += a0 * f.y;
        f = __builtin_amdgcn_cvt_pk_f32_fp8(v0.y, true);  acc[6] += a0 * f.x; acc[7] += a0 * f.y;
        i = in; e0 = e1; v0 = v1; ok0 = (in < dg);
    }
    den += __shfl_xor(den, 8);
    den += __shfl_xor(den, 16);
    den += __shfl_xor(den, 32);
    #pragma unroll
    for (int j = 0; j < 8; ++j) {
        acc[j] += __shfl_xor(acc[j], 8);
        acc[j] += __shfl_xor(acc[j], 16);
        acc[j] += __shfl_xor(acc[j], 32);
    }
    if (g) return;
    float inv = 1.0f / den;
    float val[8], mx = -1e30f;
    #pragma unroll
    for (int j = 0; j < 8; ++j) {
        int c = cbase + j;
        val[j] = (c < 40) ? acc[j] * inv + bias[c] : -1e30f;
        mx = fmaxf(mx, val[j]);
    }
    #pragma unroll
    for (int off = 4; off > 0; off >>= 1) mx = fmaxf(mx, __shfl_xor(mx, off));
    float ex = 0.f;
    #pragma unroll
    for (int j = 0; j < 8; ++j) {
        int c = cbase + j;
        if (c < 40) ex += __expf(val[j] - mx);
    }
    #pragma unroll
    for (int off = 4; off > 0; off >>= 1) ex += __shfl_xor(ex, off);
    float lse = __logf(ex);
    #pragma unroll
    for (int j = 0; j < 8; ++j) {
        int c = cbase + j;
        if (c < 40) out[(size_t)node * 40 + c] = val[j] - mx - lse;
    }
}

extern "C" void kernel_launch(void* const* d_in, const int* in_sizes, int n_in,
                              void* d_out, int out_size, void* d_ws, size_t ws_size,
                              hipStream_t stream) {
    const float* x   = (const float*)d_in[0];
    const int*   ei  = (const int*)d_in[1];
    const float* W0  = (const float*)d_in[2];
    const float* as0 = (const float*)d_in[3];
    const float* ad0 = (const float*)d_in[4];
    const float* b0  = (const float*)d_in[5];
    const float* W1  = (const float*)d_in[6];
    const float* as1 = (const float*)d_in[7];
    const float* ad1 = (const float*)d_in[8];
    const float* b1  = (const float*)d_in[9];
    const float* W2  = (const float*)d_in[10];
    const float* as2 = (const float*)d_in[11];
    const float* ad2 = (const float*)d_in[12];
    const float* b2  = (const float*)d_in[13];
    float* out = (float*)d_out;

    char* p = (char*)d_ws;
    auto carve = [&](size_t bytes) -> char* {
        char* r = p; p += (bytes + 255) & ~(size_t)255; return r;
    };
    unsigned short* xb   = (unsigned short*)carve((size_t)NP * 256 * 2);  // x bf16, later h2
    unsigned short* xpb  = (unsigned short*)carve((size_t)NP * 256 * 2);  // fp8 messages overlay
    unsigned short* h    = (unsigned short*)carve((size_t)NP * 256 * 2);  // h1
    unsigned char*  xq2  = (unsigned char*)carve((size_t)NP * 64);
    unsigned short* Wt0  = (unsigned short*)carve(256 * 256 * 2);
    unsigned short* Wt1  = (unsigned short*)carve(256 * 256 * 2);
    unsigned short* Wt2  = (unsigned short*)carve(64 * 256 * 2);
    unsigned short* u0t  = (unsigned short*)carve(16 * 256 * 2);
    float* att0 = (float*)carve((size_t)NP * 16 * 4);
    float* u1 = (float*)carve(256 * 2 * 4);
    float* u2 = (float*)carve(256 * 2 * 4);
    float* asrc1 = (float*)carve((size_t)N_NODES * 4);
    float* adst1 = (float*)carve((size_t)N_NODES * 4);
    float* asrc2 = (float*)carve((size_t)N_NODES * 4);
    float* adst2 = (float*)carve((size_t)N_NODES * 4);
    int* deg    = (int*)carve((size_t)N_NODES * 4);
    int* rowptr = (int*)carve((size_t)N_NODES * 4);
    int* bcnt   = (int*)carve((size_t)NBUCK * 4);
    int* bstart = (int*)carve((size_t)(NBUCK + 1) * 4);
    int* bcursor= (int*)carve((size_t)NBUCK * 4);
    unsigned int* stage = (unsigned int*)carve((size_t)ETOT * 4);
    unsigned short* csr = (unsigned short*)carve((size_t)ETOT * 2);
    unsigned char* xq = (unsigned char*)xpb;   // fp8 messages overlay (layers 0 and 1)

    hipMemsetAsync(bcnt, 0, (size_t)NBUCK * 4, stream);
    hipMemsetAsync(Wt2, 0, 64 * 256 * 2, stream);  // zero pad cols 40..63

    k_tb<<<(256 * 256 + 255) / 256, 256, 0, stream>>>(W0, Wt0, 256, 256);
    k_tb<<<(256 * 256 + 255) / 256, 256, 0, stream>>>(W1, Wt1, 256, 256);
    k_tb<<<(256 * 40 + 255) / 256, 256, 0, stream>>>(W2, Wt2, 256, 40);

    k_mku0<<<64, 256, 0, stream>>>(W0, as0, ad0, u0t);
    k_mku1<<<64, 256, 0, stream>>>(W1, as1, ad1, u1, 256);
    k_mku1<<<64, 256, 0, stream>>>(W2, as2, ad2, u2, 40);

    k_bcount<<<(ETOT + 4095) / 4096, 256, 0, stream>>>(ei, bcnt);
    k_bscan<<<1, 256, 0, stream>>>(bcnt, bstart, bcursor);
    k_bscatter<<<(ETOT + 8191) / 8192, 256, 0, stream>>>(ei, bcursor, stage);
    k_csr<<<NBUCK, 256, 0, stream>>>(stage, bstart, rowptr, deg, csr);

    dim3 gg(NP / 128, 2);
    dim3 gn(N_NODES / 4);
    dim3 g1(NP / 128);
    // layer 0: fp8 messages; att logits fused into the GEMM (blockIdx.y==0)
    k_split<<<(N_NODES * 64 + 255) / 256, 256, 0, stream>>>(x, xb);
    k_gemm_w<true><<<gg, 256, 0, stream>>>(xb, Wt0, xq, u0t, att0, N_NODES, 256);
    k_gatherq<8><<<gn, 256, 0, stream>>>(xq, att0, att0 + 8, rowptr, deg, csr,
                                         b0, u1, h, asrc1, adst1);
    // layer 1: fp8 messages
    k_gemm_w<false><<<gg, 256, 0, stream>>>(h, Wt1, xq, nullptr, nullptr, N_NODES, 256);
    k_gatherq<1><<<gn, 256, 0, stream>>>(xq, asrc1, adst1, rowptr, deg, csr,
                                         b1, u2, xb, asrc2, adst2);
    // layer 2: fp8 messages + log_softmax
    k_gemm_b<<<g1, 256, 0, stream>>>(xb, Wt2, xq2, N_NODES, 40, 64);
    k_gf<<<gn, 256, 0, stream>>>(xq2, asrc2, adst2, rowptr, deg, csr, b2, out);
}

// Round 13
// 389.689 us; speedup vs baseline: 3.5446x; 1.0576x over previous
//
#include <hip/hip_runtime.h>
#include <hip/hip_bf16.h>

#define N_NODES 50000
#define N_EDGES 1600000
#define ETOT (N_EDGES + N_NODES)
#define NP 50048   // N padded for GEMM row tiles (391 * 128)
#define NBUCK 196  // dst >> 8 buckets (50000/256)
#define BCAP 16384 // per-bucket capacity (expected 8448, >80 sigma headroom)

typedef __attribute__((ext_vector_type(8))) short short8;
typedef __attribute__((ext_vector_type(4))) float f32x4;
typedef __attribute__((ext_vector_type(2))) float f32x2;

__device__ __forceinline__ float b2f(unsigned short u) {
    union { unsigned int i; float f; } v; v.i = ((unsigned int)u) << 16; return v.f;
}
__device__ __forceinline__ unsigned short f2b(float f) {
    union { float f; unsigned int i; } v; v.f = f;
    unsigned int r = v.i + 0x7FFF + ((v.i >> 16) & 1);  // RNE
    return (unsigned short)(r >> 16);
}
__device__ __forceinline__ unsigned char f2q(float f) {
    int r = __builtin_amdgcn_cvt_pk_fp8_f32(f, f, 0, false);
    return (unsigned char)(r & 0xFF);
}

// ---------- merged weight transpose: W0,W1 [256,256], W2 [256,40]->[64,256] padded ----------
__global__ void k_tb3(const float* __restrict__ W0, const float* __restrict__ W1,
                      const float* __restrict__ W2,
                      unsigned short* __restrict__ Wt0, unsigned short* __restrict__ Wt1,
                      unsigned short* __restrict__ Wt2) {
    int idx = blockIdx.x * 256 + threadIdx.x;
    if (idx < 65536) {
        int k = idx >> 8, c = idx & 255;
        Wt0[c * 256 + k] = f2b(W0[idx]);
    } else if (idx < 131072) {
        int i = idx - 65536;
        int k = i >> 8, c = i & 255;
        Wt1[c * 256 + k] = f2b(W1[i]);
    } else {
        int i = idx - 131072;
        if (i >= 16384) return;
        int k = i >> 6, c = i & 63;
        Wt2[c * 256 + k] = (c < 40) ? f2b(W2[k * 40 + c]) : 0;
    }
}

// ---------- layer-0 attention projection -> bf16 Bt layout [16, 256] ----------
__global__ __launch_bounds__(256) void k_mku0(const float* __restrict__ W,
                                              const float* __restrict__ attS,
                                              const float* __restrict__ attD,
                                              unsigned short* __restrict__ u0t) {
    int lane = threadIdx.x & 63;
    int k = blockIdx.x * 4 + (threadIdx.x >> 6);
    if (k >= 256) return;
    int h = lane >> 3, c0 = lane & 7;
    const float* wr = W + (size_t)k * 256 + h * 32;
    float ss = 0.f, sd = 0.f;
    #pragma unroll
    for (int t = 0; t < 4; ++t) {
        int c = c0 + t * 8;
        float w = wr[c];
        ss += w * attS[h * 32 + c];
        sd += w * attD[h * 32 + c];
    }
    #pragma unroll
    for (int off = 1; off < 8; off <<= 1) {
        ss += __shfl_xor(ss, off);
        sd += __shfl_xor(sd, off);
    }
    if (c0 == 0) {
        u0t[(size_t)h * 256 + k] = f2b(ss);
        u0t[(size_t)(8 + h) * 256 + k] = f2b(sd);
    }
}

// merged H=1 projections: rows 0..255 -> u1 (W1, C=256); rows 256..511 -> u2 (W2, C=40)
__global__ __launch_bounds__(256) void k_mku1x2(const float* __restrict__ W1,
                                                const float* __restrict__ as1,
                                                const float* __restrict__ ad1,
                                                const float* __restrict__ W2,
                                                const float* __restrict__ as2,
                                                const float* __restrict__ ad2,
                                                float* __restrict__ u1,
                                                float* __restrict__ u2) {
    int lane = threadIdx.x & 63;
    int r = blockIdx.x * 4 + (threadIdx.x >> 6);
    if (r >= 512) return;
    const float* W; const float* aS; const float* aD; float* u; int C, k;
    if (r < 256) { W = W1; aS = as1; aD = ad1; u = u1; C = 256; k = r; }
    else         { W = W2; aS = as2; aD = ad2; u = u2; C = 40;  k = r - 256; }
    const float* wr = W + (size_t)k * C;
    float ss = 0.f, sd = 0.f;
    for (int c = lane; c < C; c += 64) {
        float w = wr[c];
        ss += w * aS[c];
        sd += w * aD[c];
    }
    #pragma unroll
    for (int off = 32; off > 0; off >>= 1) {
        ss += __shfl_xor(ss, off);
        sd += __shfl_xor(sd, off);
    }
    if (lane == 0) { u[k * 2] = ss; u[k * 2 + 1] = sd; }
}

// ---------- CSR build: fixed-capacity buckets, no global scan ----------
__global__ __launch_bounds__(256) void k_bscatter(const int* __restrict__ ei,
                                                  int* __restrict__ bcnt,
                                                  unsigned int* __restrict__ stage) {
    __shared__ int h[NBUCK], base[NBUCK], cur[NBUCK], gbase[NBUCK];
    __shared__ int tmp[256];
    __shared__ unsigned int buf[8192];
    int t = threadIdx.x;
    for (int i = t; i < NBUCK; i += 256) h[i] = 0;
    __syncthreads();
    int e0 = blockIdx.x * 8192, e1 = min(e0 + 8192, ETOT);
    for (int e = e0 + t; e < e1; e += 256) {
        int dst = (e < N_EDGES) ? ei[N_EDGES + e] : (e - N_EDGES);
        atomicAdd(&h[dst >> 8], 1);
    }
    __syncthreads();
    int v = (t < NBUCK) ? h[t] : 0;
    tmp[t] = v;
    __syncthreads();
    for (int off = 1; off < 256; off <<= 1) {
        int u = (t >= off) ? tmp[t - off] : 0;
        __syncthreads();
        tmp[t] += u;
        __syncthreads();
    }
    if (t < NBUCK) { base[t] = tmp[t] - v; cur[t] = tmp[t] - v; }
    __syncthreads();
    for (int e = e0 + t; e < e1; e += 256) {
        int src, dst;
        if (e < N_EDGES) { src = ei[e]; dst = ei[N_EDGES + e]; }
        else             { src = dst = e - N_EDGES; }
        int b = dst >> 8;
        int p = atomicAdd(&cur[b], 1);
        buf[p] = ((unsigned int)b << 24) | ((unsigned int)src << 8) | (unsigned int)(dst & 255);
    }
    __syncthreads();
    if (t < NBUCK) gbase[t] = t * BCAP + atomicAdd(&bcnt[t], h[t]);
    __syncthreads();
    int cnt = e1 - e0;
    for (int i = t; i < cnt; i += 256) {
        unsigned int pr = buf[i];
        int b = pr >> 24;
        stage[gbase[b] + (i - base[b])] = pr;
    }
}

__global__ __launch_bounds__(256) void k_csr(const unsigned int* __restrict__ stage,
                                             const int* __restrict__ bcnt,
                                             int* __restrict__ rowptr, int* __restrict__ deg,
                                             unsigned short* __restrict__ csr) {
    __shared__ int cnt[256], cur[256], tmp[256];
    int b = blockIdx.x;
    int t = threadIdx.x;
    cnt[t] = 0;
    __syncthreads();
    int s0 = b * BCAP, s1 = s0 + bcnt[b];
    for (int i = s0 + t; i < s1; i += 256)
        atomicAdd(&cnt[stage[i] & 255], 1);
    __syncthreads();
    int v = cnt[t];
    tmp[t] = v;
    __syncthreads();
    for (int off = 1; off < 256; off <<= 1) {
        int u = (t >= off) ? tmp[t - off] : 0;
        __syncthreads();
        tmp[t] += u;
        __syncthreads();
    }
    int ex = tmp[t] - v;
    int node = b * 256 + t;
    if (node < N_NODES) { rowptr[node] = s0 + ex; deg[node] = v; }
    cur[t] = s0 + ex;
    __syncthreads();
    for (int i = s0 + t; i < s1; i += 256) {
        unsigned int pr = stage[i];
        int p = atomicAdd(&cur[pr & 255], 1);
        csr[p] = (unsigned short)((pr >> 8) & 0xFFFF);
    }
}

// ---------- wide bf16 GEMM: 32rows x 128cols per wave; fp8 out; optional fused att ----------
template <bool ATT>
__global__ __launch_bounds__(256) void k_gemm_w(
    const unsigned short* __restrict__ A, const unsigned short* __restrict__ Bt,
    unsigned char* __restrict__ Cout,
    const unsigned short* __restrict__ But,    // bf16 [16,256] or null
    float* __restrict__ Catt,                  // f32 [NP,16] or null
    int nrows, int ldc) {
    const int K = 256;
    int lane = threadIdx.x & 63;
    int wave = threadIdx.x >> 6;
    int row0 = blockIdx.x * 128 + wave * 32;
    int col0 = blockIdx.y * 128;
    bool doAtt = ATT && (blockIdx.y == 0);
    int ar0 = row0 + (lane & 15); if (ar0 >= nrows) ar0 = nrows - 1;
    int ar1 = row0 + 16 + (lane & 15); if (ar1 >= nrows) ar1 = nrows - 1;
    int ks = (lane >> 4) * 8;
    const unsigned short* Ap0 = A + (size_t)ar0 * K + ks;
    const unsigned short* Ap1 = A + (size_t)ar1 * K + ks;
    f32x4 acc[2][8];
    f32x4 aat[2] = {{0,0,0,0},{0,0,0,0}};
    #pragma unroll
    for (int rt = 0; rt < 2; ++rt)
        #pragma unroll
        for (int ct = 0; ct < 8; ++ct) acc[rt][ct] = {0, 0, 0, 0};
    for (int k = 0; k < K; k += 32) {
        short8 a0 = *(const short8*)(Ap0 + k);
        short8 a1 = *(const short8*)(Ap1 + k);
        #pragma unroll
        for (int ct = 0; ct < 8; ++ct) {
            short8 b = *(const short8*)(Bt + (size_t)(col0 + ct * 16 + (lane & 15)) * K + k + ks);
            acc[0][ct] = __builtin_amdgcn_mfma_f32_16x16x32_bf16(a0, b, acc[0][ct], 0, 0, 0);
            acc[1][ct] = __builtin_amdgcn_mfma_f32_16x16x32_bf16(a1, b, acc[1][ct], 0, 0, 0);
        }
        if (doAtt) {
            short8 b = *(const short8*)(But + (size_t)(lane & 15) * K + k + ks);
            aat[0] = __builtin_amdgcn_mfma_f32_16x16x32_bf16(a0, b, aat[0], 0, 0, 0);
            aat[1] = __builtin_amdgcn_mfma_f32_16x16x32_bf16(a1, b, aat[1], 0, 0, 0);
        }
    }
    int cb = lane & 15;
    #pragma unroll
    for (int rt = 0; rt < 2; ++rt) {
        int rbase = row0 + rt * 16 + (lane >> 4) * 4;
        #pragma unroll
        for (int ct = 0; ct < 8; ++ct) {
            int cc = col0 + ct * 16 + cb;
            #pragma unroll
            for (int j = 0; j < 4; ++j)
                Cout[(size_t)(rbase + j) * ldc + cc] = f2q(acc[rt][ct][j]);
        }
        if (doAtt) {
            #pragma unroll
            for (int j = 0; j < 4; ++j)
                Catt[(size_t)(rbase + j) * 16 + cb] = aat[rt][j];
        }
    }
}

// ---------- narrow bf16 GEMM (64 cols), fp8 output, for layer 2 ----------
__global__ __launch_bounds__(256) void k_gemm_b(
    const unsigned short* __restrict__ A, const unsigned short* __restrict__ Bt,
    unsigned char* __restrict__ Cout, int nrows, int ncols, int ldc) {
    const int K = 256;
    int lane = threadIdx.x & 63;
    int wave = threadIdx.x >> 6;
    int row0 = blockIdx.x * 128 + wave * 32;
    int ar0 = row0 + (lane & 15); if (ar0 >= nrows) ar0 = nrows - 1;
    int ar1 = row0 + 16 + (lane & 15); if (ar1 >= nrows) ar1 = nrows - 1;
    int ks = (lane >> 4) * 8;
    const unsigned short* Ap0 = A + (size_t)ar0 * K + ks;
    const unsigned short* Ap1 = A + (size_t)ar1 * K + ks;
    f32x4 acc[2][4] = {{{0,0,0,0},{0,0,0,0},{0,0,0,0},{0,0,0,0}},
                       {{0,0,0,0},{0,0,0,0},{0,0,0,0},{0,0,0,0}}};
    for (int k = 0; k < K; k += 32) {
        short8 a0 = *(const short8*)(Ap0 + k);
        short8 a1 = *(const short8*)(Ap1 + k);
        #pragma unroll
        for (int ct = 0; ct < 4; ++ct) {
            short8 b = *(const short8*)(Bt + (size_t)(ct * 16 + (lane & 15)) * K + k + ks);
            acc[0][ct] = __builtin_amdgcn_mfma_f32_16x16x32_bf16(a0, b, acc[0][ct], 0, 0, 0);
            acc[1][ct] = __builtin_amdgcn_mfma_f32_16x16x32_bf16(a1, b, acc[1][ct], 0, 0, 0);
        }
    }
    int cb = lane & 15;
    #pragma unroll
    for (int rt = 0; rt < 2; ++rt) {
        int rbase = row0 + rt * 16 + (lane >> 4) * 4;
        #pragma unroll
        for (int ct = 0; ct < 4; ++ct) {
            int cc = ct * 16 + cb;
            #pragma unroll
            for (int j = 0; j < 4; ++j) {
                float v = (cc < ncols) ? acc[rt][ct][j] : 0.f;
                Cout[(size_t)(rbase + j) * ldc + cc] = f2q(v);
            }
        }
    }
}

// ---------- x f32 -> xb bf16, streaming ----------
__global__ __launch_bounds__(256) void k_split(const float* __restrict__ x,
                                               unsigned short* __restrict__ xb) {
    int idx = blockIdx.x * 256 + threadIdx.x;
    if (idx >= N_NODES * 64) return;
    float4 v = *(const float4*)(x + (size_t)idx * 4);
    ushort4 w;
    w.x = f2b(v.x); w.y = f2b(v.y); w.z = f2b(v.z); w.w = f2b(v.w);
    *(ushort4*)(xb + (size_t)idx * 4) = w;
}

// ---------- fp8 gather (layers 0 & 1): 16 lanes/edge, 4 edges in flight ----------
// H==8: asrc/adst point into att0 with row stride 16 (adst = att0 + 8).
template <int H>
__global__ __launch_bounds__(256) void k_gatherq(
    const unsigned char* __restrict__ xq,      // fp8 [NP,256]
    const float* __restrict__ asrc, const float* __restrict__ adst,
    const int* __restrict__ rowptr, const int* __restrict__ deg,
    const unsigned short* __restrict__ csr,
    const float* __restrict__ bias,            // f32 [256]
    const float* __restrict__ un,              // f32 [256*2] (next-layer u)
    unsigned short* __restrict__ o,            // bf16 [NP,256]
    float* __restrict__ asn, float* __restrict__ adn) {
    constexpr int SS = (H == 8) ? 16 : 1;
    int lane = threadIdx.x & 63;
    int node = blockIdx.x * 4 + (threadIdx.x >> 6);
    if (node >= N_NODES) return;
    int ptr = rowptr[node], dg = deg[node];
    int g = lane >> 4, l4 = lane & 15;
    int cbase = l4 * 16;
    int head = (H == 8) ? (l4 >> 1) : 0;
    float ad = adst[(size_t)node * SS + head];
    float acc[16];
    #pragma unroll
    for (int j = 0; j < 16; ++j) acc[j] = 0.f;
    float den = 0.f;
    int dge = (dg + 3) & ~3;
    int i = g;
    int ci = ptr + min(i, dg - 1);
    int sn0 = csr[ci];
    float e0 = asrc[(size_t)sn0 * SS + head];
    uint4 v0 = *(const uint4*)(xq + (size_t)sn0 * 256 + cbase);
    bool ok0 = (i < dg);
    while (i < dge) {
        int in = i + 4;
        int cn = ptr + min(in, dg - 1);
        int sn1 = csr[cn];
        float e1 = asrc[(size_t)sn1 * SS + head];
        uint4 v1 = *(const uint4*)(xq + (size_t)sn1 * 256 + cbase);
        float e = e0 + ad;
        e = (e >= 0.f) ? e : 0.2f * e;
        float a0 = ok0 ? __expf(fminf(e, 70.f)) : 0.f;
        den += a0;
        f32x2 f;
        f = __builtin_amdgcn_cvt_pk_f32_fp8(v0.x, false); acc[0] += a0 * f.x;  acc[1] += a0 * f.y;
        f = __builtin_amdgcn_cvt_pk_f32_fp8(v0.x, true);  acc[2] += a0 * f.x;  acc[3] += a0 * f.y;
        f = __builtin_amdgcn_cvt_pk_f32_fp8(v0.y, false); acc[4] += a0 * f.x;  acc[5] += a0 * f.y;
        f = __builtin_amdgcn_cvt_pk_f32_fp8(v0.y, true);  acc[6] += a0 * f.x;  acc[7] += a0 * f.y;
        f = __builtin_amdgcn_cvt_pk_f32_fp8(v0.z, false); acc[8] += a0 * f.x;  acc[9] += a0 * f.y;
        f = __builtin_amdgcn_cvt_pk_f32_fp8(v0.z, true);  acc[10] += a0 * f.x; acc[11] += a0 * f.y;
        f = __builtin_amdgcn_cvt_pk_f32_fp8(v0.w, false); acc[12] += a0 * f.x; acc[13] += a0 * f.y;
        f = __builtin_amdgcn_cvt_pk_f32_fp8(v0.w, true);  acc[14] += a0 * f.x; acc[15] += a0 * f.y;
        i = in; e0 = e1; v0 = v1; ok0 = (in < dg);
    }
    den += __shfl_xor(den, 16);
    den += __shfl_xor(den, 32);
    #pragma unroll
    for (int j = 0; j < 16; ++j) {
        acc[j] += __shfl_xor(acc[j], 16);
        acc[j] += __shfl_xor(acc[j], 32);
    }
    if (g) return;
    float inv = 1.0f / den;
    float sN = 0.f, dN = 0.f;
    short8 w0, w1;
    #pragma unroll
    for (int j = 0; j < 16; ++j) {
        int c = cbase + j;
        float v = acc[j] * inv + bias[c];
        v = (v > 0.f) ? v : (__expf(v) - 1.f);   // ELU
        unsigned short bb = f2b(v);
        if (j < 8) w0[j] = (short)bb; else w1[j - 8] = (short)bb;
        sN += v * un[c * 2];
        dN += v * un[c * 2 + 1];
    }
    *(short8*)(o + (size_t)node * 256 + cbase) = w0;
    *(short8*)(o + (size_t)node * 256 + cbase + 8) = w1;
    #pragma unroll
    for (int off = 8; off > 0; off >>= 1) {
        sN += __shfl_xor(sN, off);
        dN += __shfl_xor(dN, off);
    }
    if (l4 == 0) { asn[node] = sN; adn[node] = dN; }
}

// ---------- final gather: fp8 messages, 8 lanes/edge + log_softmax ----------
__global__ __launch_bounds__(256) void k_gf(
    const unsigned char* __restrict__ xq,      // fp8 [NP,64]
    const float* __restrict__ asrc, const float* __restrict__ adst,
    const int* __restrict__ rowptr, const int* __restrict__ deg,
    const unsigned short* __restrict__ csr,
    const float* __restrict__ bias,            // f32 [40]
    float* __restrict__ out) {                 // f32 [N,40]
    int lane = threadIdx.x & 63;
    int node = blockIdx.x * 4 + (threadIdx.x >> 6);
    if (node >= N_NODES) return;
    int ptr = rowptr[node], dg = deg[node];
    int g = lane >> 3, l8 = lane & 7;
    int cbase = l8 * 8;
    float ad = adst[node];
    float acc[8] = {0,0,0,0,0,0,0,0};
    float den = 0.f;
    int dge = (dg + 7) & ~7;
    int i = g;
    int ci = ptr + min(i, dg - 1);
    int sn0 = csr[ci];
    float e0 = asrc[sn0];
    uint2 v0 = *(const uint2*)(xq + (size_t)sn0 * 64 + cbase);
    bool ok0 = (i < dg);
    while (i < dge) {
        int in = i + 8;
        int cn = ptr + min(in, dg - 1);
        int sn1 = csr[cn];
        float e1 = asrc[sn1];
        uint2 v1 = *(const uint2*)(xq + (size_t)sn1 * 64 + cbase);
        float e = e0 + ad;
        e = (e >= 0.f) ? e : 0.2f * e;
        float a0 = ok0 ? __expf(fminf(e, 70.f)) : 0.f;
        den += a0;
        f32x2 f;
        f = __builtin_amdgcn_cvt_pk_f32_fp8(v0.x, false); acc[0] += a0 * f.x; acc[1] += a0 * f.y;
        f = __builtin_amdgcn_cvt_pk_f32_fp8(v0.x, true);  acc[2] += a0 * f.x; acc[3] += a0 * f.y;
        f = __builtin_amdgcn_cvt_pk_f32_fp8(v0.y, false); acc[4] += a0 * f.x; acc[5] += a0 * f.y;
        f = __builtin_amdgcn_cvt_pk_f32_fp8(v0.y, true);  acc[6] += a0 * f.x; acc[7] += a0 * f.y;
        i = in; e0 = e1; v0 = v1; ok0 = (in < dg);
    }
    den += __shfl_xor(den, 8);
    den += __shfl_xor(den, 16);
    den += __shfl_xor(den, 32);
    #pragma unroll
    for (int j = 0; j < 8; ++j) {
        acc[j] += __shfl_xor(acc[j], 8);
        acc[j] += __shfl_xor(acc[j], 16);
        acc[j] += __shfl_xor(acc[j], 32);
    }
    if (g) return;
    float inv = 1.0f / den;
    float val[8], mx = -1e30f;
    #pragma unroll
    for (int j = 0; j < 8; ++j) {
        int c = cbase + j;
        val[j] = (c < 40) ? acc[j] * inv + bias[c] : -1e30f;
        mx = fmaxf(mx, val[j]);
    }
    #pragma unroll
    for (int off = 4; off > 0; off >>= 1) mx = fmaxf(mx, __shfl_xor(mx, off));
    float ex = 0.f;
    #pragma unroll
    for (int j = 0; j < 8; ++j) {
        int c = cbase + j;
        if (c < 40) ex += __expf(val[j] - mx);
    }
    #pragma unroll
    for (int off = 4; off > 0; off >>= 1) ex += __shfl_xor(ex, off);
    float lse = __logf(ex);
    #pragma unroll
    for (int j = 0; j < 8; ++j) {
        int c = cbase + j;
        if (c < 40) out[(size_t)node * 40 + c] = val[j] - mx - lse;
    }
}

extern "C" void kernel_launch(void* const* d_in, const int* in_sizes, int n_in,
                              void* d_out, int out_size, void* d_ws, size_t ws_size,
                              hipStream_t stream) {
    const float* x   = (const float*)d_in[0];
    const int*   ei  = (const int*)d_in[1];
    const float* W0  = (const float*)d_in[2];
    const float* as0 = (const float*)d_in[3];
    const float* ad0 = (const float*)d_in[4];
    const float* b0  = (const float*)d_in[5];
    const float* W1  = (const float*)d_in[6];
    const float* as1 = (const float*)d_in[7];
    const float* ad1 = (const float*)d_in[8];
    const float* b1  = (const float*)d_in[9];
    const float* W2  = (const float*)d_in[10];
    const float* as2 = (const float*)d_in[11];
    const float* ad2 = (const float*)d_in[12];
    const float* b2  = (const float*)d_in[13];
    float* out = (float*)d_out;

    char* p = (char*)d_ws;
    auto carve = [&](size_t bytes) -> char* {
        char* r = p; p += (bytes + 255) & ~(size_t)255; return r;
    };
    unsigned short* xb   = (unsigned short*)carve((size_t)NP * 256 * 2);  // x bf16, later h2
    unsigned short* xpb  = (unsigned short*)carve((size_t)NP * 256 * 2);  // fp8 messages overlay
    unsigned short* h    = (unsigned short*)carve((size_t)NP * 256 * 2);  // h1
    unsigned char*  xq2  = (unsigned char*)carve((size_t)NP * 64);
    unsigned short* Wt0  = (unsigned short*)carve(256 * 256 * 2);
    unsigned short* Wt1  = (unsigned short*)carve(256 * 256 * 2);
    unsigned short* Wt2  = (unsigned short*)carve(64 * 256 * 2);
    unsigned short* u0t  = (unsigned short*)carve(16 * 256 * 2);
    float* att0 = (float*)carve((size_t)NP * 16 * 4);
    float* u1 = (float*)carve(256 * 2 * 4);
    float* u2 = (float*)carve(256 * 2 * 4);
    float* asrc1 = (float*)carve((size_t)N_NODES * 4);
    float* adst1 = (float*)carve((size_t)N_NODES * 4);
    float* asrc2 = (float*)carve((size_t)N_NODES * 4);
    float* adst2 = (float*)carve((size_t)N_NODES * 4);
    int* deg    = (int*)carve((size_t)N_NODES * 4);
    int* rowptr = (int*)carve((size_t)N_NODES * 4);
    int* bcnt   = (int*)carve((size_t)NBUCK * 4);
    unsigned int* stage = (unsigned int*)carve((size_t)NBUCK * BCAP * 4);
    unsigned short* csr = (unsigned short*)carve((size_t)NBUCK * BCAP * 2);
    unsigned char* xq = (unsigned char*)xpb;   // fp8 messages overlay (layers 0 and 1)

    hipMemsetAsync(bcnt, 0, (size_t)NBUCK * 4, stream);

    k_tb3<<<(147456 + 255) / 256, 256, 0, stream>>>(W0, W1, W2, Wt0, Wt1, Wt2);
    k_mku0<<<64, 256, 0, stream>>>(W0, as0, ad0, u0t);
    k_mku1x2<<<128, 256, 0, stream>>>(W1, as1, ad1, W2, as2, ad2, u1, u2);

    k_bscatter<<<(ETOT + 8191) / 8192, 256, 0, stream>>>(ei, bcnt, stage);
    k_csr<<<NBUCK, 256, 0, stream>>>(stage, bcnt, rowptr, deg, csr);

    dim3 gg(NP / 128, 2);
    dim3 gn(N_NODES / 4);
    dim3 g1(NP / 128);
    // layer 0: fp8 messages; att logits fused into the GEMM (blockIdx.y==0)
    k_split<<<(N_NODES * 64 + 255) / 256, 256, 0, stream>>>(x, xb);
    k_gemm_w<true><<<gg, 256, 0, stream>>>(xb, Wt0, xq, u0t, att0, N_NODES, 256);
    k_gatherq<8><<<gn, 256, 0, stream>>>(xq, att0, att0 + 8, rowptr, deg, csr,
                                         b0, u1, h, asrc1, adst1);
    // layer 1: fp8 messages
    k_gemm_w<false><<<gg, 256, 0, stream>>>(h, Wt1, xq, nullptr, nullptr, N_NODES, 256);
    k_gatherq<1><<<gn, 256, 0, stream>>>(xq, asrc1, adst1, rowptr, deg, csr,
                                         b1, u2, xb, asrc2, adst2);
    // layer 2: fp8 messages + log_softmax
    k_gemm_b<<<g1, 256, 0, stream>>>(xb, Wt2, xq2, N_NODES, 40, 64);
    k_gf<<<gn, 256, 0, stream>>>(xq2, asrc2, adst2, rowptr, deg, csr, b2, out);
}

// Round 14
// 380.848 us; speedup vs baseline: 3.6269x; 1.0232x over previous
//
#include <hip/hip_runtime.h>
#include <hip/hip_bf16.h>

#define N_NODES 50000
#define N_EDGES 1600000
#define ETOT (N_EDGES + N_NODES)
#define NP 50048   // N padded for GEMM row tiles (391 * 128)
#define NBUCK 196  // dst >> 8 buckets (50000/256)
#define BCAP 16384 // per-bucket capacity (expected 8448, >80 sigma headroom)

typedef __attribute__((ext_vector_type(8))) short short8;
typedef __attribute__((ext_vector_type(4))) float f32x4;
typedef __attribute__((ext_vector_type(2))) float f32x2;

__device__ __forceinline__ float b2f(unsigned short u) {
    union { unsigned int i; float f; } v; v.i = ((unsigned int)u) << 16; return v.f;
}
__device__ __forceinline__ unsigned short f2b(float f) {
    union { float f; unsigned int i; } v; v.f = f;
    unsigned int r = v.i + 0x7FFF + ((v.i >> 16) & 1);  // RNE
    return (unsigned short)(r >> 16);
}
__device__ __forceinline__ unsigned char f2q(float f) {
    int r = __builtin_amdgcn_cvt_pk_fp8_f32(f, f, 0, false);
    return (unsigned char)(r & 0xFF);
}

// ---------- merged weight transpose + bcnt zeroing ----------
__global__ void k_tb3(const float* __restrict__ W0, const float* __restrict__ W1,
                      const float* __restrict__ W2,
                      unsigned short* __restrict__ Wt0, unsigned short* __restrict__ Wt1,
                      unsigned short* __restrict__ Wt2, int* __restrict__ bcnt) {
    int idx = blockIdx.x * 256 + threadIdx.x;
    if (blockIdx.x == 0 && threadIdx.x < NBUCK) bcnt[threadIdx.x] = 0;
    if (idx < 65536) {
        int k = idx >> 8, c = idx & 255;
        Wt0[c * 256 + k] = f2b(W0[idx]);
    } else if (idx < 131072) {
        int i = idx - 65536;
        int k = i >> 8, c = i & 255;
        Wt1[c * 256 + k] = f2b(W1[i]);
    } else {
        int i = idx - 131072;
        if (i >= 16384) return;
        int k = i >> 6, c = i & 63;
        Wt2[c * 256 + k] = (c < 40) ? f2b(W2[k * 40 + c]) : 0;
    }
}

// ---------- layer-0 attention projection -> bf16 Bt layout [16, 256] ----------
__global__ __launch_bounds__(256) void k_mku0(const float* __restrict__ W,
                                              const float* __restrict__ attS,
                                              const float* __restrict__ attD,
                                              unsigned short* __restrict__ u0t) {
    int lane = threadIdx.x & 63;
    int k = blockIdx.x * 4 + (threadIdx.x >> 6);
    if (k >= 256) return;
    int h = lane >> 3, c0 = lane & 7;
    const float* wr = W + (size_t)k * 256 + h * 32;
    float ss = 0.f, sd = 0.f;
    #pragma unroll
    for (int t = 0; t < 4; ++t) {
        int c = c0 + t * 8;
        float w = wr[c];
        ss += w * attS[h * 32 + c];
        sd += w * attD[h * 32 + c];
    }
    #pragma unroll
    for (int off = 1; off < 8; off <<= 1) {
        ss += __shfl_xor(ss, off);
        sd += __shfl_xor(sd, off);
    }
    if (c0 == 0) {
        u0t[(size_t)h * 256 + k] = f2b(ss);
        u0t[(size_t)(8 + h) * 256 + k] = f2b(sd);
    }
}

// merged H=1 projections: rows 0..255 -> u1 (W1, C=256); rows 256..511 -> u2 (W2, C=40)
__global__ __launch_bounds__(256) void k_mku1x2(const float* __restrict__ W1,
                                                const float* __restrict__ as1,
                                                const float* __restrict__ ad1,
                                                const float* __restrict__ W2,
                                                const float* __restrict__ as2,
                                                const float* __restrict__ ad2,
                                                float* __restrict__ u1,
                                                float* __restrict__ u2) {
    int lane = threadIdx.x & 63;
    int r = blockIdx.x * 4 + (threadIdx.x >> 6);
    if (r >= 512) return;
    const float* W; const float* aS; const float* aD; float* u; int C, k;
    if (r < 256) { W = W1; aS = as1; aD = ad1; u = u1; C = 256; k = r; }
    else         { W = W2; aS = as2; aD = ad2; u = u2; C = 40;  k = r - 256; }
    const float* wr = W + (size_t)k * C;
    float ss = 0.f, sd = 0.f;
    for (int c = lane; c < C; c += 64) {
        float w = wr[c];
        ss += w * aS[c];
        sd += w * aD[c];
    }
    #pragma unroll
    for (int off = 32; off > 0; off >>= 1) {
        ss += __shfl_xor(ss, off);
        sd += __shfl_xor(sd, off);
    }
    if (lane == 0) { u[k * 2] = ss; u[k * 2 + 1] = sd; }
}

// ---------- CSR build: fixed-capacity buckets, no global scan ----------
__global__ __launch_bounds__(256) void k_bscatter(const int* __restrict__ ei,
                                                  int* __restrict__ bcnt,
                                                  unsigned int* __restrict__ stage) {
    __shared__ int h[NBUCK], base[NBUCK], cur[NBUCK], gbase[NBUCK];
    __shared__ int tmp[256];
    __shared__ unsigned int buf[8192];
    int t = threadIdx.x;
    for (int i = t; i < NBUCK; i += 256) h[i] = 0;
    __syncthreads();
    int e0 = blockIdx.x * 8192, e1 = min(e0 + 8192, ETOT);
    for (int e = e0 + t; e < e1; e += 256) {
        int dst = (e < N_EDGES) ? ei[N_EDGES + e] : (e - N_EDGES);
        atomicAdd(&h[dst >> 8], 1);
    }
    __syncthreads();
    int v = (t < NBUCK) ? h[t] : 0;
    tmp[t] = v;
    __syncthreads();
    for (int off = 1; off < 256; off <<= 1) {
        int u = (t >= off) ? tmp[t - off] : 0;
        __syncthreads();
        tmp[t] += u;
        __syncthreads();
    }
    if (t < NBUCK) { base[t] = tmp[t] - v; cur[t] = tmp[t] - v; }
    __syncthreads();
    for (int e = e0 + t; e < e1; e += 256) {
        int src, dst;
        if (e < N_EDGES) { src = ei[e]; dst = ei[N_EDGES + e]; }
        else             { src = dst = e - N_EDGES; }
        int b = dst >> 8;
        int p = atomicAdd(&cur[b], 1);
        buf[p] = ((unsigned int)b << 24) | ((unsigned int)src << 8) | (unsigned int)(dst & 255);
    }
    __syncthreads();
    if (t < NBUCK) gbase[t] = t * BCAP + atomicAdd(&bcnt[t], h[t]);
    __syncthreads();
    int cnt = e1 - e0;
    for (int i = t; i < cnt; i += 256) {
        unsigned int pr = buf[i];
        int b = pr >> 24;
        stage[gbase[b] + (i - base[b])] = pr;
    }
}

__global__ __launch_bounds__(256) void k_csr(const unsigned int* __restrict__ stage,
                                             const int* __restrict__ bcnt,
                                             int* __restrict__ rowptr, int* __restrict__ deg,
                                             unsigned short* __restrict__ csr) {
    __shared__ int cnt[256], cur[256], tmp[256];
    int b = blockIdx.x;
    int t = threadIdx.x;
    cnt[t] = 0;
    __syncthreads();
    int s0 = b * BCAP, s1 = s0 + bcnt[b];
    for (int i = s0 + t; i < s1; i += 256)
        atomicAdd(&cnt[stage[i] & 255], 1);
    __syncthreads();
    int v = cnt[t];
    tmp[t] = v;
    __syncthreads();
    for (int off = 1; off < 256; off <<= 1) {
        int u = (t >= off) ? tmp[t - off] : 0;
        __syncthreads();
        tmp[t] += u;
        __syncthreads();
    }
    int ex = tmp[t] - v;
    int node = b * 256 + t;
    if (node < N_NODES) { rowptr[node] = s0 + ex; deg[node] = v; }
    cur[t] = s0 + ex;
    __syncthreads();
    for (int i = s0 + t; i < s1; i += 256) {
        unsigned int pr = stage[i];
        int p = atomicAdd(&cur[pr & 255], 1);
        csr[p] = (unsigned short)((pr >> 8) & 0xFFFF);
    }
}

// ---------- wide bf16 GEMM: 32rows x 128cols per wave; fp8 out ----------
// F32A: A is f32 (x), converted in-register; else bf16. ATT: fused att logits.
template <bool ATT, bool F32A>
__global__ __launch_bounds__(256) void k_gemm_w(
    const void* __restrict__ Av, const unsigned short* __restrict__ Bt,
    unsigned char* __restrict__ Cout,
    const unsigned short* __restrict__ But,    // bf16 [16,256] or null
    float* __restrict__ Catt,                  // f32 [NP,16] or null
    int nrows, int ldc) {
    const int K = 256;
    int lane = threadIdx.x & 63;
    int wave = threadIdx.x >> 6;
    int row0 = blockIdx.x * 128 + wave * 32;
    int col0 = blockIdx.y * 128;
    bool doAtt = ATT && (blockIdx.y == 0);
    int ar0 = row0 + (lane & 15); if (ar0 >= nrows) ar0 = nrows - 1;
    int ar1 = row0 + 16 + (lane & 15); if (ar1 >= nrows) ar1 = nrows - 1;
    int ks = (lane >> 4) * 8;
    const unsigned short* A16 = (const unsigned short*)Av;
    const float* A32 = (const float*)Av;
    f32x4 acc[2][8];
    f32x4 aat[2] = {{0,0,0,0},{0,0,0,0}};
    #pragma unroll
    for (int rt = 0; rt < 2; ++rt)
        #pragma unroll
        for (int ct = 0; ct < 8; ++ct) acc[rt][ct] = {0, 0, 0, 0};
    for (int k = 0; k < K; k += 32) {
        short8 a0, a1;
        if (F32A) {
            const float* p0 = A32 + (size_t)ar0 * K + ks + k;
            const float* p1 = A32 + (size_t)ar1 * K + ks + k;
            float4 x0 = *(const float4*)p0, y0 = *(const float4*)(p0 + 4);
            float4 x1 = *(const float4*)p1, y1 = *(const float4*)(p1 + 4);
            a0[0] = (short)f2b(x0.x); a0[1] = (short)f2b(x0.y);
            a0[2] = (short)f2b(x0.z); a0[3] = (short)f2b(x0.w);
            a0[4] = (short)f2b(y0.x); a0[5] = (short)f2b(y0.y);
            a0[6] = (short)f2b(y0.z); a0[7] = (short)f2b(y0.w);
            a1[0] = (short)f2b(x1.x); a1[1] = (short)f2b(x1.y);
            a1[2] = (short)f2b(x1.z); a1[3] = (short)f2b(x1.w);
            a1[4] = (short)f2b(y1.x); a1[5] = (short)f2b(y1.y);
            a1[6] = (short)f2b(y1.z); a1[7] = (short)f2b(y1.w);
        } else {
            a0 = *(const short8*)(A16 + (size_t)ar0 * K + ks + k);
            a1 = *(const short8*)(A16 + (size_t)ar1 * K + ks + k);
        }
        #pragma unroll
        for (int ct = 0; ct < 8; ++ct) {
            short8 b = *(const short8*)(Bt + (size_t)(col0 + ct * 16 + (lane & 15)) * K + k + ks);
            acc[0][ct] = __builtin_amdgcn_mfma_f32_16x16x32_bf16(a0, b, acc[0][ct], 0, 0, 0);
            acc[1][ct] = __builtin_amdgcn_mfma_f32_16x16x32_bf16(a1, b, acc[1][ct], 0, 0, 0);
        }
        if (doAtt) {
            short8 b = *(const short8*)(But + (size_t)(lane & 15) * K + k + ks);
            aat[0] = __builtin_amdgcn_mfma_f32_16x16x32_bf16(a0, b, aat[0], 0, 0, 0);
            aat[1] = __builtin_amdgcn_mfma_f32_16x16x32_bf16(a1, b, aat[1], 0, 0, 0);
        }
    }
    int cb = lane & 15;
    #pragma unroll
    for (int rt = 0; rt < 2; ++rt) {
        int rbase = row0 + rt * 16 + (lane >> 4) * 4;
        #pragma unroll
        for (int ct = 0; ct < 8; ++ct) {
            int cc = col0 + ct * 16 + cb;
            #pragma unroll
            for (int j = 0; j < 4; ++j)
                Cout[(size_t)(rbase + j) * ldc + cc] = f2q(acc[rt][ct][j]);
        }
        if (doAtt) {
            #pragma unroll
            for (int j = 0; j < 4; ++j)
                Catt[(size_t)(rbase + j) * 16 + cb] = aat[rt][j];
        }
    }
}

// ---------- narrow bf16 GEMM (64 cols), fp8 output, for layer 2 ----------
__global__ __launch_bounds__(256) void k_gemm_b(
    const unsigned short* __restrict__ A, const unsigned short* __restrict__ Bt,
    unsigned char* __restrict__ Cout, int nrows, int ncols, int ldc) {
    const int K = 256;
    int lane = threadIdx.x & 63;
    int wave = threadIdx.x >> 6;
    int row0 = blockIdx.x * 128 + wave * 32;
    int ar0 = row0 + (lane & 15); if (ar0 >= nrows) ar0 = nrows - 1;
    int ar1 = row0 + 16 + (lane & 15); if (ar1 >= nrows) ar1 = nrows - 1;
    int ks = (lane >> 4) * 8;
    const unsigned short* Ap0 = A + (size_t)ar0 * K + ks;
    const unsigned short* Ap1 = A + (size_t)ar1 * K + ks;
    f32x4 acc[2][4] = {{{0,0,0,0},{0,0,0,0},{0,0,0,0},{0,0,0,0}},
                       {{0,0,0,0},{0,0,0,0},{0,0,0,0},{0,0,0,0}}};
    for (int k = 0; k < K; k += 32) {
        short8 a0 = *(const short8*)(Ap0 + k);
        short8 a1 = *(const short8*)(Ap1 + k);
        #pragma unroll
        for (int ct = 0; ct < 4; ++ct) {
            short8 b = *(const short8*)(Bt + (size_t)(ct * 16 + (lane & 15)) * K + k + ks);
            acc[0][ct] = __builtin_amdgcn_mfma_f32_16x16x32_bf16(a0, b, acc[0][ct], 0, 0, 0);
            acc[1][ct] = __builtin_amdgcn_mfma_f32_16x16x32_bf16(a1, b, acc[1][ct], 0, 0, 0);
        }
    }
    int cb = lane & 15;
    #pragma unroll
    for (int rt = 0; rt < 2; ++rt) {
        int rbase = row0 + rt * 16 + (lane >> 4) * 4;
        #pragma unroll
        for (int ct = 0; ct < 4; ++ct) {
            int cc = ct * 16 + cb;
            #pragma unroll
            for (int j = 0; j < 4; ++j) {
                float v = (cc < ncols) ? acc[rt][ct][j] : 0.f;
                Cout[(size_t)(rbase + j) * ldc + cc] = f2q(v);
            }
        }
    }
}

// ---------- fp8 gather (layers 0 & 1): 16 lanes/edge, 4 edges in flight ----------
// H==8: asrc/adst point into att0 with row stride 16 (adst = att0 + 8).
template <int H>
__global__ __launch_bounds__(256) void k_gatherq(
    const unsigned char* __restrict__ xq,      // fp8 [NP,256]
    const float* __restrict__ asrc, const float* __restrict__ adst,
    const int* __restrict__ rowptr, const int* __restrict__ deg,
    const unsigned short* __restrict__ csr,
    const float* __restrict__ bias,            // f32 [256]
    const float* __restrict__ un,              // f32 [256*2] (next-layer u)
    unsigned short* __restrict__ o,            // bf16 [NP,256]
    float* __restrict__ asn, float* __restrict__ adn) {
    constexpr int SS = (H == 8) ? 16 : 1;
    int lane = threadIdx.x & 63;
    int node = blockIdx.x * 4 + (threadIdx.x >> 6);
    if (node >= N_NODES) return;
    int ptr = rowptr[node], dg = deg[node];
    int g = lane >> 4, l4 = lane & 15;
    int cbase = l4 * 16;
    int head = (H == 8) ? (l4 >> 1) : 0;
    float ad = adst[(size_t)node * SS + head];
    float acc[16];
    #pragma unroll
    for (int j = 0; j < 16; ++j) acc[j] = 0.f;
    float den = 0.f;
    int dge = (dg + 3) & ~3;
    int i = g;
    int ci = ptr + min(i, dg - 1);
    int sn0 = csr[ci];
    float e0 = asrc[(size_t)sn0 * SS + head];
    uint4 v0 = *(const uint4*)(xq + (size_t)sn0 * 256 + cbase);
    bool ok0 = (i < dg);
    while (i < dge) {
        int in = i + 4;
        int cn = ptr + min(in, dg - 1);
        int sn1 = csr[cn];
        float e1 = asrc[(size_t)sn1 * SS + head];
        uint4 v1 = *(const uint4*)(xq + (size_t)sn1 * 256 + cbase);
        float e = e0 + ad;
        e = (e >= 0.f) ? e : 0.2f * e;
        float a0 = ok0 ? __expf(fminf(e, 70.f)) : 0.f;
        den += a0;
        f32x2 f;
        f = __builtin_amdgcn_cvt_pk_f32_fp8(v0.x, false); acc[0] += a0 * f.x;  acc[1] += a0 * f.y;
        f = __builtin_amdgcn_cvt_pk_f32_fp8(v0.x, true);  acc[2] += a0 * f.x;  acc[3] += a0 * f.y;
        f = __builtin_amdgcn_cvt_pk_f32_fp8(v0.y, false); acc[4] += a0 * f.x;  acc[5] += a0 * f.y;
        f = __builtin_amdgcn_cvt_pk_f32_fp8(v0.y, true);  acc[6] += a0 * f.x;  acc[7] += a0 * f.y;
        f = __builtin_amdgcn_cvt_pk_f32_fp8(v0.z, false); acc[8] += a0 * f.x;  acc[9] += a0 * f.y;
        f = __builtin_amdgcn_cvt_pk_f32_fp8(v0.z, true);  acc[10] += a0 * f.x; acc[11] += a0 * f.y;
        f = __builtin_amdgcn_cvt_pk_f32_fp8(v0.w, false); acc[12] += a0 * f.x; acc[13] += a0 * f.y;
        f = __builtin_amdgcn_cvt_pk_f32_fp8(v0.w, true);  acc[14] += a0 * f.x; acc[15] += a0 * f.y;
        i = in; e0 = e1; v0 = v1; ok0 = (in < dg);
    }
    den += __shfl_xor(den, 16);
    den += __shfl_xor(den, 32);
    #pragma unroll
    for (int j = 0; j < 16; ++j) {
        acc[j] += __shfl_xor(acc[j], 16);
        acc[j] += __shfl_xor(acc[j], 32);
    }
    if (g) return;
    float inv = 1.0f / den;
    float sN = 0.f, dN = 0.f;
    short8 w0, w1;
    #pragma unroll
    for (int j = 0; j < 16; ++j) {
        int c = cbase + j;
        float v = acc[j] * inv + bias[c];
        v = (v > 0.f) ? v : (__expf(v) - 1.f);   // ELU
        unsigned short bb = f2b(v);
        if (j < 8) w0[j] = (short)bb; else w1[j - 8] = (short)bb;
        sN += v * un[c * 2];
        dN += v * un[c * 2 + 1];
    }
    *(short8*)(o + (size_t)node * 256 + cbase) = w0;
    *(short8*)(o + (size_t)node * 256 + cbase + 8) = w1;
    #pragma unroll
    for (int off = 8; off > 0; off >>= 1) {
        sN += __shfl_xor(sN, off);
        dN += __shfl_xor(dN, off);
    }
    if (l4 == 0) { asn[node] = sN; adn[node] = dN; }
}

// ---------- final gather: fp8 messages, 8 lanes/edge + log_softmax ----------
__global__ __launch_bounds__(256) void k_gf(
    const unsigned char* __restrict__ xq,      // fp8 [NP,64]
    const float* __restrict__ asrc, const float* __restrict__ adst,
    const int* __restrict__ rowptr, const int* __restrict__ deg,
    const unsigned short* __restrict__ csr,
    const float* __restrict__ bias,            // f32 [40]
    float* __restrict__ out) {                 // f32 [N,40]
    int lane = threadIdx.x & 63;
    int node = blockIdx.x * 4 + (threadIdx.x >> 6);
    if (node >= N_NODES) return;
    int ptr = rowptr[node], dg = deg[node];
    int g = lane >> 3, l8 = lane & 7;
    int cbase = l8 * 8;
    float ad = adst[node];
    float acc[8] = {0,0,0,0,0,0,0,0};
    float den = 0.f;
    int dge = (dg + 7) & ~7;
    int i = g;
    int ci = ptr + min(i, dg - 1);
    int sn0 = csr[ci];
    float e0 = asrc[sn0];
    uint2 v0 = *(const uint2*)(xq + (size_t)sn0 * 64 + cbase);
    bool ok0 = (i < dg);
    while (i < dge) {
        int in = i + 8;
        int cn = ptr + min(in, dg - 1);
        int sn1 = csr[cn];
        float e1 = asrc[sn1];
        uint2 v1 = *(const uint2*)(xq + (size_t)sn1 * 64 + cbase);
        float e = e0 + ad;
        e = (e >= 0.f) ? e : 0.2f * e;
        float a0 = ok0 ? __expf(fminf(e, 70.f)) : 0.f;
        den += a0;
        f32x2 f;
        f = __builtin_amdgcn_cvt_pk_f32_fp8(v0.x, false); acc[0] += a0 * f.x; acc[1] += a0 * f.y;
        f = __builtin_amdgcn_cvt_pk_f32_fp8(v0.x, true);  acc[2] += a0 * f.x; acc[3] += a0 * f.y;
        f = __builtin_amdgcn_cvt_pk_f32_fp8(v0.y, false); acc[4] += a0 * f.x; acc[5] += a0 * f.y;
        f = __builtin_amdgcn_cvt_pk_f32_fp8(v0.y, true);  acc[6] += a0 * f.x; acc[7] += a0 * f.y;
        i = in; e0 = e1; v0 = v1; ok0 = (in < dg);
    }
    den += __shfl_xor(den, 8);
    den += __shfl_xor(den, 16);
    den += __shfl_xor(den, 32);
    #pragma unroll
    for (int j = 0; j < 8; ++j) {
        acc[j] += __shfl_xor(acc[j], 8);
        acc[j] += __shfl_xor(acc[j], 16);
        acc[j] += __shfl_xor(acc[j], 32);
    }
    if (g) return;
    float inv = 1.0f / den;
    float val[8], mx = -1e30f;
    #pragma unroll
    for (int j = 0; j < 8; ++j) {
        int c = cbase + j;
        val[j] = (c < 40) ? acc[j] * inv + bias[c] : -1e30f;
        mx = fmaxf(mx, val[j]);
    }
    #pragma unroll
    for (int off = 4; off > 0; off >>= 1) mx = fmaxf(mx, __shfl_xor(mx, off));
    float ex = 0.f;
    #pragma unroll
    for (int j = 0; j < 8; ++j) {
        int c = cbase + j;
        if (c < 40) ex += __expf(val[j] - mx);
    }
    #pragma unroll
    for (int off = 4; off > 0; off >>= 1) ex += __shfl_xor(ex, off);
    float lse = __logf(ex);
    #pragma unroll
    for (int j = 0; j < 8; ++j) {
        int c = cbase + j;
        if (c < 40) out[(size_t)node * 40 + c] = val[j] - mx - lse;
    }
}

extern "C" void kernel_launch(void* const* d_in, const int* in_sizes, int n_in,
                              void* d_out, int out_size, void* d_ws, size_t ws_size,
                              hipStream_t stream) {
    const float* x   = (const float*)d_in[0];
    const int*   ei  = (const int*)d_in[1];
    const float* W0  = (const float*)d_in[2];
    const float* as0 = (const float*)d_in[3];
    const float* ad0 = (const float*)d_in[4];
    const float* b0  = (const float*)d_in[5];
    const float* W1  = (const float*)d_in[6];
    const float* as1 = (const float*)d_in[7];
    const float* ad1 = (const float*)d_in[8];
    const float* b1  = (const float*)d_in[9];
    const float* W2  = (const float*)d_in[10];
    const float* as2 = (const float*)d_in[11];
    const float* ad2 = (const float*)d_in[12];
    const float* b2  = (const float*)d_in[13];
    float* out = (float*)d_out;

    char* p = (char*)d_ws;
    auto carve = [&](size_t bytes) -> char* {
        char* r = p; p += (bytes + 255) & ~(size_t)255; return r;
    };
    unsigned short* h2   = (unsigned short*)carve((size_t)NP * 256 * 2);  // h2 (layer-1 out)
    unsigned short* xpb  = (unsigned short*)carve((size_t)NP * 256 * 2);  // fp8 messages overlay
    unsigned short* h    = (unsigned short*)carve((size_t)NP * 256 * 2);  // h1
    unsigned char*  xq2  = (unsigned char*)carve((size_t)NP * 64);
    unsigned short* Wt0  = (unsigned short*)carve(256 * 256 * 2);
    unsigned short* Wt1  = (unsigned short*)carve(256 * 256 * 2);
    unsigned short* Wt2  = (unsigned short*)carve(64 * 256 * 2);
    unsigned short* u0t  = (unsigned short*)carve(16 * 256 * 2);
    float* att0 = (float*)carve((size_t)NP * 16 * 4);
    float* u1 = (float*)carve(256 * 2 * 4);
    float* u2 = (float*)carve(256 * 2 * 4);
    float* asrc1 = (float*)carve((size_t)N_NODES * 4);
    float* adst1 = (float*)carve((size_t)N_NODES * 4);
    float* asrc2 = (float*)carve((size_t)N_NODES * 4);
    float* adst2 = (float*)carve((size_t)N_NODES * 4);
    int* deg    = (int*)carve((size_t)N_NODES * 4);
    int* rowptr = (int*)carve((size_t)N_NODES * 4);
    int* bcnt   = (int*)carve((size_t)NBUCK * 4);
    unsigned int* stage = (unsigned int*)carve((size_t)NBUCK * BCAP * 4);
    unsigned short* csr = (unsigned short*)carve((size_t)NBUCK * BCAP * 2);
    unsigned char* xq = (unsigned char*)xpb;   // fp8 messages overlay (layers 0 and 1)

    k_tb3<<<(147456 + 255) / 256, 256, 0, stream>>>(W0, W1, W2, Wt0, Wt1, Wt2, bcnt);
    k_mku0<<<64, 256, 0, stream>>>(W0, as0, ad0, u0t);
    k_mku1x2<<<128, 256, 0, stream>>>(W1, as1, ad1, W2, as2, ad2, u1, u2);

    k_bscatter<<<(ETOT + 8191) / 8192, 256, 0, stream>>>(ei, bcnt, stage);
    k_csr<<<NBUCK, 256, 0, stream>>>(stage, bcnt, rowptr, deg, csr);

    dim3 gg(NP / 128, 2);
    dim3 gn(N_NODES / 4);
    dim3 g1(NP / 128);
    // layer 0: GEMM reads x (f32) directly, converts in-register; fp8 messages;
    // att logits fused into the GEMM (blockIdx.y==0)
    k_gemm_w<true, true><<<gg, 256, 0, stream>>>(x, Wt0, xq, u0t, att0, N_NODES, 256);
    k_gatherq<8><<<gn, 256, 0, stream>>>(xq, att0, att0 + 8, rowptr, deg, csr,
                                         b0, u1, h, asrc1, adst1);
    // layer 1: fp8 messages
    k_gemm_w<false, false><<<gg, 256, 0, stream>>>(h, Wt1, xq, nullptr, nullptr, N_NODES, 256);
    k_gatherq<1><<<gn, 256, 0, stream>>>(xq, asrc1, adst1, rowptr, deg, csr,
                                         b1, u2, h2, asrc2, adst2);
    // layer 2: fp8 messages + log_softmax
    k_gemm_b<<<g1, 256, 0, stream>>>(h2, Wt2, xq2, N_NODES, 40, 64);
    k_gf<<<gn, 256, 0, stream>>>(xq2, asrc2, adst2, rowptr, deg, csr, b2, out);
}